// Round 17
// baseline (306.272 us; speedup 1.0000x reference)
//
#include <hip/hip_runtime.h>
#include <hip/hip_bf16.h>

#define FINF 3.402823466e38f

typedef short bf16x8 __attribute__((ext_vector_type(8)));
typedef float f32x4 __attribute__((ext_vector_type(4)));

__device__ __forceinline__ unsigned short f2bf_rne(float f) {
  unsigned u = __float_as_uint(f);
  unsigned r = u + 0x7fff + ((u >> 16) & 1);
  return (unsigned short)(r >> 16);
}
__device__ __forceinline__ float bf2f(unsigned short u) {
  return __uint_as_float(((unsigned)u) << 16);
}
__device__ __forceinline__ unsigned long long shflx64(unsigned long long v, int m) {
  unsigned lo = __shfl_xor((unsigned)(v & 0xFFFFFFFFu), m, 64);
  unsigned hi = __shfl_xor((unsigned)(v >> 32), m, 64);
  return (((unsigned long long)hi) << 32) | lo;
}
// raw barrier: waits LDS ops only, leaves global prefetches in flight
__device__ __forceinline__ void lds_barrier() {
  asm volatile("s_waitcnt lgkmcnt(0)" ::: "memory");
  __builtin_amdgcn_s_barrier();
  __builtin_amdgcn_sched_barrier(0);
}
// async global->LDS, 16B per lane; LDS dest = uniform base + lane*16
__device__ __forceinline__ void gload16(const unsigned short* g, short* l) {
  __builtin_amdgcn_global_load_lds(
      (const __attribute__((address_space(1))) unsigned int*)g,
      (__attribute__((address_space(3))) unsigned int*)l, 16, 0, 0);
}

// ---------------- w1swz: conv1_w [32,4,8,8] -> B frags [ky8][nf2][64][8] hi/lo ----------------
__global__ __launch_bounds__(128) void w1swz_k(const float* __restrict__ w1,
                                               unsigned short* __restrict__ bh,
                                               unsigned short* __restrict__ bl) {
  int ky = blockIdx.x;
  int t = threadIdx.x, nf = t >> 6, l = t & 63;
  int oc = nf * 16 + (l & 15), ic = l >> 4;
  bf16x8 hv, lv;
#pragma unroll
  for (int j = 0; j < 8; ++j) {
    float v = w1[((oc * 4 + ic) * 8 + ky) * 8 + j];
    unsigned short h = f2bf_rne(v);
    hv[j] = (short)h;
    lv[j] = (short)f2bf_rne(v - bf2f(h));
  }
  *(bf16x8*)(&bh[((size_t)(ky * 2 + nf) * 64 + l) * 8]) = hv;
  *(bf16x8*)(&bl[((size_t)(ky * 2 + nf) * 64 + l) * 8]) = lv;
}

// ---------------- conv1m: x f32 -> h1s NHWC [204800 pix][32hi|32lo], 8-tap MFMA ----------------
__global__ __launch_bounds__(256) void conv1m_k(
    const float* __restrict__ x,
    const unsigned short* __restrict__ bh, const unsigned short* __restrict__ bl,
    const float* __restrict__ bias, unsigned short* __restrict__ h1s) {
  __shared__ short As[256 * 72];  // row*72: [0,32)=hi (4ic x 8kx), [36,68)=lo
  int t = threadIdx.x, w = t >> 6, lane = t & 63, lm = lane & 15, hi4 = lane >> 4;
  int m = blockIdx.x * 256 + t;
  int n = m / 400, p = m % 400, oy = p / 20, ox = p % 20;
  size_t xoff = (size_t)n * 28224 + (size_t)(oy * 4) * 84 + ox * 4;  // + ic*7056 + ky*84
  f32x4 acc[4][2];
#pragma unroll
  for (int mf = 0; mf < 4; ++mf)
#pragma unroll
    for (int nf = 0; nf < 2; ++nf) acc[mf][nf] = (f32x4){0.f, 0.f, 0.f, 0.f};

  float4 fa[8];  // current tap: [ic*2 + half]
#pragma unroll
  for (int ic = 0; ic < 4; ++ic) {
    fa[ic * 2 + 0] = *(const float4*)(x + xoff + ic * 7056);
    fa[ic * 2 + 1] = *(const float4*)(x + xoff + ic * 7056 + 4);
  }
  const unsigned short* bfp = bh + (size_t)lane * 8;
  const unsigned short* blp = bl + (size_t)lane * 8;
  bf16x8 cbh[2], cbl[2];
#pragma unroll
  for (int nf = 0; nf < 2; ++nf) {
    cbh[nf] = *(const bf16x8*)(bfp + nf * 512);
    cbl[nf] = *(const bf16x8*)(blp + nf * 512);
  }
#pragma unroll
  for (int ky = 0; ky < 8; ++ky) {
    if (ky) lds_barrier();
    {
      short* wp = &As[t * 72];
#pragma unroll
      for (int ic = 0; ic < 4; ++ic) {
        float e0 = fa[ic * 2].x, e1 = fa[ic * 2].y, e2 = fa[ic * 2].z, e3 = fa[ic * 2].w;
        float e4 = fa[ic * 2 + 1].x, e5 = fa[ic * 2 + 1].y, e6 = fa[ic * 2 + 1].z, e7 = fa[ic * 2 + 1].w;
        bf16x8 hv, lv;
        unsigned short h;
        h = f2bf_rne(e0); hv[0] = (short)h; lv[0] = (short)f2bf_rne(e0 - bf2f(h));
        h = f2bf_rne(e1); hv[1] = (short)h; lv[1] = (short)f2bf_rne(e1 - bf2f(h));
        h = f2bf_rne(e2); hv[2] = (short)h; lv[2] = (short)f2bf_rne(e2 - bf2f(h));
        h = f2bf_rne(e3); hv[3] = (short)h; lv[3] = (short)f2bf_rne(e3 - bf2f(h));
        h = f2bf_rne(e4); hv[4] = (short)h; lv[4] = (short)f2bf_rne(e4 - bf2f(h));
        h = f2bf_rne(e5); hv[5] = (short)h; lv[5] = (short)f2bf_rne(e5 - bf2f(h));
        h = f2bf_rne(e6); hv[6] = (short)h; lv[6] = (short)f2bf_rne(e6 - bf2f(h));
        h = f2bf_rne(e7); hv[7] = (short)h; lv[7] = (short)f2bf_rne(e7 - bf2f(h));
        *(bf16x8*)(wp + ic * 8) = hv;
        *(bf16x8*)(wp + 36 + ic * 8) = lv;
      }
    }
    lds_barrier();
    bf16x8 nbh[2], nbl[2];
    if (ky < 7) {
      size_t ap = xoff + (size_t)(ky + 1) * 84;
#pragma unroll
      for (int ic = 0; ic < 4; ++ic) {
        fa[ic * 2 + 0] = *(const float4*)(x + ap + ic * 7056);
        fa[ic * 2 + 1] = *(const float4*)(x + ap + ic * 7056 + 4);
      }
#pragma unroll
      for (int nf = 0; nf < 2; ++nf) {
        nbh[nf] = *(const bf16x8*)(bfp + ((ky + 1) * 2 + nf) * 512);
        nbl[nf] = *(const bf16x8*)(blp + ((ky + 1) * 2 + nf) * 512);
      }
    }
    bf16x8 ah[4], al[4];
#pragma unroll
    for (int mf = 0; mf < 4; ++mf) {
      const short* rp = &As[(w * 64 + mf * 16 + lm) * 72 + hi4 * 8];
      ah[mf] = *(const bf16x8*)(rp);
      al[mf] = *(const bf16x8*)(rp + 36);
    }
#pragma unroll
    for (int mf = 0; mf < 4; ++mf)
#pragma unroll
      for (int nf = 0; nf < 2; ++nf) {
        acc[mf][nf] = __builtin_amdgcn_mfma_f32_16x16x32_bf16(ah[mf], cbh[nf], acc[mf][nf], 0, 0, 0);
        acc[mf][nf] = __builtin_amdgcn_mfma_f32_16x16x32_bf16(ah[mf], cbl[nf], acc[mf][nf], 0, 0, 0);
        acc[mf][nf] = __builtin_amdgcn_mfma_f32_16x16x32_bf16(al[mf], cbh[nf], acc[mf][nf], 0, 0, 0);
      }
    if (ky < 7) {
#pragma unroll
      for (int nf = 0; nf < 2; ++nf) { cbh[nf] = nbh[nf]; cbl[nf] = nbl[nf]; }
    }
  }
  float bv[2];
#pragma unroll
  for (int nf = 0; nf < 2; ++nf) bv[nf] = bias[nf * 16 + lm];
#pragma unroll
  for (int mf = 0; mf < 4; ++mf)
#pragma unroll
    for (int nf = 0; nf < 2; ++nf)
#pragma unroll
      for (int r = 0; r < 4; ++r) {
        size_t mrow = (size_t)blockIdx.x * 256 + w * 64 + mf * 16 + hi4 * 4 + r;
        float v = fmaxf(acc[mf][nf][r] + bv[nf], 0.f);
        unsigned short h = f2bf_rne(v);
        h1s[mrow * 64 + nf * 16 + lm] = h;
        h1s[mrow * 64 + 32 + nf * 16 + lm] = f2bf_rne(v - bf2f(h));
      }
}

// ---------------- w2swz: conv2_w -> MFMA B-frag layout hi/lo [tap16][nf4][64][8] ----------------
__global__ __launch_bounds__(256) void w2swz_k(const float* __restrict__ w2,
                                               unsigned short* __restrict__ bh,
                                               unsigned short* __restrict__ bl) {
  int tap = blockIdx.x, ky = tap >> 2, kx = tap & 3;
  int t = threadIdx.x, nf = t >> 6, l = t & 63;
  int oc = nf * 16 + (l & 15);
  bf16x8 hv, lv;
#pragma unroll
  for (int j = 0; j < 8; ++j) {
    int ic = (l >> 4) * 8 + j;
    float v = w2[((oc * 32 + ic) * 4 + ky) * 4 + kx];
    unsigned short h = f2bf_rne(v);
    hv[j] = (short)h;
    lv[j] = (short)f2bf_rne(v - bf2f(h));
  }
  *(bf16x8*)(&bh[((size_t)(tap * 4 + nf) * 64 + l) * 8]) = hv;
  *(bf16x8*)(&bl[((size_t)(tap * 4 + nf) * 64 + l) * 8]) = lv;
}

// ---------------- w3swz: conv3_w -> [tt18][nf4][64][8] (tt = tap*2+half) ----------------
__global__ __launch_bounds__(256) void w3swz_k(const float* __restrict__ w3,
                                               unsigned short* __restrict__ bh,
                                               unsigned short* __restrict__ bl) {
  int tt = blockIdx.x, tap = tt >> 1, half = tt & 1, ky = tap / 3, kx = tap % 3;
  int t = threadIdx.x, nf = t >> 6, l = t & 63;
  int oc = nf * 16 + (l & 15);
  bf16x8 hv, lv;
#pragma unroll
  for (int j = 0; j < 8; ++j) {
    int ic = half * 32 + (l >> 4) * 8 + j;
    float v = w3[((oc * 64 + ic) * 3 + ky) * 3 + kx];
    unsigned short h = f2bf_rne(v);
    hv[j] = (short)h;
    lv[j] = (short)f2bf_rne(v - bf2f(h));
  }
  *(bf16x8*)(&bh[((size_t)(tt * 4 + nf) * 64 + l) * 8]) = hv;
  *(bf16x8*)(&bl[((size_t)(tt * 4 + nf) * 64 + l) * 8]) = lv;
}

// ---------------- conv2m: h1s NHWC -> h2s [41472 pix][64hi|64lo], 16-tap MFMA, single-buf ----------------
__global__ __launch_bounds__(256) void conv2m_k(
    const unsigned short* __restrict__ h1s, const unsigned short* __restrict__ bh,
    const unsigned short* __restrict__ bl, const float* __restrict__ bias,
    unsigned short* __restrict__ h2s) {
  __shared__ short As[256 * 72];
  int t = threadIdx.x, w = t >> 6, lane = t & 63, lm = lane & 15, hi4 = lane >> 4;
  int m = blockIdx.x * 256 + t;
  int n = m / 81, p = m % 81, oy = p / 9, ox = p % 9;
  const unsigned short* abase = h1s + (size_t)(n * 400 + oy * 40 + ox * 2) * 64;
  f32x4 acc[4][4];
#pragma unroll
  for (int mf = 0; mf < 4; ++mf)
#pragma unroll
    for (int nf = 0; nf < 4; ++nf) acc[mf][nf] = (f32x4){0.f, 0.f, 0.f, 0.f};

  bf16x8 s0, s1, s2, s3, s4, s5, s6, s7;
  {
    const unsigned short* ap = abase;  // tap 0
    s0 = *(const bf16x8*)(ap);      s1 = *(const bf16x8*)(ap + 8);
    s2 = *(const bf16x8*)(ap + 16); s3 = *(const bf16x8*)(ap + 24);
    s4 = *(const bf16x8*)(ap + 32); s5 = *(const bf16x8*)(ap + 40);
    s6 = *(const bf16x8*)(ap + 48); s7 = *(const bf16x8*)(ap + 56);
  }
  const unsigned short* bfp = bh + (size_t)lane * 8;
  const unsigned short* blp = bl + (size_t)lane * 8;
  bf16x8 cbh[4], cbl[4];
#pragma unroll
  for (int nf = 0; nf < 4; ++nf) {
    cbh[nf] = *(const bf16x8*)(bfp + nf * 512);
    cbl[nf] = *(const bf16x8*)(blp + nf * 512);
  }
#pragma unroll
  for (int tap = 0; tap < 16; ++tap) {
    if (tap) lds_barrier();
    {
      short* wp = &As[t * 72];
      *(bf16x8*)(wp) = s0;      *(bf16x8*)(wp + 8) = s1;
      *(bf16x8*)(wp + 16) = s2; *(bf16x8*)(wp + 24) = s3;
      *(bf16x8*)(wp + 36) = s4; *(bf16x8*)(wp + 44) = s5;
      *(bf16x8*)(wp + 52) = s6; *(bf16x8*)(wp + 60) = s7;
    }
    lds_barrier();
    bf16x8 nbh[4], nbl[4];
    if (tap < 15) {
      const unsigned short* ap = abase + (((tap + 1) >> 2) * 1280 + ((tap + 1) & 3) * 64);
      s0 = *(const bf16x8*)(ap);      s1 = *(const bf16x8*)(ap + 8);
      s2 = *(const bf16x8*)(ap + 16); s3 = *(const bf16x8*)(ap + 24);
      s4 = *(const bf16x8*)(ap + 32); s5 = *(const bf16x8*)(ap + 40);
      s6 = *(const bf16x8*)(ap + 48); s7 = *(const bf16x8*)(ap + 56);
#pragma unroll
      for (int nf = 0; nf < 4; ++nf) {
        nbh[nf] = *(const bf16x8*)(bfp + ((tap + 1) * 4 + nf) * 512);
        nbl[nf] = *(const bf16x8*)(blp + ((tap + 1) * 4 + nf) * 512);
      }
    }
    bf16x8 ah[4], al[4];
#pragma unroll
    for (int mf = 0; mf < 4; ++mf) {
      const short* rp = &As[(w * 64 + mf * 16 + lm) * 72 + hi4 * 8];
      ah[mf] = *(const bf16x8*)(rp);
      al[mf] = *(const bf16x8*)(rp + 36);
    }
#pragma unroll
    for (int mf = 0; mf < 4; ++mf)
#pragma unroll
      for (int nf = 0; nf < 4; ++nf) {
        acc[mf][nf] = __builtin_amdgcn_mfma_f32_16x16x32_bf16(ah[mf], cbh[nf], acc[mf][nf], 0, 0, 0);
        acc[mf][nf] = __builtin_amdgcn_mfma_f32_16x16x32_bf16(ah[mf], cbl[nf], acc[mf][nf], 0, 0, 0);
        acc[mf][nf] = __builtin_amdgcn_mfma_f32_16x16x32_bf16(al[mf], cbh[nf], acc[mf][nf], 0, 0, 0);
      }
    if (tap < 15) {
#pragma unroll
      for (int nf = 0; nf < 4; ++nf) { cbh[nf] = nbh[nf]; cbl[nf] = nbl[nf]; }
    }
  }
  float bv[4];
#pragma unroll
  for (int nf = 0; nf < 4; ++nf) bv[nf] = bias[nf * 16 + lm];
#pragma unroll
  for (int mf = 0; mf < 4; ++mf)
#pragma unroll
    for (int nf = 0; nf < 4; ++nf)
#pragma unroll
      for (int r = 0; r < 4; ++r) {
        size_t mrow = (size_t)blockIdx.x * 256 + w * 64 + mf * 16 + hi4 * 4 + r;
        float v = fmaxf(acc[mf][nf][r] + bv[nf], 0.f);
        unsigned short h = f2bf_rne(v);
        h2s[mrow * 128 + nf * 16 + lm] = h;
        h2s[mrow * 128 + 64 + nf * 16 + lm] = f2bf_rne(v - bf2f(h));
      }
}

// ---------------- conv3m: h2s -> h3hi/h3lo [25088 pix][64], 18-chunk MFMA, single-buf ----------------
__global__ __launch_bounds__(256) void conv3m_k(
    const unsigned short* __restrict__ h2s, const unsigned short* __restrict__ bh,
    const unsigned short* __restrict__ bl, const float* __restrict__ bias,
    unsigned short* __restrict__ h3hi, unsigned short* __restrict__ h3lo) {
  __shared__ short As[256 * 72];
  int t = threadIdx.x, w = t >> 6, lane = t & 63, lm = lane & 15, hi4 = lane >> 4;
  int m = blockIdx.x * 256 + t;
  int n = m / 49, p = m % 49, oy = p / 7, ox = p % 7;
  const unsigned short* abase = h2s + (size_t)(n * 81 + oy * 9 + ox) * 128;
  f32x4 acc[4][4];
#pragma unroll
  for (int mf = 0; mf < 4; ++mf)
#pragma unroll
    for (int nf = 0; nf < 4; ++nf) acc[mf][nf] = (f32x4){0.f, 0.f, 0.f, 0.f};

  bf16x8 s0, s1, s2, s3, s4, s5, s6, s7;
  {
    const unsigned short* ap = abase;
    s0 = *(const bf16x8*)(ap);      s1 = *(const bf16x8*)(ap + 8);
    s2 = *(const bf16x8*)(ap + 16); s3 = *(const bf16x8*)(ap + 24);
    s4 = *(const bf16x8*)(ap + 64); s5 = *(const bf16x8*)(ap + 72);
    s6 = *(const bf16x8*)(ap + 80); s7 = *(const bf16x8*)(ap + 88);
  }
  const unsigned short* bfp = bh + (size_t)lane * 8;
  const unsigned short* blp = bl + (size_t)lane * 8;
  bf16x8 cbh[4], cbl[4];
#pragma unroll
  for (int nf = 0; nf < 4; ++nf) {
    cbh[nf] = *(const bf16x8*)(bfp + nf * 512);
    cbl[nf] = *(const bf16x8*)(blp + nf * 512);
  }
#pragma unroll
  for (int tt = 0; tt < 18; ++tt) {
    if (tt) lds_barrier();
    {
      short* wp = &As[t * 72];
      *(bf16x8*)(wp) = s0;      *(bf16x8*)(wp + 8) = s1;
      *(bf16x8*)(wp + 16) = s2; *(bf16x8*)(wp + 24) = s3;
      *(bf16x8*)(wp + 36) = s4; *(bf16x8*)(wp + 44) = s5;
      *(bf16x8*)(wp + 52) = s6; *(bf16x8*)(wp + 60) = s7;
    }
    lds_barrier();
    bf16x8 nbh[4], nbl[4];
    if (tt < 17) {
      const int tn = tt + 1, tapn = tn >> 1, halfn = tn & 1;
      const unsigned short* ap = abase + ((tapn / 3) * 9 + (tapn % 3)) * 128 + halfn * 32;
      s0 = *(const bf16x8*)(ap);      s1 = *(const bf16x8*)(ap + 8);
      s2 = *(const bf16x8*)(ap + 16); s3 = *(const bf16x8*)(ap + 24);
      s4 = *(const bf16x8*)(ap + 64); s5 = *(const bf16x8*)(ap + 72);
      s6 = *(const bf16x8*)(ap + 80); s7 = *(const bf16x8*)(ap + 88);
#pragma unroll
      for (int nf = 0; nf < 4; ++nf) {
        nbh[nf] = *(const bf16x8*)(bfp + ((tt + 1) * 4 + nf) * 512);
        nbl[nf] = *(const bf16x8*)(blp + ((tt + 1) * 4 + nf) * 512);
      }
    }
    bf16x8 ah[4], al[4];
#pragma unroll
    for (int mf = 0; mf < 4; ++mf) {
      const short* rp = &As[(w * 64 + mf * 16 + lm) * 72 + hi4 * 8];
      ah[mf] = *(const bf16x8*)(rp);
      al[mf] = *(const bf16x8*)(rp + 36);
    }
#pragma unroll
    for (int mf = 0; mf < 4; ++mf)
#pragma unroll
      for (int nf = 0; nf < 4; ++nf) {
        acc[mf][nf] = __builtin_amdgcn_mfma_f32_16x16x32_bf16(ah[mf], cbh[nf], acc[mf][nf], 0, 0, 0);
        acc[mf][nf] = __builtin_amdgcn_mfma_f32_16x16x32_bf16(ah[mf], cbl[nf], acc[mf][nf], 0, 0, 0);
        acc[mf][nf] = __builtin_amdgcn_mfma_f32_16x16x32_bf16(al[mf], cbh[nf], acc[mf][nf], 0, 0, 0);
      }
    if (tt < 17) {
#pragma unroll
      for (int nf = 0; nf < 4; ++nf) { cbh[nf] = nbh[nf]; cbl[nf] = nbl[nf]; }
    }
  }
  float bv[4];
#pragma unroll
  for (int nf = 0; nf < 4; ++nf) bv[nf] = bias[nf * 16 + lm];
#pragma unroll
  for (int mf = 0; mf < 4; ++mf)
#pragma unroll
    for (int nf = 0; nf < 4; ++nf)
#pragma unroll
      for (int r = 0; r < 4; ++r) {
        size_t mrow = (size_t)blockIdx.x * 256 + w * 64 + mf * 16 + hi4 * 4 + r;
        float v = fmaxf(acc[mf][nf][r] + bv[nf], 0.f);
        unsigned short h = f2bf_rne(v);
        h3hi[mrow * 64 + nf * 16 + lm] = h;
        h3lo[mrow * 64 + nf * 16 + lm] = f2bf_rne(v - bf2f(h));
      }
}

// ---------------- fcwcvt: fc_w [3136,256] -> fwhi/fwlo [256][3136] bf16, k' = p*64+c ----------------
__global__ __launch_bounds__(256) void fcwcvt_k(const float* __restrict__ fw,
                                                unsigned short* __restrict__ fwhi,
                                                unsigned short* __restrict__ fwlo) {
  __shared__ float tile[64][65];
  int p = blockIdx.x, nb = blockIdx.y;  // 49 x 4
  int t = threadIdx.x;
#pragma unroll
  for (int i = 0; i < 16; ++i) {
    int c = (t >> 6) * 16 + i;
    tile[c][t & 63] = fw[(c * 49 + p) * 256 + nb * 64 + (t & 63)];
  }
  __syncthreads();
#pragma unroll
  for (int i = 0; i < 16; ++i) {
    int n2 = (t >> 6) * 16 + i, c2 = t & 63;
    float v = tile[c2][n2];
    unsigned short h = f2bf_rne(v);
    size_t o = (size_t)(nb * 64 + n2) * 3136 + p * 64 + c2;
    fwhi[o] = h;
    fwlo[o] = f2bf_rne(v - bf2f(h));
  }
}

// ---------------- fc2: split-bf16 MFMA, grid 8mb x 14kc, 7 k-steps each, fused 3 terms ----------------
__global__ __launch_bounds__(256) void fc2_k(
    const unsigned short* __restrict__ h3hi, const unsigned short* __restrict__ h3lo,
    const unsigned short* __restrict__ fwhi, const unsigned short* __restrict__ fwlo,
    float* __restrict__ hpre) {
  int t = threadIdx.x, w = t >> 6, lane = t & 63, lm = lane & 15, hi4 = lane >> 4;
  int b = blockIdx.x, mb = b / 14, kc = b % 14;
  int m0 = mb * 64, n0 = w * 64;
  size_t kof = (size_t)kc * 224 + hi4 * 8;
  const unsigned short* pah[4]; const unsigned short* pal[4];
  const unsigned short* pbh[4]; const unsigned short* pbl[4];
#pragma unroll
  for (int mf = 0; mf < 4; ++mf) {
    pah[mf] = h3hi + (size_t)(m0 + mf * 16 + lm) * 3136 + kof;
    pal[mf] = h3lo + (size_t)(m0 + mf * 16 + lm) * 3136 + kof;
  }
#pragma unroll
  for (int nf = 0; nf < 4; ++nf) {
    pbh[nf] = fwhi + (size_t)(n0 + nf * 16 + lm) * 3136 + kof;
    pbl[nf] = fwlo + (size_t)(n0 + nf * 16 + lm) * 3136 + kof;
  }
  f32x4 acc[4][4];
#pragma unroll
  for (int mf = 0; mf < 4; ++mf)
#pragma unroll
    for (int nf = 0; nf < 4; ++nf) acc[mf][nf] = (f32x4){0.f, 0.f, 0.f, 0.f};
  bf16x8 cah[4], cal[4], cbh[4], cbl[4];
#pragma unroll
  for (int i = 0; i < 4; ++i) {
    cah[i] = *(const bf16x8*)(pah[i]); cal[i] = *(const bf16x8*)(pal[i]);
    cbh[i] = *(const bf16x8*)(pbh[i]); cbl[i] = *(const bf16x8*)(pbl[i]);
  }
#pragma unroll
  for (int ks = 0; ks < 7; ++ks) {
    bf16x8 nah[4], nal[4], nbh[4], nbl[4];
    if (ks < 6) {
      const int off = (ks + 1) * 32;
#pragma unroll
      for (int i = 0; i < 4; ++i) {
        nah[i] = *(const bf16x8*)(pah[i] + off); nal[i] = *(const bf16x8*)(pal[i] + off);
        nbh[i] = *(const bf16x8*)(pbh[i] + off); nbl[i] = *(const bf16x8*)(pbl[i] + off);
      }
    }
#pragma unroll
    for (int mf = 0; mf < 4; ++mf)
#pragma unroll
      for (int nf = 0; nf < 4; ++nf) {
        acc[mf][nf] = __builtin_amdgcn_mfma_f32_16x16x32_bf16(cah[mf], cbh[nf], acc[mf][nf], 0, 0, 0);
        acc[mf][nf] = __builtin_amdgcn_mfma_f32_16x16x32_bf16(cah[mf], cbl[nf], acc[mf][nf], 0, 0, 0);
        acc[mf][nf] = __builtin_amdgcn_mfma_f32_16x16x32_bf16(cal[mf], cbh[nf], acc[mf][nf], 0, 0, 0);
      }
    if (ks < 6) {
#pragma unroll
      for (int i = 0; i < 4; ++i) {
        cah[i] = nah[i]; cal[i] = nal[i]; cbh[i] = nbh[i]; cbl[i] = nbl[i];
      }
    }
  }
  float* outp = hpre + (size_t)kc * 131072;
#pragma unroll
  for (int mf = 0; mf < 4; ++mf)
#pragma unroll
    for (int nf = 0; nf < 4; ++nf)
#pragma unroll
      for (int r = 0; r < 4; ++r)
        outp[(m0 + mf * 16 + hi4 * 4 + r) * 256 + n0 + nf * 16 + lm] = acc[mf][nf][r];
}

// ---------------- fc_post: sum 14 k-planes + bias + relu -> hout + a_split ----------------
__global__ __launch_bounds__(256) void fc_post_k(
    const float* __restrict__ hpre, const float* __restrict__ fb,
    float* __restrict__ hout, unsigned short* __restrict__ a_split) {
  int m = blockIdx.x, n = threadIdx.x;
  float v = fb[n];
#pragma unroll
  for (int kc = 0; kc < 14; ++kc) v += hpre[(size_t)kc * 131072 + m * 256 + n];
  v = fmaxf(v, 0.f);
  hout[m * 256 + n] = v;
  unsigned short hi = f2bf_rne(v);
  unsigned short lo = f2bf_rne(v - bf2f(hi));
  a_split[(size_t)m * 768 + n] = hi;
  a_split[(size_t)m * 768 + 256 + n] = hi;
  a_split[(size_t)m * 768 + 512 + n] = lo;
}

// ---------------- embcvt: buf_emb -> Bemb[50176,512] bf16 (hi|lo) + nrm ----------------
__global__ __launch_bounds__(256) void embcvt_k(const float* __restrict__ e,
                                                unsigned short* __restrict__ Bemb,
                                                float* __restrict__ nrm) {
  int row = blockIdx.x * 4 + (threadIdx.x >> 6);
  if (row >= 50000) return;
  int lane = threadIdx.x & 63;
  float4 v = ((const float4*)(e + row * 256))[lane];
  float s = v.x * v.x + v.y * v.y + v.z * v.z + v.w * v.w;
  unsigned short h0 = f2bf_rne(v.x), h1 = f2bf_rne(v.y), h2 = f2bf_rne(v.z), h3 = f2bf_rne(v.w);
  unsigned short l0 = f2bf_rne(v.x - bf2f(h0)), l1 = f2bf_rne(v.y - bf2f(h1));
  unsigned short l2 = f2bf_rne(v.z - bf2f(h2)), l3 = f2bf_rne(v.w - bf2f(h3));
  *(ushort4*)(Bemb + (size_t)row * 512 + lane * 4) = make_ushort4(h0, h1, h2, h3);
  *(ushort4*)(Bemb + (size_t)row * 512 + 256 + lane * 4) = make_ushort4(l0, l1, l2, l3);
  for (int off = 32; off > 0; off >>= 1) s += __shfl_down(s, off);
  if (lane == 0) nrm[row] = s;
}

// ---------------- dist3: B-only LDS staging, A direct from L2, merged-term MFMA + top-5 ----------------
// grid 1568 = 8xcd x 196; p = xcd*196+idx; nb = p>>2 (0..391), mb = p&3.
// Tile M=128 x N=128; 4 waves 2mw x 2nw. K = 4 slices of 64 shorts.
// LDS: Bh/Bl only (32KB, single-buffer) -> 4+ blocks/CU. A (a_split, 768KB, L2-hot:
// each mb-slice read by 392 blocks) is read as per-lane 16B fragments directly from
// global. Per slice: all 3 split terms = 96 MFMA/wave per exposure.
// B swizzle: 16B slot' = slot ^ (row&7) at per-lane GLOBAL source + on ds_read.
__global__ __launch_bounds__(256) void dist3_k(
    const unsigned short* __restrict__ a_split, const unsigned short* __restrict__ Bemb,
    const float* __restrict__ nrm, unsigned long long* __restrict__ cand) {
  __shared__ short Bh[8192];
  __shared__ short Bl[8192];
  int t = threadIdx.x, w = t >> 6, lane = t & 63, lm = lane & 15, hi = lane >> 4;
  int mw = w >> 1, nw = w & 1;
  int b = blockIdx.x;
  int p = (b & 7) * 196 + (b >> 3);
  int nb = p >> 2, mb = p & 3;

  const unsigned short* aTile = a_split + (size_t)mb * 128 * 768;
  const unsigned short* bTile = Bemb + (size_t)nb * 128 * 512;

  int crow[4], csl[4];
#pragma unroll
  for (int i = 0; i < 4; ++i) {
    int p16 = (w * 4 + i) * 64 + lane;
    crow[i] = p16 >> 3;
    csl[i] = ((p16 & 7) ^ (crow[i] & 7)) * 8;
  }

  f32x4 acc[4][4];  // [nf][mf]
#pragma unroll
  for (int nf = 0; nf < 4; ++nf)
#pragma unroll
    for (int mf = 0; mf < 4; ++mf) acc[nf][mf] = (f32x4){0.f, 0.f, 0.f, 0.f};

  const int arow0 = mw * 64;
  const int brow0 = nw * 64;

#pragma unroll
  for (int kk = 0; kk < 4; ++kk) {
    if (kk) lds_barrier();  // all waves done reading previous B slice
    const int ko = kk * 64;
#pragma unroll
    for (int i = 0; i < 4; ++i) {
      gload16(bTile + (size_t)crow[i] * 512 + ko + csl[i], &Bh[(w * 4 + i) * 512]);
      gload16(bTile + (size_t)crow[i] * 512 + 256 + ko + csl[i], &Bl[(w * 4 + i) * 512]);
    }
    asm volatile("s_waitcnt vmcnt(0)" ::: "memory");
    __builtin_amdgcn_s_barrier();
    __builtin_amdgcn_sched_barrier(0);
#pragma unroll
    for (int q2 = 0; q2 < 2; ++q2) {
      bf16x8 fah[4], fal[4], fbh[4], fbl[4];
#pragma unroll
      for (int mf = 0; mf < 4; ++mf) {
        const unsigned short* ap =
            aTile + (size_t)(arow0 + mf * 16 + lm) * 768 + ko + q2 * 32 + hi * 8;
        fah[mf] = *(const bf16x8*)(ap);
        fal[mf] = *(const bf16x8*)(ap + 512);
      }
#pragma unroll
      for (int nf = 0; nf < 4; ++nf) {
        int row = brow0 + nf * 16 + lm;
        int off = row * 64 + (((q2 * 4 + hi) ^ (lm & 7)) * 8);
        fbh[nf] = *(const bf16x8*)(&Bh[off]);
        fbl[nf] = *(const bf16x8*)(&Bl[off]);
      }
#pragma unroll
      for (int nf = 0; nf < 4; ++nf)
#pragma unroll
        for (int mf = 0; mf < 4; ++mf) {
          acc[nf][mf] = __builtin_amdgcn_mfma_f32_16x16x32_bf16(fbh[nf], fah[mf], acc[nf][mf], 0, 0, 0);
          acc[nf][mf] = __builtin_amdgcn_mfma_f32_16x16x32_bf16(fbl[nf], fah[mf], acc[nf][mf], 0, 0, 0);
          acc[nf][mf] = __builtin_amdgcn_mfma_f32_16x16x32_bf16(fbh[nf], fal[mf], acc[nf][mf], 0, 0, 0);
        }
    }
  }

  // ---- fused selection: per lane, per mf: sorted-5 of (score|n) u64 keys ----
  const int nbase = nb * 128 + nw * 64;
  const int mbase = mb * 128 + mw * 64;
  unsigned long long Lst[4][5];
#pragma unroll
  for (int mf = 0; mf < 4; ++mf)
#pragma unroll
    for (int j = 0; j < 5; ++j) Lst[mf][j] = ~0ull;

#pragma unroll
  for (int nf = 0; nf < 4; ++nf) {
    int n0 = nbase + nf * 16 + hi * 4;
    float4 nv = *(const float4*)(nrm + n0);
#pragma unroll
    for (int r = 0; r < 4; ++r) {
      int n = n0 + r;
      bool ok = n < 50000;
      float nvr = (r == 0) ? nv.x : (r == 1) ? nv.y : (r == 2) ? nv.z : nv.w;
#pragma unroll
      for (int mf = 0; mf < 4; ++mf) {
        float sc = nvr - 2.f * acc[nf][mf][r];
        unsigned u = __float_as_uint(sc);
        u = ((int)u < 0) ? ~u : (u | 0x80000000u);
        unsigned long long k = ok ? ((((unsigned long long)u) << 32) | (unsigned)n) : ~0ull;
        if (k < Lst[mf][4]) {
          bool b3 = k < Lst[mf][3], b2 = k < Lst[mf][2], b1 = k < Lst[mf][1], b0 = k < Lst[mf][0];
          Lst[mf][4] = b3 ? Lst[mf][3] : k;
          Lst[mf][3] = b3 ? (b2 ? Lst[mf][2] : k) : Lst[mf][3];
          Lst[mf][2] = b2 ? (b1 ? Lst[mf][1] : k) : Lst[mf][2];
          Lst[mf][1] = b1 ? (b0 ? Lst[mf][0] : k) : Lst[mf][1];
          Lst[mf][0] = b0 ? k : Lst[mf][0];
        }
      }
    }
  }
#pragma unroll
  for (int mf = 0; mf < 4; ++mf) {
#pragma unroll
    for (int s = 16; s <= 32; s <<= 1) {
      unsigned long long b0 = shflx64(Lst[mf][0], s), b1 = shflx64(Lst[mf][1], s),
                         b2 = shflx64(Lst[mf][2], s), b3 = shflx64(Lst[mf][3], s),
                         b4 = shflx64(Lst[mf][4], s);
      unsigned long long a0 = Lst[mf][0], a1 = Lst[mf][1], a2 = Lst[mf][2],
                         a3 = Lst[mf][3], a4 = Lst[mf][4];
#pragma unroll
      for (int j = 0; j < 5; ++j) {
        bool ta = a0 <= b0;
        Lst[mf][j] = ta ? a0 : b0;
        unsigned long long na0 = ta ? a1 : a0, na1 = ta ? a2 : a1, na2 = ta ? a3 : a2, na3 = ta ? a4 : a3;
        unsigned long long nb0 = ta ? b0 : b1, nb1 = ta ? b1 : b2, nb2 = ta ? b2 : b3, nb3 = ta ? b3 : b4;
        a0 = na0; a1 = na1; a2 = na2; a3 = na3;
        b0 = nb0; b1 = nb1; b2 = nb2; b3 = nb3;
      }
    }
  }
  if (lane < 16) {
#pragma unroll
    for (int mf = 0; mf < 4; ++mf) {
      size_t base = ((size_t)(mbase + mf * 16 + lm) * 784 + (nb * 2 + nw)) * 5;
#pragma unroll
      for (int j = 0; j < 5; ++j) cand[base + j] = Lst[mf][j];
    }
  }
}

// ---------------- merge2: per row top-5 of 3920 keys, gather+blend ----------------
__global__ __launch_bounds__(64) void merge2_k(
    const unsigned long long* __restrict__ cand, const float* __restrict__ hbuf,
    const float* __restrict__ bufq, const float* __restrict__ out_w,
    const float* __restrict__ out_b, float* __restrict__ qout) {
  int row = blockIdx.x, lane = threadIdx.x;
  unsigned long long L0 = ~0ull, L1 = ~0ull, L2 = ~0ull, L3 = ~0ull, L4 = ~0ull;
  const unsigned long long* cr = cand + (size_t)row * 3920;
  for (int i = lane; i < 3920; i += 64) {
    unsigned long long k = cr[i];
    if (k < L4) {
      bool b3 = k < L3, b2 = k < L2, b1 = k < L1, b0 = k < L0;
      L4 = b3 ? L3 : k;
      L3 = b3 ? (b2 ? L2 : k) : L3;
      L2 = b2 ? (b1 ? L1 : k) : L2;
      L1 = b1 ? (b0 ? L0 : k) : L1;
      L0 = b0 ? k : L0;
    }
  }
#pragma unroll
  for (int s = 1; s < 64; s <<= 1) {
    unsigned long long o0 = shflx64(L0, s), o1 = shflx64(L1, s), o2 = shflx64(L2, s),
                       o3 = shflx64(L3, s), o4 = shflx64(L4, s);
    unsigned long long a0 = L0, a1 = L1, a2 = L2, a3 = L3, a4 = L4;
    unsigned long long b0 = o0, b1 = o1, b2 = o2, b3 = o3, b4 = o4;
    unsigned long long m[5];
#pragma unroll
    for (int j = 0; j < 5; ++j) {
      bool ta = a0 <= b0;
      m[j] = ta ? a0 : b0;
      unsigned long long na0 = ta ? a1 : a0, na1 = ta ? a2 : a1, na2 = ta ? a3 : a2, na3 = ta ? a4 : a3;
      unsigned long long nb0 = ta ? b0 : b1, nb1 = ta ? b1 : b2, nb2 = ta ? b2 : b3, nb3 = ta ? b3 : b4;
      a0 = na0; a1 = na1; a2 = na2; a3 = na3;
      b0 = nb0; b1 = nb1; b2 = nb2; b3 = nb3;
    }
    L0 = m[0]; L1 = m[1]; L2 = m[2]; L3 = m[3]; L4 = m[4];
  }
  int i0 = (int)(L0 & 0xFFFFFFFFu), i1 = (int)(L1 & 0xFFFFFFFFu), i2 = (int)(L2 & 0xFFFFFFFFu);
  int i3 = (int)(L3 & 0xFFFFFFFFu), i4 = (int)(L4 & 0xFFFFFFFFu);
  if (lane < 18) {
    float np = 0.2f * (bufq[(size_t)i0 * 18 + lane] + bufq[(size_t)i1 * 18 + lane] +
                       bufq[(size_t)i2 * 18 + lane] + bufq[(size_t)i3 * 18 + lane] +
                       bufq[(size_t)i4 * 18 + lane]);
    const float* hr = hbuf + row * 256;
    float q = out_b[lane];
    for (int d = 0; d < 256; ++d) q += hr[d] * out_w[d * 18 + lane];
    qout[row * 18 + lane] = 0.5f * q + 0.5f * np;
  }
}

// ================= fallback (round-1 f32 path, unchanged) =================
__global__ __launch_bounds__(320) void conv1_k(
    const float* __restrict__ x, const float* __restrict__ w,
    const float* __restrict__ b, float* __restrict__ y) {
  __shared__ float x_s[4 * 84 * 84];
  int n = blockIdx.x;
  {
    const float4* src = (const float4*)(x + n * 28224);
    float4* dst = (float4*)x_s;
    for (int i = threadIdx.x; i < 7056; i += 320) dst[i] = src[i];
  }
  __syncthreads();
  int t = threadIdx.x;
  int ocg = t / 80, rem = t % 80, oy = rem / 4, oxg = rem % 4;
  float acc[8][5];
#pragma unroll
  for (int r = 0; r < 8; ++r) {
    float bv = b[ocg * 8 + r];
#pragma unroll
    for (int i = 0; i < 5; ++i) acc[r][i] = bv;
  }
  for (int ic = 0; ic < 4; ++ic) {
    for (int ky = 0; ky < 8; ++ky) {
      const float* xrow = x_s + ic * 7056 + (oy * 4 + ky) * 84 + oxg * 20;
      const float* wrow = w + ic * 64 + ky * 8;
#pragma unroll
      for (int kx = 0; kx < 8; ++kx) {
        float xv[5];
#pragma unroll
        for (int i = 0; i < 5; ++i) xv[i] = xrow[i * 4 + kx];
#pragma unroll
        for (int r = 0; r < 8; ++r) {
          float wv = wrow[(ocg * 8 + r) * 256 + kx];
#pragma unroll
          for (int i = 0; i < 5; ++i) acc[r][i] += wv * xv[i];
        }
      }
    }
  }
  float* yb = y + n * 12800 + oy * 20 + oxg * 5;
#pragma unroll
  for (int r = 0; r < 8; ++r)
#pragma unroll
    for (int i = 0; i < 5; ++i)
      yb[(ocg * 8 + r) * 400 + i] = fmaxf(acc[r][i], 0.f);
}

__global__ __launch_bounds__(256) void conv2_k(
    const float* __restrict__ h1, const float* __restrict__ w,
    const float* __restrict__ b, float* __restrict__ y) {
  __shared__ float x_s[32 * 400];
  int n = blockIdx.x;
  {
    const float4* src = (const float4*)(h1 + n * 12800);
    float4* dst = (float4*)x_s;
    for (int i = threadIdx.x; i < 3200; i += 256) dst[i] = src[i];
  }
  __syncthreads();
  int t = threadIdx.x;
  if (t < 216) {
    int ocg = t / 27, rem = t % 27, oy = rem / 3, oxg = rem % 3;
    float acc[8][3];
#pragma unroll
    for (int r = 0; r < 8; ++r) {
      float bv = b[ocg * 8 + r];
#pragma unroll
      for (int i = 0; i < 3; ++i) acc[r][i] = bv;
    }
    const float* xbase = x_s + (oy * 2) * 20 + oxg * 6;
    for (int ic = 0; ic < 32; ++ic) {
#pragma unroll
      for (int ky = 0; ky < 4; ++ky) {
        const float* xr = xbase + ic * 400 + ky * 20;
        const float* wr = w + ic * 16 + ky * 4;
#pragma unroll
        for (int kx = 0; kx < 4; ++kx) {
          float xv0 = xr[kx], xv1 = xr[kx + 2], xv2 = xr[kx + 4];
#pragma unroll
          for (int r = 0; r < 8; ++r) {
            float wv = wr[(ocg * 8 + r) * 512 + kx];
            acc[r][0] += wv * xv0;
            acc[r][1] += wv * xv1;
            acc[r][2] += wv * xv2;
          }
        }
      }
    }
    float* yb = y + n * 5184 + oy * 9 + oxg * 3;
#pragma unroll
    for (int r = 0; r < 8; ++r)
#pragma unroll
      for (int i = 0; i < 3; ++i)
        yb[(ocg * 8 + r) * 81 + i] = fmaxf(acc[r][i], 0.f);
  }
}

__global__ __launch_bounds__(128) void conv3_k(
    const float* __restrict__ h2, const float* __restrict__ w,
    const float* __restrict__ b, float* __restrict__ y) {
  __shared__ float x_s[64 * 81];
  int n = blockIdx.x;
  {
    const float4* src = (const float4*)(h2 + n * 5184);
    float4* dst = (float4*)x_s;
    for (int i = threadIdx.x; i < 1296; i += 128) dst[i] = src[i];
  }
  __syncthreads();
  int t = threadIdx.x;
  if (t < 112) {
    int ocg = t / 7, oy = t % 7;
    float acc[4][7];
#pragma unroll
    for (int r = 0; r < 4; ++r) {
      float bv = b[ocg * 4 + r];
#pragma unroll
      for (int i = 0; i < 7; ++i) acc[r][i] = bv;
    }
    for (int ic = 0; ic < 64; ++ic) {
#pragma unroll
      for (int ky = 0; ky < 3; ++ky) {
        const float* xr = x_s + ic * 81 + (oy + ky) * 9;
        float xv[9];
#pragma unroll
        for (int i = 0; i < 9; ++i) xv[i] = xr[i];
        const float* wr = w + ic * 9 + ky * 3;
#pragma unroll
        for (int kx = 0; kx < 3; ++kx) {
#pragma unroll
          for (int r = 0; r < 4; ++r) {
            float wv = wr[(ocg * 4 + r) * 576 + kx];
#pragma unroll
            for (int i = 0; i < 7; ++i) acc[r][i] += wv * xv[i + kx];
          }
        }
      }
    }
    float* yb = y + n * 3136 + oy * 7;
#pragma unroll
    for (int r = 0; r < 4; ++r)
#pragma unroll
      for (int i = 0; i < 7; ++i)
        yb[(ocg * 4 + r) * 49 + i] = fmaxf(acc[r][i], 0.f);
  }
}

__global__ __launch_bounds__(256) void fc_k(
    const float* __restrict__ h3, const float* __restrict__ fw,
    const float* __restrict__ fb, float* __restrict__ hout,
    unsigned short* __restrict__ a_split) {
  __shared__ float a_s[4 * 3136];
  int n0 = blockIdx.x * 4;
  {
    const float4* src = (const float4*)(h3 + n0 * 3136);
    float4* dst = (float4*)a_s;
    for (int i = threadIdx.x; i < 3136; i += 256) dst[i] = src[i];
  }
  __syncthreads();
  int j = threadIdx.x;
  float a0 = fb[j], a1 = a0, a2 = a0, a3 = a0;
  for (int k = 0; k < 3136; ++k) {
    float wv = fw[k * 256 + j];
    a0 += a_s[k] * wv;
    a1 += a_s[3136 + k] * wv;
    a2 += a_s[2 * 3136 + k] * wv;
    a3 += a_s[3 * 3136 + k] * wv;
  }
  float hv[4];
  hv[0] = fmaxf(a0, 0.f); hv[1] = fmaxf(a1, 0.f);
  hv[2] = fmaxf(a2, 0.f); hv[3] = fmaxf(a3, 0.f);
#pragma unroll
  for (int r = 0; r < 4; ++r) {
    hout[(n0 + r) * 256 + j] = hv[r];
    if (a_split) {
      unsigned short hi = f2bf_rne(hv[r]);
      unsigned short lo = f2bf_rne(hv[r] - bf2f(hi));
      a_split[(size_t)(n0 + r) * 768 + j] = hi;
      a_split[(size_t)(n0 + r) * 768 + 256 + j] = hi;
      a_split[(size_t)(n0 + r) * 768 + 512 + j] = lo;
    }
  }
}

__global__ __launch_bounds__(256) void norm_k(const float* __restrict__ e,
                                              float* __restrict__ nrm) {
  int row = blockIdx.x * 4 + (threadIdx.x >> 6);
  if (row >= 50000) return;
  int lane = threadIdx.x & 63;
  float4 v = ((const float4*)(e + row * 256))[lane];
  float s = v.x * v.x + v.y * v.y + v.z * v.z + v.w * v.w;
  for (int off = 32; off > 0; off >>= 1) s += __shfl_down(s, off);
  if (lane == 0) nrm[row] = s;
}

__global__ __launch_bounds__(256) void dist_topk_k(
    const float* __restrict__ hbuf, const float* __restrict__ emb,
    const float* __restrict__ nrm, float* __restrict__ cand_d,
    int* __restrict__ cand_i) {
  __shared__ float a_s[16 * 256];
  __shared__ float b_s[512 * 17];
  int rb = blockIdx.x & 31, cb = blockIdx.x >> 5;
  int t = threadIdx.x;
  {
    const float4* src = (const float4*)(hbuf + rb * 16 * 256);
    float4* dst = (float4*)a_s;
    for (int i = t; i < 1024; i += 256) dst[i] = src[i];
  }
  float acc[8][4];
#pragma unroll
  for (int r = 0; r < 8; ++r)
#pragma unroll
    for (int c = 0; c < 4; ++c) acc[r][c] = 0.f;
  int ct = t & 127, rt = t >> 7;
  for (int kb = 0; kb < 256; kb += 16) {
    __syncthreads();
    for (int i = t; i < 2048; i += 256) {
      int j = i >> 2, kq = i & 3;
      int jg = cb * 512 + j;
      float4 v = make_float4(0.f, 0.f, 0.f, 0.f);
      if (jg < 50000) v = *(const float4*)(emb + jg * 256 + kb + kq * 4);
      float* dst = b_s + j * 17 + kq * 4;
      dst[0] = v.x; dst[1] = v.y; dst[2] = v.z; dst[3] = v.w;
    }
    __syncthreads();
#pragma unroll
    for (int k = 0; k < 16; ++k) {
      float av[8];
#pragma unroll
      for (int r = 0; r < 8; ++r) av[r] = a_s[(rt * 8 + r) * 256 + kb + k];
#pragma unroll
      for (int cc = 0; cc < 4; ++cc) {
        float bv = b_s[(ct + cc * 128) * 17 + k];
#pragma unroll
        for (int r = 0; r < 8; ++r) acc[r][cc] += av[r] * bv;
      }
    }
  }
  __syncthreads();
  float* score = b_s;
#pragma unroll
  for (int cc = 0; cc < 4; ++cc) {
    int c = ct + cc * 128;
    int jg = cb * 512 + c;
    float nv = (jg < 50000) ? nrm[jg] : 0.f;
#pragma unroll
    for (int r = 0; r < 8; ++r)
      score[(rt * 8 + r) * 512 + c] = (jg < 50000) ? (nv - 2.f * acc[r][cc]) : FINF;
  }
  __syncthreads();
  int wave = t >> 6, lane = t & 63;
  for (int rr = 0; rr < 4; ++rr) {
    int r = wave * 4 + rr;
    float v[8];
#pragma unroll
    for (int i = 0; i < 8; ++i) v[i] = score[r * 512 + lane + i * 64];
    for (int it = 0; it < 5; ++it) {
      float bv = v[0];
      int bc = lane;
#pragma unroll
      for (int i = 1; i < 8; ++i) {
        float xv = v[i];
        int c = lane + i * 64;
        if (xv < bv) { bv = xv; bc = c; }
      }
      for (int off = 32; off > 0; off >>= 1) {
        float ov = __shfl_down(bv, off);
        int ocx = __shfl_down(bc, off);
        if (ov < bv || (ov == bv && ocx < bc)) { bv = ov; bc = ocx; }
      }
      bv = __shfl(bv, 0);
      bc = __shfl(bc, 0);
      if (lane == 0) {
        int row_g = rb * 16 + r;
        int slot = (row_g * 98 + cb) * 5 + it;
        cand_d[slot] = bv;
        cand_i[slot] = cb * 512 + bc;
      }
#pragma unroll
      for (int i = 0; i < 8; ++i)
        if (lane + i * 64 == bc) v[i] = FINF;
    }
  }
}

__global__ __launch_bounds__(64) void merge_k(
    const float* __restrict__ cand_d, const int* __restrict__ cand_i,
    const float* __restrict__ hbuf, const float* __restrict__ bufq,
    const float* __restrict__ out_w, const float* __restrict__ out_b,
    float* __restrict__ qout) {
  int row = blockIdx.x, lane = threadIdx.x;
  __shared__ float sd[490];
  __shared__ int si[490];
  __shared__ int win[5];
  for (int i = lane; i < 490; i += 64) {
    sd[i] = cand_d[row * 490 + i];
    si[i] = cand_i[row * 490 + i];
  }
  __syncthreads();
  float v[8];
  int ix[8];
#pragma unroll
  for (int i = 0; i < 8; ++i) {
    int s = lane + i * 64;
    v[i] = (s < 490) ? sd[s] : FINF;
    ix[i] = (s < 490) ? si[s] : 0x7fffffff;
  }
  for (int it = 0; it < 5; ++it) {
    float bv = v[0];
    int bi = ix[0];
#pragma unroll
    for (int i = 1; i < 8; ++i)
      if (v[i] < bv || (v[i] == bv && ix[i] < bi)) { bv = v[i]; bi = ix[i]; }
    for (int off = 32; off > 0; off >>= 1) {
      float ov = __shfl_down(bv, off);
      int oi = __shfl_down(bi, off);
      if (ov < bv || (ov == bv && oi < bi)) { bv = ov; bi = oi; }
    }
    bi = __shfl(bi, 0);
    if (lane == 0) win[it] = bi;
#pragma unroll
    for (int i = 0; i < 8; ++i)
      if (ix[i] == bi) v[i] = FINF;
  }
  __syncthreads();
  if (lane < 18) {
    float np = 0.f;
#pragma unroll
    for (int it = 0; it < 5; ++it) np += bufq[win[it] * 18 + lane];
    np *= 0.2f;
    const float* hr = hbuf + row * 256;
    float q = out_b[lane];
    for (int d = 0; d < 256; ++d) q += hr[d] * out_w[d * 18 + lane];
    qout[row * 18 + lane] = 0.5f * q + 0.5f * np;
  }
}

extern "C" void kernel_launch(void* const* d_in, const int* in_sizes, int n_in,
                              void* d_out, int out_size, void* d_ws, size_t ws_size,
                              hipStream_t stream) {
  const float* x       = (const float*)d_in[0];
  const float* conv1_w = (const float*)d_in[1];
  const float* conv1_b = (const float*)d_in[2];
  const float* conv2_w = (const float*)d_in[3];
  const float* conv2_b = (const float*)d_in[4];
  const float* conv3_w = (const float*)d_in[5];
  const float* conv3_b = (const float*)d_in[6];
  const float* fc_w    = (const float*)d_in[7];
  const float* fc_b    = (const float*)d_in[8];
  const float* out_w   = (const float*)d_in[9];
  const float* out_b   = (const float*)d_in[10];
  const float* buf_emb = (const float*)d_in[11];
  const float* buf_q   = (const float*)d_in[12];

  float* out = (float*)d_out;  // [0,9216): q_blend; [9216,...): h
  float* hout = out + 9216;

  float* ws = (float*)d_ws;
  // mfma-path layout (float offsets into ws)
  unsigned short* h1s  = (unsigned short*)(ws);               // [0, 6,553,600 f)
  unsigned short* h2s  = (unsigned short*)(ws + 6553600);     // [6,553,600, 9,207,808 f)
  unsigned short* h3hi = (unsigned short*)(ws);               // reuses dead h1 region
  unsigned short* h3lo = (unsigned short*)(ws + 802816);
  unsigned short* Bs1h = (unsigned short*)(ws + 6553600);     // in h2s region (dead until conv2m)
  unsigned short* Bs1l = (unsigned short*)(ws + 6557696);
  float* nrm = ws + 9207808;                                  // [9,207,808, 9,257,984 f)
  unsigned long long* cand = (unsigned long long*)(ws + 9257984);  // [9,257,984, 13,272,064 f)
  // overlays inside cand region (dead before dist3 writes cand):
  unsigned short* Bs2h = (unsigned short*)(ws + 9257984);
  unsigned short* Bs2l = (unsigned short*)(ws + 9274368);
  unsigned short* Bs3h = (unsigned short*)(ws + 9290752);
  unsigned short* Bs3l = (unsigned short*)(ws + 9309184);     // ends 9,327,616 f
  unsigned short* fwhi = (unsigned short*)(ws + 9327616);
  unsigned short* fwlo = (unsigned short*)(ws + 9729024);     // ends 10,130,432 f
  float* hpre = ws + 10130432;
  unsigned short* a_split = (unsigned short*)(ws + 13272064);
  unsigned short* Bemb = (unsigned short*)(ws + 13468672);    // ends 26,313,728 f
  const size_t NEED = 105254912ull;

  bool mfma_path = (ws_size >= NEED);

  if (mfma_path) {
    w1swz_k<<<8, 128, 0, stream>>>(conv1_w, Bs1h, Bs1l);
    w2swz_k<<<16, 256, 0, stream>>>(conv2_w, Bs2h, Bs2l);
    w3swz_k<<<18, 256, 0, stream>>>(conv3_w, Bs3h, Bs3l);
    fcwcvt_k<<<dim3(49, 4), 256, 0, stream>>>(fc_w, fwhi, fwlo);
    embcvt_k<<<12500, 256, 0, stream>>>(buf_emb, Bemb, nrm);
    conv1m_k<<<800, 256, 0, stream>>>(x, Bs1h, Bs1l, conv1_b, h1s);
    conv2m_k<<<162, 256, 0, stream>>>(h1s, Bs2h, Bs2l, conv2_b, h2s);
    conv3m_k<<<98, 256, 0, stream>>>(h2s, Bs3h, Bs3l, conv3_b, h3hi, h3lo);
    fc2_k<<<112, 256, 0, stream>>>(h3hi, h3lo, fwhi, fwlo, hpre);
    fc_post_k<<<512, 256, 0, stream>>>(hpre, fc_b, hout, a_split);
    dist3_k<<<1568, 256, 0, stream>>>(a_split, Bemb, nrm, cand);
    merge2_k<<<512, 64, 0, stream>>>(cand, hout, buf_q, out_w, out_b, out);
  } else {
    // round-1 f32 fallback
    float* h1 = ws;
    float* h2 = h1 + 6553600;
    float* h3 = ws;
    float* nrm_o = h2 + 2654208;
    float* cand_d = nrm_o + 50000;
    int* cand_i = (int*)(cand_d + 250880);
    conv1_k<<<512, 320, 0, stream>>>(x, conv1_w, conv1_b, h1);
    conv2_k<<<512, 256, 0, stream>>>(h1, conv2_w, conv2_b, h2);
    conv3_k<<<512, 128, 0, stream>>>(h2, conv3_w, conv3_b, h3);
    fc_k<<<128, 256, 0, stream>>>(h3, fc_w, fc_b, hout, nullptr);
    norm_k<<<12500, 256, 0, stream>>>(buf_emb, nrm_o);
    dist_topk_k<<<3136, 256, 0, stream>>>(hout, buf_emb, nrm_o, cand_d, cand_i);
    merge_k<<<512, 64, 0, stream>>>(cand_d, cand_i, hout, buf_q, out_w, out_b, out);
  }
}

// Round 18
// 251.258 us; speedup vs baseline: 1.2190x; 1.2190x over previous
//
#include <hip/hip_runtime.h>
#include <hip/hip_bf16.h>

#define FINF 3.402823466e38f

typedef short bf16x8 __attribute__((ext_vector_type(8)));
typedef float f32x4 __attribute__((ext_vector_type(4)));

__device__ __forceinline__ unsigned short f2bf_rne(float f) {
  unsigned u = __float_as_uint(f);
  unsigned r = u + 0x7fff + ((u >> 16) & 1);
  return (unsigned short)(r >> 16);
}
__device__ __forceinline__ float bf2f(unsigned short u) {
  return __uint_as_float(((unsigned)u) << 16);
}
__device__ __forceinline__ unsigned long long shflx64(unsigned long long v, int m) {
  unsigned lo = __shfl_xor((unsigned)(v & 0xFFFFFFFFu), m, 64);
  unsigned hi = __shfl_xor((unsigned)(v >> 32), m, 64);
  return (((unsigned long long)hi) << 32) | lo;
}
// raw barrier: waits LDS ops only, leaves global prefetches in flight
__device__ __forceinline__ void lds_barrier() {
  asm volatile("s_waitcnt lgkmcnt(0)" ::: "memory");
  __builtin_amdgcn_s_barrier();
  __builtin_amdgcn_sched_barrier(0);
}
// wave-local LDS sync: ds_write -> ds_read within ONE wave needs only lgkmcnt,
// no s_barrier (rule #18: sched_barrier stops MFMA hoisting past the wait)
__device__ __forceinline__ void wave_sync() {
  asm volatile("s_waitcnt lgkmcnt(0)" ::: "memory");
  __builtin_amdgcn_sched_barrier(0);
}
// async global->LDS, 16B per lane; LDS dest = uniform base + lane*16
__device__ __forceinline__ void gload16(const unsigned short* g, short* l) {
  __builtin_amdgcn_global_load_lds(
      (const __attribute__((address_space(1))) unsigned int*)g,
      (__attribute__((address_space(3))) unsigned int*)l, 16, 0, 0);
}

// ---------------- w1swz: conv1_w [32,4,8,8] -> B frags [ky8][nf2][64][8] hi/lo ----------------
__global__ __launch_bounds__(128) void w1swz_k(const float* __restrict__ w1,
                                               unsigned short* __restrict__ bh,
                                               unsigned short* __restrict__ bl) {
  int ky = blockIdx.x;
  int t = threadIdx.x, nf = t >> 6, l = t & 63;
  int oc = nf * 16 + (l & 15), ic = l >> 4;
  bf16x8 hv, lv;
#pragma unroll
  for (int j = 0; j < 8; ++j) {
    float v = w1[((oc * 4 + ic) * 8 + ky) * 8 + j];
    unsigned short h = f2bf_rne(v);
    hv[j] = (short)h;
    lv[j] = (short)f2bf_rne(v - bf2f(h));
  }
  *(bf16x8*)(&bh[((size_t)(ky * 2 + nf) * 64 + l) * 8]) = hv;
  *(bf16x8*)(&bl[((size_t)(ky * 2 + nf) * 64 + l) * 8]) = lv;
}

// ---------------- conv1m: x f32 -> h1s NHWC [204800 pix][32hi|32lo], 8-tap MFMA ----------------
// LDS is wave-local (wave w writes rows w*64+lane, reads rows w*64+mf*16+lm) -> no barriers.
__global__ __launch_bounds__(256) void conv1m_k(
    const float* __restrict__ x,
    const unsigned short* __restrict__ bh, const unsigned short* __restrict__ bl,
    const float* __restrict__ bias, unsigned short* __restrict__ h1s) {
  __shared__ short As[256 * 72];  // row*72: [0,32)=hi (4ic x 8kx), [36,68)=lo
  int t = threadIdx.x, w = t >> 6, lane = t & 63, lm = lane & 15, hi4 = lane >> 4;
  int m = blockIdx.x * 256 + t;
  int n = m / 400, p = m % 400, oy = p / 20, ox = p % 20;
  size_t xoff = (size_t)n * 28224 + (size_t)(oy * 4) * 84 + ox * 4;  // + ic*7056 + ky*84
  f32x4 acc[4][2];
#pragma unroll
  for (int mf = 0; mf < 4; ++mf)
#pragma unroll
    for (int nf = 0; nf < 2; ++nf) acc[mf][nf] = (f32x4){0.f, 0.f, 0.f, 0.f};

  float4 fa[8];  // current tap: [ic*2 + half]
#pragma unroll
  for (int ic = 0; ic < 4; ++ic) {
    fa[ic * 2 + 0] = *(const float4*)(x + xoff + ic * 7056);
    fa[ic * 2 + 1] = *(const float4*)(x + xoff + ic * 7056 + 4);
  }
  const unsigned short* bfp = bh + (size_t)lane * 8;
  const unsigned short* blp = bl + (size_t)lane * 8;
  bf16x8 cbh[2], cbl[2];
#pragma unroll
  for (int nf = 0; nf < 2; ++nf) {
    cbh[nf] = *(const bf16x8*)(bfp + nf * 512);
    cbl[nf] = *(const bf16x8*)(blp + nf * 512);
  }
#pragma unroll
  for (int ky = 0; ky < 8; ++ky) {
    if (ky) wave_sync();  // own-wave reads of previous tap done
    {
      short* wp = &As[t * 72];
#pragma unroll
      for (int ic = 0; ic < 4; ++ic) {
        float e0 = fa[ic * 2].x, e1 = fa[ic * 2].y, e2 = fa[ic * 2].z, e3 = fa[ic * 2].w;
        float e4 = fa[ic * 2 + 1].x, e5 = fa[ic * 2 + 1].y, e6 = fa[ic * 2 + 1].z, e7 = fa[ic * 2 + 1].w;
        bf16x8 hv, lv;
        unsigned short h;
        h = f2bf_rne(e0); hv[0] = (short)h; lv[0] = (short)f2bf_rne(e0 - bf2f(h));
        h = f2bf_rne(e1); hv[1] = (short)h; lv[1] = (short)f2bf_rne(e1 - bf2f(h));
        h = f2bf_rne(e2); hv[2] = (short)h; lv[2] = (short)f2bf_rne(e2 - bf2f(h));
        h = f2bf_rne(e3); hv[3] = (short)h; lv[3] = (short)f2bf_rne(e3 - bf2f(h));
        h = f2bf_rne(e4); hv[4] = (short)h; lv[4] = (short)f2bf_rne(e4 - bf2f(h));
        h = f2bf_rne(e5); hv[5] = (short)h; lv[5] = (short)f2bf_rne(e5 - bf2f(h));
        h = f2bf_rne(e6); hv[6] = (short)h; lv[6] = (short)f2bf_rne(e6 - bf2f(h));
        h = f2bf_rne(e7); hv[7] = (short)h; lv[7] = (short)f2bf_rne(e7 - bf2f(h));
        *(bf16x8*)(wp + ic * 8) = hv;
        *(bf16x8*)(wp + 36 + ic * 8) = lv;
      }
    }
    wave_sync();  // own writes visible to own reads
    bf16x8 nbh[2], nbl[2];
    if (ky < 7) {
      size_t ap = xoff + (size_t)(ky + 1) * 84;
#pragma unroll
      for (int ic = 0; ic < 4; ++ic) {
        fa[ic * 2 + 0] = *(const float4*)(x + ap + ic * 7056);
        fa[ic * 2 + 1] = *(const float4*)(x + ap + ic * 7056 + 4);
      }
#pragma unroll
      for (int nf = 0; nf < 2; ++nf) {
        nbh[nf] = *(const bf16x8*)(bfp + ((ky + 1) * 2 + nf) * 512);
        nbl[nf] = *(const bf16x8*)(blp + ((ky + 1) * 2 + nf) * 512);
      }
    }
    bf16x8 ah[4], al[4];
#pragma unroll
    for (int mf = 0; mf < 4; ++mf) {
      const short* rp = &As[(w * 64 + mf * 16 + lm) * 72 + hi4 * 8];
      ah[mf] = *(const bf16x8*)(rp);
      al[mf] = *(const bf16x8*)(rp + 36);
    }
#pragma unroll
    for (int mf = 0; mf < 4; ++mf)
#pragma unroll
      for (int nf = 0; nf < 2; ++nf) {
        acc[mf][nf] = __builtin_amdgcn_mfma_f32_16x16x32_bf16(ah[mf], cbh[nf], acc[mf][nf], 0, 0, 0);
        acc[mf][nf] = __builtin_amdgcn_mfma_f32_16x16x32_bf16(ah[mf], cbl[nf], acc[mf][nf], 0, 0, 0);
        acc[mf][nf] = __builtin_amdgcn_mfma_f32_16x16x32_bf16(al[mf], cbh[nf], acc[mf][nf], 0, 0, 0);
      }
    if (ky < 7) {
#pragma unroll
      for (int nf = 0; nf < 2; ++nf) { cbh[nf] = nbh[nf]; cbl[nf] = nbl[nf]; }
    }
  }
  float bv[2];
#pragma unroll
  for (int nf = 0; nf < 2; ++nf) bv[nf] = bias[nf * 16 + lm];
#pragma unroll
  for (int mf = 0; mf < 4; ++mf)
#pragma unroll
    for (int nf = 0; nf < 2; ++nf)
#pragma unroll
      for (int r = 0; r < 4; ++r) {
        size_t mrow = (size_t)blockIdx.x * 256 + w * 64 + mf * 16 + hi4 * 4 + r;
        float v = fmaxf(acc[mf][nf][r] + bv[nf], 0.f);
        unsigned short h = f2bf_rne(v);
        h1s[mrow * 64 + nf * 16 + lm] = h;
        h1s[mrow * 64 + 32 + nf * 16 + lm] = f2bf_rne(v - bf2f(h));
      }
}

// ---------------- w2swz: conv2_w -> MFMA B-frag layout hi/lo [tap16][nf4][64][8] ----------------
__global__ __launch_bounds__(256) void w2swz_k(const float* __restrict__ w2,
                                               unsigned short* __restrict__ bh,
                                               unsigned short* __restrict__ bl) {
  int tap = blockIdx.x, ky = tap >> 2, kx = tap & 3;
  int t = threadIdx.x, nf = t >> 6, l = t & 63;
  int oc = nf * 16 + (l & 15);
  bf16x8 hv, lv;
#pragma unroll
  for (int j = 0; j < 8; ++j) {
    int ic = (l >> 4) * 8 + j;
    float v = w2[((oc * 32 + ic) * 4 + ky) * 4 + kx];
    unsigned short h = f2bf_rne(v);
    hv[j] = (short)h;
    lv[j] = (short)f2bf_rne(v - bf2f(h));
  }
  *(bf16x8*)(&bh[((size_t)(tap * 4 + nf) * 64 + l) * 8]) = hv;
  *(bf16x8*)(&bl[((size_t)(tap * 4 + nf) * 64 + l) * 8]) = lv;
}

// ---------------- w3swz: conv3_w -> [tt18][nf4][64][8] (tt = tap*2+half) ----------------
__global__ __launch_bounds__(256) void w3swz_k(const float* __restrict__ w3,
                                               unsigned short* __restrict__ bh,
                                               unsigned short* __restrict__ bl) {
  int tt = blockIdx.x, tap = tt >> 1, half = tt & 1, ky = tap / 3, kx = tap % 3;
  int t = threadIdx.x, nf = t >> 6, l = t & 63;
  int oc = nf * 16 + (l & 15);
  bf16x8 hv, lv;
#pragma unroll
  for (int j = 0; j < 8; ++j) {
    int ic = half * 32 + (l >> 4) * 8 + j;
    float v = w3[((oc * 64 + ic) * 3 + ky) * 3 + kx];
    unsigned short h = f2bf_rne(v);
    hv[j] = (short)h;
    lv[j] = (short)f2bf_rne(v - bf2f(h));
  }
  *(bf16x8*)(&bh[((size_t)(tt * 4 + nf) * 64 + l) * 8]) = hv;
  *(bf16x8*)(&bl[((size_t)(tt * 4 + nf) * 64 + l) * 8]) = lv;
}

// ---------------- conv2m: h1s NHWC -> h2s [41472 pix][64hi|64lo], 16-tap MFMA, wave-local LDS ----------------
__global__ __launch_bounds__(256) void conv2m_k(
    const unsigned short* __restrict__ h1s, const unsigned short* __restrict__ bh,
    const unsigned short* __restrict__ bl, const float* __restrict__ bias,
    unsigned short* __restrict__ h2s) {
  __shared__ short As[256 * 72];
  int t = threadIdx.x, w = t >> 6, lane = t & 63, lm = lane & 15, hi4 = lane >> 4;
  int m = blockIdx.x * 256 + t;
  int n = m / 81, p = m % 81, oy = p / 9, ox = p % 9;
  const unsigned short* abase = h1s + (size_t)(n * 400 + oy * 40 + ox * 2) * 64;
  f32x4 acc[4][4];
#pragma unroll
  for (int mf = 0; mf < 4; ++mf)
#pragma unroll
    for (int nf = 0; nf < 4; ++nf) acc[mf][nf] = (f32x4){0.f, 0.f, 0.f, 0.f};

  bf16x8 s0, s1, s2, s3, s4, s5, s6, s7;
  {
    const unsigned short* ap = abase;  // tap 0
    s0 = *(const bf16x8*)(ap);      s1 = *(const bf16x8*)(ap + 8);
    s2 = *(const bf16x8*)(ap + 16); s3 = *(const bf16x8*)(ap + 24);
    s4 = *(const bf16x8*)(ap + 32); s5 = *(const bf16x8*)(ap + 40);
    s6 = *(const bf16x8*)(ap + 48); s7 = *(const bf16x8*)(ap + 56);
  }
  const unsigned short* bfp = bh + (size_t)lane * 8;
  const unsigned short* blp = bl + (size_t)lane * 8;
  bf16x8 cbh[4], cbl[4];
#pragma unroll
  for (int nf = 0; nf < 4; ++nf) {
    cbh[nf] = *(const bf16x8*)(bfp + nf * 512);
    cbl[nf] = *(const bf16x8*)(blp + nf * 512);
  }
#pragma unroll
  for (int tap = 0; tap < 16; ++tap) {
    if (tap) wave_sync();
    {
      short* wp = &As[t * 72];
      *(bf16x8*)(wp) = s0;      *(bf16x8*)(wp + 8) = s1;
      *(bf16x8*)(wp + 16) = s2; *(bf16x8*)(wp + 24) = s3;
      *(bf16x8*)(wp + 36) = s4; *(bf16x8*)(wp + 44) = s5;
      *(bf16x8*)(wp + 52) = s6; *(bf16x8*)(wp + 60) = s7;
    }
    wave_sync();
    bf16x8 nbh[4], nbl[4];
    if (tap < 15) {
      const unsigned short* ap = abase + (((tap + 1) >> 2) * 1280 + ((tap + 1) & 3) * 64);
      s0 = *(const bf16x8*)(ap);      s1 = *(const bf16x8*)(ap + 8);
      s2 = *(const bf16x8*)(ap + 16); s3 = *(const bf16x8*)(ap + 24);
      s4 = *(const bf16x8*)(ap + 32); s5 = *(const bf16x8*)(ap + 40);
      s6 = *(const bf16x8*)(ap + 48); s7 = *(const bf16x8*)(ap + 56);
#pragma unroll
      for (int nf = 0; nf < 4; ++nf) {
        nbh[nf] = *(const bf16x8*)(bfp + ((tap + 1) * 4 + nf) * 512);
        nbl[nf] = *(const bf16x8*)(blp + ((tap + 1) * 4 + nf) * 512);
      }
    }
    bf16x8 ah[4], al[4];
#pragma unroll
    for (int mf = 0; mf < 4; ++mf) {
      const short* rp = &As[(w * 64 + mf * 16 + lm) * 72 + hi4 * 8];
      ah[mf] = *(const bf16x8*)(rp);
      al[mf] = *(const bf16x8*)(rp + 36);
    }
#pragma unroll
    for (int mf = 0; mf < 4; ++mf)
#pragma unroll
      for (int nf = 0; nf < 4; ++nf) {
        acc[mf][nf] = __builtin_amdgcn_mfma_f32_16x16x32_bf16(ah[mf], cbh[nf], acc[mf][nf], 0, 0, 0);
        acc[mf][nf] = __builtin_amdgcn_mfma_f32_16x16x32_bf16(ah[mf], cbl[nf], acc[mf][nf], 0, 0, 0);
        acc[mf][nf] = __builtin_amdgcn_mfma_f32_16x16x32_bf16(al[mf], cbh[nf], acc[mf][nf], 0, 0, 0);
      }
    if (tap < 15) {
#pragma unroll
      for (int nf = 0; nf < 4; ++nf) { cbh[nf] = nbh[nf]; cbl[nf] = nbl[nf]; }
    }
  }
  float bv[4];
#pragma unroll
  for (int nf = 0; nf < 4; ++nf) bv[nf] = bias[nf * 16 + lm];
#pragma unroll
  for (int mf = 0; mf < 4; ++mf)
#pragma unroll
    for (int nf = 0; nf < 4; ++nf)
#pragma unroll
      for (int r = 0; r < 4; ++r) {
        size_t mrow = (size_t)blockIdx.x * 256 + w * 64 + mf * 16 + hi4 * 4 + r;
        float v = fmaxf(acc[mf][nf][r] + bv[nf], 0.f);
        unsigned short h = f2bf_rne(v);
        h2s[mrow * 128 + nf * 16 + lm] = h;
        h2s[mrow * 128 + 64 + nf * 16 + lm] = f2bf_rne(v - bf2f(h));
      }
}

// ---------------- conv3m: h2s -> h3hi/h3lo [25088 pix][64], 18-chunk MFMA, wave-local LDS ----------------
__global__ __launch_bounds__(256) void conv3m_k(
    const unsigned short* __restrict__ h2s, const unsigned short* __restrict__ bh,
    const unsigned short* __restrict__ bl, const float* __restrict__ bias,
    unsigned short* __restrict__ h3hi, unsigned short* __restrict__ h3lo) {
  __shared__ short As[256 * 72];
  int t = threadIdx.x, w = t >> 6, lane = t & 63, lm = lane & 15, hi4 = lane >> 4;
  int m = blockIdx.x * 256 + t;
  int n = m / 49, p = m % 49, oy = p / 7, ox = p % 7;
  const unsigned short* abase = h2s + (size_t)(n * 81 + oy * 9 + ox) * 128;
  f32x4 acc[4][4];
#pragma unroll
  for (int mf = 0; mf < 4; ++mf)
#pragma unroll
    for (int nf = 0; nf < 4; ++nf) acc[mf][nf] = (f32x4){0.f, 0.f, 0.f, 0.f};

  bf16x8 s0, s1, s2, s3, s4, s5, s6, s7;
  {
    const unsigned short* ap = abase;
    s0 = *(const bf16x8*)(ap);      s1 = *(const bf16x8*)(ap + 8);
    s2 = *(const bf16x8*)(ap + 16); s3 = *(const bf16x8*)(ap + 24);
    s4 = *(const bf16x8*)(ap + 64); s5 = *(const bf16x8*)(ap + 72);
    s6 = *(const bf16x8*)(ap + 80); s7 = *(const bf16x8*)(ap + 88);
  }
  const unsigned short* bfp = bh + (size_t)lane * 8;
  const unsigned short* blp = bl + (size_t)lane * 8;
  bf16x8 cbh[4], cbl[4];
#pragma unroll
  for (int nf = 0; nf < 4; ++nf) {
    cbh[nf] = *(const bf16x8*)(bfp + nf * 512);
    cbl[nf] = *(const bf16x8*)(blp + nf * 512);
  }
#pragma unroll
  for (int tt = 0; tt < 18; ++tt) {
    if (tt) wave_sync();
    {
      short* wp = &As[t * 72];
      *(bf16x8*)(wp) = s0;      *(bf16x8*)(wp + 8) = s1;
      *(bf16x8*)(wp + 16) = s2; *(bf16x8*)(wp + 24) = s3;
      *(bf16x8*)(wp + 36) = s4; *(bf16x8*)(wp + 44) = s5;
      *(bf16x8*)(wp + 52) = s6; *(bf16x8*)(wp + 60) = s7;
    }
    wave_sync();
    bf16x8 nbh[4], nbl[4];
    if (tt < 17) {
      const int tn = tt + 1, tapn = tn >> 1, halfn = tn & 1;
      const unsigned short* ap = abase + ((tapn / 3) * 9 + (tapn % 3)) * 128 + halfn * 32;
      s0 = *(const bf16x8*)(ap);      s1 = *(const bf16x8*)(ap + 8);
      s2 = *(const bf16x8*)(ap + 16); s3 = *(const bf16x8*)(ap + 24);
      s4 = *(const bf16x8*)(ap + 64); s5 = *(const bf16x8*)(ap + 72);
      s6 = *(const bf16x8*)(ap + 80); s7 = *(const bf16x8*)(ap + 88);
#pragma unroll
      for (int nf = 0; nf < 4; ++nf) {
        nbh[nf] = *(const bf16x8*)(bfp + ((tt + 1) * 4 + nf) * 512);
        nbl[nf] = *(const bf16x8*)(blp + ((tt + 1) * 4 + nf) * 512);
      }
    }
    bf16x8 ah[4], al[4];
#pragma unroll
    for (int mf = 0; mf < 4; ++mf) {
      const short* rp = &As[(w * 64 + mf * 16 + lm) * 72 + hi4 * 8];
      ah[mf] = *(const bf16x8*)(rp);
      al[mf] = *(const bf16x8*)(rp + 36);
    }
#pragma unroll
    for (int mf = 0; mf < 4; ++mf)
#pragma unroll
      for (int nf = 0; nf < 4; ++nf) {
        acc[mf][nf] = __builtin_amdgcn_mfma_f32_16x16x32_bf16(ah[mf], cbh[nf], acc[mf][nf], 0, 0, 0);
        acc[mf][nf] = __builtin_amdgcn_mfma_f32_16x16x32_bf16(ah[mf], cbl[nf], acc[mf][nf], 0, 0, 0);
        acc[mf][nf] = __builtin_amdgcn_mfma_f32_16x16x32_bf16(al[mf], cbh[nf], acc[mf][nf], 0, 0, 0);
      }
    if (tt < 17) {
#pragma unroll
      for (int nf = 0; nf < 4; ++nf) { cbh[nf] = nbh[nf]; cbl[nf] = nbl[nf]; }
    }
  }
  float bv[4];
#pragma unroll
  for (int nf = 0; nf < 4; ++nf) bv[nf] = bias[nf * 16 + lm];
#pragma unroll
  for (int mf = 0; mf < 4; ++mf)
#pragma unroll
    for (int nf = 0; nf < 4; ++nf)
#pragma unroll
      for (int r = 0; r < 4; ++r) {
        size_t mrow = (size_t)blockIdx.x * 256 + w * 64 + mf * 16 + hi4 * 4 + r;
        float v = fmaxf(acc[mf][nf][r] + bv[nf], 0.f);
        unsigned short h = f2bf_rne(v);
        h3hi[mrow * 64 + nf * 16 + lm] = h;
        h3lo[mrow * 64 + nf * 16 + lm] = f2bf_rne(v - bf2f(h));
      }
}

// ---------------- fcwcvt: fc_w [3136,256] -> fwhi/fwlo [256][3136] bf16, k' = p*64+c ----------------
__global__ __launch_bounds__(256) void fcwcvt_k(const float* __restrict__ fw,
                                                unsigned short* __restrict__ fwhi,
                                                unsigned short* __restrict__ fwlo) {
  __shared__ float tile[64][65];
  int p = blockIdx.x, nb = blockIdx.y;  // 49 x 4
  int t = threadIdx.x;
#pragma unroll
  for (int i = 0; i < 16; ++i) {
    int c = (t >> 6) * 16 + i;
    tile[c][t & 63] = fw[(c * 49 + p) * 256 + nb * 64 + (t & 63)];
  }
  __syncthreads();
#pragma unroll
  for (int i = 0; i < 16; ++i) {
    int n2 = (t >> 6) * 16 + i, c2 = t & 63;
    float v = tile[c2][n2];
    unsigned short h = f2bf_rne(v);
    size_t o = (size_t)(nb * 64 + n2) * 3136 + p * 64 + c2;
    fwhi[o] = h;
    fwlo[o] = f2bf_rne(v - bf2f(h));
  }
}

// ---------------- fc2: split-bf16 MFMA, grid 8mb x 14kc, 7 k-steps each, fused 3 terms ----------------
__global__ __launch_bounds__(256) void fc2_k(
    const unsigned short* __restrict__ h3hi, const unsigned short* __restrict__ h3lo,
    const unsigned short* __restrict__ fwhi, const unsigned short* __restrict__ fwlo,
    float* __restrict__ hpre) {
  int t = threadIdx.x, w = t >> 6, lane = t & 63, lm = lane & 15, hi4 = lane >> 4;
  int b = blockIdx.x, mb = b / 14, kc = b % 14;
  int m0 = mb * 64, n0 = w * 64;
  size_t kof = (size_t)kc * 224 + hi4 * 8;
  const unsigned short* pah[4]; const unsigned short* pal[4];
  const unsigned short* pbh[4]; const unsigned short* pbl[4];
#pragma unroll
  for (int mf = 0; mf < 4; ++mf) {
    pah[mf] = h3hi + (size_t)(m0 + mf * 16 + lm) * 3136 + kof;
    pal[mf] = h3lo + (size_t)(m0 + mf * 16 + lm) * 3136 + kof;
  }
#pragma unroll
  for (int nf = 0; nf < 4; ++nf) {
    pbh[nf] = fwhi + (size_t)(n0 + nf * 16 + lm) * 3136 + kof;
    pbl[nf] = fwlo + (size_t)(n0 + nf * 16 + lm) * 3136 + kof;
  }
  f32x4 acc[4][4];
#pragma unroll
  for (int mf = 0; mf < 4; ++mf)
#pragma unroll
    for (int nf = 0; nf < 4; ++nf) acc[mf][nf] = (f32x4){0.f, 0.f, 0.f, 0.f};
  bf16x8 cah[4], cal[4], cbh[4], cbl[4];
#pragma unroll
  for (int i = 0; i < 4; ++i) {
    cah[i] = *(const bf16x8*)(pah[i]); cal[i] = *(const bf16x8*)(pal[i]);
    cbh[i] = *(const bf16x8*)(pbh[i]); cbl[i] = *(const bf16x8*)(pbl[i]);
  }
#pragma unroll
  for (int ks = 0; ks < 7; ++ks) {
    bf16x8 nah[4], nal[4], nbh[4], nbl[4];
    if (ks < 6) {
      const int off = (ks + 1) * 32;
#pragma unroll
      for (int i = 0; i < 4; ++i) {
        nah[i] = *(const bf16x8*)(pah[i] + off); nal[i] = *(const bf16x8*)(pal[i] + off);
        nbh[i] = *(const bf16x8*)(pbh[i] + off); nbl[i] = *(const bf16x8*)(pbl[i] + off);
      }
    }
#pragma unroll
    for (int mf = 0; mf < 4; ++mf)
#pragma unroll
      for (int nf = 0; nf < 4; ++nf) {
        acc[mf][nf] = __builtin_amdgcn_mfma_f32_16x16x32_bf16(cah[mf], cbh[nf], acc[mf][nf], 0, 0, 0);
        acc[mf][nf] = __builtin_amdgcn_mfma_f32_16x16x32_bf16(cah[mf], cbl[nf], acc[mf][nf], 0, 0, 0);
        acc[mf][nf] = __builtin_amdgcn_mfma_f32_16x16x32_bf16(cal[mf], cbh[nf], acc[mf][nf], 0, 0, 0);
      }
    if (ks < 6) {
#pragma unroll
      for (int i = 0; i < 4; ++i) {
        cah[i] = nah[i]; cal[i] = nal[i]; cbh[i] = nbh[i]; cbl[i] = nbl[i];
      }
    }
  }
  float* outp = hpre + (size_t)kc * 131072;
#pragma unroll
  for (int mf = 0; mf < 4; ++mf)
#pragma unroll
    for (int nf = 0; nf < 4; ++nf)
#pragma unroll
      for (int r = 0; r < 4; ++r)
        outp[(m0 + mf * 16 + hi4 * 4 + r) * 256 + n0 + nf * 16 + lm] = acc[mf][nf][r];
}

// ---------------- fc_post: sum 14 k-planes + bias + relu -> hout + a_split ----------------
__global__ __launch_bounds__(256) void fc_post_k(
    const float* __restrict__ hpre, const float* __restrict__ fb,
    float* __restrict__ hout, unsigned short* __restrict__ a_split) {
  int m = blockIdx.x, n = threadIdx.x;
  float v = fb[n];
#pragma unroll
  for (int kc = 0; kc < 14; ++kc) v += hpre[(size_t)kc * 131072 + m * 256 + n];
  v = fmaxf(v, 0.f);
  hout[m * 256 + n] = v;
  unsigned short hi = f2bf_rne(v);
  unsigned short lo = f2bf_rne(v - bf2f(hi));
  a_split[(size_t)m * 768 + n] = hi;
  a_split[(size_t)m * 768 + 256 + n] = hi;
  a_split[(size_t)m * 768 + 512 + n] = lo;
}

// ---------------- embcvt: buf_emb -> Bemb[50176,512] bf16 (hi|lo) + nrm ----------------
__global__ __launch_bounds__(256) void embcvt_k(const float* __restrict__ e,
                                                unsigned short* __restrict__ Bemb,
                                                float* __restrict__ nrm) {
  int row = blockIdx.x * 4 + (threadIdx.x >> 6);
  if (row >= 50000) return;
  int lane = threadIdx.x & 63;
  float4 v = ((const float4*)(e + row * 256))[lane];
  float s = v.x * v.x + v.y * v.y + v.z * v.z + v.w * v.w;
  unsigned short h0 = f2bf_rne(v.x), h1 = f2bf_rne(v.y), h2 = f2bf_rne(v.z), h3 = f2bf_rne(v.w);
  unsigned short l0 = f2bf_rne(v.x - bf2f(h0)), l1 = f2bf_rne(v.y - bf2f(h1));
  unsigned short l2 = f2bf_rne(v.z - bf2f(h2)), l3 = f2bf_rne(v.w - bf2f(h3));
  *(ushort4*)(Bemb + (size_t)row * 512 + lane * 4) = make_ushort4(h0, h1, h2, h3);
  *(ushort4*)(Bemb + (size_t)row * 512 + 256 + lane * 4) = make_ushort4(l0, l1, l2, l3);
  for (int off = 32; off > 0; off >>= 1) s += __shfl_down(s, off);
  if (lane == 0) nrm[row] = s;
}

// ---------------- dist3: merged-term gload_lds MFMA distance GEMM + fused top-5 (R16 best) ----------------
// grid 1568 = 8xcd x 196; p = xcd*196+idx; nb = p>>2 (0..391), mb = p&3.
// Tile M=128 x N=128; 4 waves 2mw x 2nw. K = 4 slices of 64 shorts; per slice load
// Ah/Al/Bh/Bl planes ([128][64] each, 64KB total, single-buffer) and run all 3 split
// terms (Ah*Bh + Ah*Bl + Al*Bh) = 96 MFMA/wave per latency exposure.
// Swizzle: 16B slot' = slot ^ (row&7) at per-lane GLOBAL source + on ds_read.
__global__ __launch_bounds__(256) void dist3_k(
    const unsigned short* __restrict__ a_split, const unsigned short* __restrict__ Bemb,
    const float* __restrict__ nrm, unsigned long long* __restrict__ cand) {
  __shared__ short Ah[8192];
  __shared__ short Al[8192];
  __shared__ short Bh[8192];
  __shared__ short Bl[8192];
  int t = threadIdx.x, w = t >> 6, lane = t & 63, lm = lane & 15, hi = lane >> 4;
  int mw = w >> 1, nw = w & 1;
  int b = blockIdx.x;
  int p = (b & 7) * 196 + (b >> 3);
  int nb = p >> 2, mb = p & 3;

  const unsigned short* aTile = a_split + (size_t)mb * 128 * 768;
  const unsigned short* bTile = Bemb + (size_t)nb * 128 * 512;

  int crow[4], csl[4];
#pragma unroll
  for (int i = 0; i < 4; ++i) {
    int p16 = (w * 4 + i) * 64 + lane;
    crow[i] = p16 >> 3;
    csl[i] = ((p16 & 7) ^ (crow[i] & 7)) * 8;
  }

  f32x4 acc[4][4];  // [nf][mf]
#pragma unroll
  for (int nf = 0; nf < 4; ++nf)
#pragma unroll
    for (int mf = 0; mf < 4; ++mf) acc[nf][mf] = (f32x4){0.f, 0.f, 0.f, 0.f};

  const int arow0 = mw * 64;
  const int brow0 = nw * 64;

  // prologue: issue slice 0 (kk=0)
#pragma unroll
  for (int i = 0; i < 4; ++i) {
    gload16(aTile + (size_t)crow[i] * 768 + csl[i], &Ah[(w * 4 + i) * 512]);
    gload16(aTile + (size_t)crow[i] * 768 + 512 + csl[i], &Al[(w * 4 + i) * 512]);
    gload16(bTile + (size_t)crow[i] * 512 + csl[i], &Bh[(w * 4 + i) * 512]);
    gload16(bTile + (size_t)crow[i] * 512 + 256 + csl[i], &Bl[(w * 4 + i) * 512]);
  }

#pragma unroll
  for (int kk = 0; kk < 4; ++kk) {
    asm volatile("s_waitcnt vmcnt(0)" ::: "memory");
    __builtin_amdgcn_s_barrier();
    __builtin_amdgcn_sched_barrier(0);
#pragma unroll
    for (int q2 = 0; q2 < 2; ++q2) {
      bf16x8 fah[4], fal[4], fbh[4], fbl[4];
#pragma unroll
      for (int mf = 0; mf < 4; ++mf) {
        int row = arow0 + mf * 16 + lm;
        int off = row * 64 + (((q2 * 4 + hi) ^ (lm & 7)) * 8);
        fah[mf] = *(const bf16x8*)(&Ah[off]);
        fal[mf] = *(const bf16x8*)(&Al[off]);
      }
#pragma unroll
      for (int nf = 0; nf < 4; ++nf) {
        int row = brow0 + nf * 16 + lm;
        int off = row * 64 + (((q2 * 4 + hi) ^ (lm & 7)) * 8);
        fbh[nf] = *(const bf16x8*)(&Bh[off]);
        fbl[nf] = *(const bf16x8*)(&Bl[off]);
      }
#pragma unroll
      for (int nf = 0; nf < 4; ++nf)
#pragma unroll
        for (int mf = 0; mf < 4; ++mf) {
          acc[nf][mf] = __builtin_amdgcn_mfma_f32_16x16x32_bf16(fbh[nf], fah[mf], acc[nf][mf], 0, 0, 0);
          acc[nf][mf] = __builtin_amdgcn_mfma_f32_16x16x32_bf16(fbl[nf], fah[mf], acc[nf][mf], 0, 0, 0);
          acc[nf][mf] = __builtin_amdgcn_mfma_f32_16x16x32_bf16(fbh[nf], fal[mf], acc[nf][mf], 0, 0, 0);
        }
    }
    if (kk < 3) {
      lds_barrier();  // all waves done reading this slice
      const int ko = (kk + 1) * 64;
#pragma unroll
      for (int i = 0; i < 4; ++i) {
        gload16(aTile + (size_t)crow[i] * 768 + ko + csl[i], &Ah[(w * 4 + i) * 512]);
        gload16(aTile + (size_t)crow[i] * 768 + 512 + ko + csl[i], &Al[(w * 4 + i) * 512]);
        gload16(bTile + (size_t)crow[i] * 512 + ko + csl[i], &Bh[(w * 4 + i) * 512]);
        gload16(bTile + (size_t)crow[i] * 512 + 256 + ko + csl[i], &Bl[(w * 4 + i) * 512]);
      }
    }
  }

  // ---- fused selection: per lane, per mf: sorted-5 of (score|n) u64 keys ----
  const int nbase = nb * 128 + nw * 64;
  const int mbase = mb * 128 + mw * 64;
  unsigned long long Lst[4][5];
#pragma unroll
  for (int mf = 0; mf < 4; ++mf)
#pragma unroll
    for (int j = 0; j < 5; ++j) Lst[mf][j] = ~0ull;

#pragma unroll
  for (int nf = 0; nf < 4; ++nf) {
    int n0 = nbase + nf * 16 + hi * 4;
    float4 nv = *(const float4*)(nrm + n0);
#pragma unroll
    for (int r = 0; r < 4; ++r) {
      int n = n0 + r;
      bool ok = n < 50000;
      float nvr = (r == 0) ? nv.x : (r == 1) ? nv.y : (r == 2) ? nv.z : nv.w;
#pragma unroll
      for (int mf = 0; mf < 4; ++mf) {
        float sc = nvr - 2.f * acc[nf][mf][r];
        unsigned u = __float_as_uint(sc);
        u = ((int)u < 0) ? ~u : (u | 0x80000000u);
        unsigned long long k = ok ? ((((unsigned long long)u) << 32) | (unsigned)n) : ~0ull;
        if (k < Lst[mf][4]) {
          bool b3 = k < Lst[mf][3], b2 = k < Lst[mf][2], b1 = k < Lst[mf][1], b0 = k < Lst[mf][0];
          Lst[mf][4] = b3 ? Lst[mf][3] : k;
          Lst[mf][3] = b3 ? (b2 ? Lst[mf][2] : k) : Lst[mf][3];
          Lst[mf][2] = b2 ? (b1 ? Lst[mf][1] : k) : Lst[mf][2];
          Lst[mf][1] = b1 ? (b0 ? Lst[mf][0] : k) : Lst[mf][1];
          Lst[mf][0] = b0 ? k : Lst[mf][0];
        }
      }
    }
  }
#pragma unroll
  for (int mf = 0; mf < 4; ++mf) {
#pragma unroll
    for (int s = 16; s <= 32; s <<= 1) {
      unsigned long long b0 = shflx64(Lst[mf][0], s), b1 = shflx64(Lst[mf][1], s),
                         b2 = shflx64(Lst[mf][2], s), b3 = shflx64(Lst[mf][3], s),
                         b4 = shflx64(Lst[mf][4], s);
      unsigned long long a0 = Lst[mf][0], a1 = Lst[mf][1], a2 = Lst[mf][2],
                         a3 = Lst[mf][3], a4 = Lst[mf][4];
#pragma unroll
      for (int j = 0; j < 5; ++j) {
        bool ta = a0 <= b0;
        Lst[mf][j] = ta ? a0 : b0;
        unsigned long long na0 = ta ? a1 : a0, na1 = ta ? a2 : a1, na2 = ta ? a3 : a2, na3 = ta ? a4 : a3;
        unsigned long long nb0 = ta ? b0 : b1, nb1 = ta ? b1 : b2, nb2 = ta ? b2 : b3, nb3 = ta ? b3 : b4;
        a0 = na0; a1 = na1; a2 = na2; a3 = na3;
        b0 = nb0; b1 = nb1; b2 = nb2; b3 = nb3;
      }
    }
  }
  if (lane < 16) {
#pragma unroll
    for (int mf = 0; mf < 4; ++mf) {
      size_t base = ((size_t)(mbase + mf * 16 + lm) * 784 + (nb * 2 + nw)) * 5;
#pragma unroll
      for (int j = 0; j < 5; ++j) cand[base + j] = Lst[mf][j];
    }
  }
}

// ---------------- merge2: per row top-5 of 3920 keys, gather+blend ----------------
__global__ __launch_bounds__(64) void merge2_k(
    const unsigned long long* __restrict__ cand, const float* __restrict__ hbuf,
    const float* __restrict__ bufq, const float* __restrict__ out_w,
    const float* __restrict__ out_b, float* __restrict__ qout) {
  int row = blockIdx.x, lane = threadIdx.x;
  unsigned long long L0 = ~0ull, L1 = ~0ull, L2 = ~0ull, L3 = ~0ull, L4 = ~0ull;
  const unsigned long long* cr = cand + (size_t)row * 3920;
  for (int i = lane; i < 3920; i += 64) {
    unsigned long long k = cr[i];
    if (k < L4) {
      bool b3 = k < L3, b2 = k < L2, b1 = k < L1, b0 = k < L0;
      L4 = b3 ? L3 : k;
      L3 = b3 ? (b2 ? L2 : k) : L3;
      L2 = b2 ? (b1 ? L1 : k) : L2;
      L1 = b1 ? (b0 ? L0 : k) : L1;
      L0 = b0 ? k : L0;
    }
  }
#pragma unroll
  for (int s = 1; s < 64; s <<= 1) {
    unsigned long long o0 = shflx64(L0, s), o1 = shflx64(L1, s), o2 = shflx64(L2, s),
                       o3 = shflx64(L3, s), o4 = shflx64(L4, s);
    unsigned long long a0 = L0, a1 = L1, a2 = L2, a3 = L3, a4 = L4;
    unsigned long long b0 = o0, b1 = o1, b2 = o2, b3 = o3, b4 = o4;
    unsigned long long m[5];
#pragma unroll
    for (int j = 0; j < 5; ++j) {
      bool ta = a0 <= b0;
      m[j] = ta ? a0 : b0;
      unsigned long long na0 = ta ? a1 : a0, na1 = ta ? a2 : a1, na2 = ta ? a3 : a2, na3 = ta ? a4 : a3;
      unsigned long long nb0 = ta ? b0 : b1, nb1 = ta ? b1 : b2, nb2 = ta ? b2 : b3, nb3 = ta ? b3 : b4;
      a0 = na0; a1 = na1; a2 = na2; a3 = na3;
      b0 = nb0; b1 = nb1; b2 = nb2; b3 = nb3;
    }
    L0 = m[0]; L1 = m[1]; L2 = m[2]; L3 = m[3]; L4 = m[4];
  }
  int i0 = (int)(L0 & 0xFFFFFFFFu), i1 = (int)(L1 & 0xFFFFFFFFu), i2 = (int)(L2 & 0xFFFFFFFFu);
  int i3 = (int)(L3 & 0xFFFFFFFFu), i4 = (int)(L4 & 0xFFFFFFFFu);
  if (lane < 18) {
    float np = 0.2f * (bufq[(size_t)i0 * 18 + lane] + bufq[(size_t)i1 * 18 + lane] +
                       bufq[(size_t)i2 * 18 + lane] + bufq[(size_t)i3 * 18 + lane] +
                       bufq[(size_t)i4 * 18 + lane]);
    const float* hr = hbuf + row * 256;
    float q = out_b[lane];
    for (int d = 0; d < 256; ++d) q += hr[d] * out_w[d * 18 + lane];
    qout[row * 18 + lane] = 0.5f * q + 0.5f * np;
  }
}

// ================= fallback (round-1 f32 path, unchanged) =================
__global__ __launch_bounds__(320) void conv1_k(
    const float* __restrict__ x, const float* __restrict__ w,
    const float* __restrict__ b, float* __restrict__ y) {
  __shared__ float x_s[4 * 84 * 84];
  int n = blockIdx.x;
  {
    const float4* src = (const float4*)(x + n * 28224);
    float4* dst = (float4*)x_s;
    for (int i = threadIdx.x; i < 7056; i += 320) dst[i] = src[i];
  }
  __syncthreads();
  int t = threadIdx.x;
  int ocg = t / 80, rem = t % 80, oy = rem / 4, oxg = rem % 4;
  float acc[8][5];
#pragma unroll
  for (int r = 0; r < 8; ++r) {
    float bv = b[ocg * 8 + r];
#pragma unroll
    for (int i = 0; i < 5; ++i) acc[r][i] = bv;
  }
  for (int ic = 0; ic < 4; ++ic) {
    for (int ky = 0; ky < 8; ++ky) {
      const float* xrow = x_s + ic * 7056 + (oy * 4 + ky) * 84 + oxg * 20;
      const float* wrow = w + ic * 64 + ky * 8;
#pragma unroll
      for (int kx = 0; kx < 8; ++kx) {
        float xv[5];
#pragma unroll
        for (int i = 0; i < 5; ++i) xv[i] = xrow[i * 4 + kx];
#pragma unroll
        for (int r = 0; r < 8; ++r) {
          float wv = wrow[(ocg * 8 + r) * 256 + kx];
#pragma unroll
          for (int i = 0; i < 5; ++i) acc[r][i] += wv * xv[i];
        }
      }
    }
  }
  float* yb = y + n * 12800 + oy * 20 + oxg * 5;
#pragma unroll
  for (int r = 0; r < 8; ++r)
#pragma unroll
    for (int i = 0; i < 5; ++i)
      yb[(ocg * 8 + r) * 400 + i] = fmaxf(acc[r][i], 0.f);
}

__global__ __launch_bounds__(256) void conv2_k(
    const float* __restrict__ h1, const float* __restrict__ w,
    const float* __restrict__ b, float* __restrict__ y) {
  __shared__ float x_s[32 * 400];
  int n = blockIdx.x;
  {
    const float4* src = (const float4*)(h1 + n * 12800);
    float4* dst = (float4*)x_s;
    for (int i = threadIdx.x; i < 3200; i += 256) dst[i] = src[i];
  }
  __syncthreads();
  int t = threadIdx.x;
  if (t < 216) {
    int ocg = t / 27, rem = t % 27, oy = rem / 3, oxg = rem % 3;
    float acc[8][3];
#pragma unroll
    for (int r = 0; r < 8; ++r) {
      float bv = b[ocg * 8 + r];
#pragma unroll
      for (int i = 0; i < 3; ++i) acc[r][i] = bv;
    }
    const float* xbase = x_s + (oy * 2) * 20 + oxg * 6;
    for (int ic = 0; ic < 32; ++ic) {
#pragma unroll
      for (int ky = 0; ky < 4; ++ky) {
        const float* xr = xbase + ic * 400 + ky * 20;
        const float* wr = w + ic * 16 + ky * 4;
#pragma unroll
        for (int kx = 0; kx < 4; ++kx) {
          float xv0 = xr[kx], xv1 = xr[kx + 2], xv2 = xr[kx + 4];
#pragma unroll
          for (int r = 0; r < 8; ++r) {
            float wv = wr[(ocg * 8 + r) * 512 + kx];
            acc[r][0] += wv * xv0;
            acc[r][1] += wv * xv1;
            acc[r][2] += wv * xv2;
          }
        }
      }
    }
    float* yb = y + n * 5184 + oy * 9 + oxg * 3;
#pragma unroll
    for (int r = 0; r < 8; ++r)
#pragma unroll
      for (int i = 0; i < 3; ++i)
        yb[(ocg * 8 + r) * 81 + i] = fmaxf(acc[r][i], 0.f);
  }
}

__global__ __launch_bounds__(128) void conv3_k(
    const float* __restrict__ h2, const float* __restrict__ w,
    const float* __restrict__ b, float* __restrict__ y) {
  __shared__ float x_s[64 * 81];
  int n = blockIdx.x;
  {
    const float4* src = (const float4*)(h2 + n * 5184);
    float4* dst = (float4*)x_s;
    for (int i = threadIdx.x; i < 1296; i += 128) dst[i] = src[i];
  }
  __syncthreads();
  int t = threadIdx.x;
  if (t < 112) {
    int ocg = t / 7, oy = t % 7;
    float acc[4][7];
#pragma unroll
    for (int r = 0; r < 4; ++r) {
      float bv = b[ocg * 4 + r];
#pragma unroll
      for (int i = 0; i < 7; ++i) acc[r][i] = bv;
    }
    for (int ic = 0; ic < 64; ++ic) {
#pragma unroll
      for (int ky = 0; ky < 3; ++ky) {
        const float* xr = x_s + ic * 81 + (oy + ky) * 9;
        float xv[9];
#pragma unroll
        for (int i = 0; i < 9; ++i) xv[i] = xr[i];
        const float* wr = w + ic * 9 + ky * 3;
#pragma unroll
        for (int kx = 0; kx < 3; ++kx) {
#pragma unroll
          for (int r = 0; r < 4; ++r) {
            float wv = wr[(ocg * 4 + r) * 576 + kx];
#pragma unroll
            for (int i = 0; i < 7; ++i) acc[r][i] += wv * xv[i + kx];
          }
        }
      }
    }
    float* yb = y + n * 3136 + oy * 7;
#pragma unroll
    for (int r = 0; r < 4; ++r)
#pragma unroll
      for (int i = 0; i < 7; ++i)
        yb[(ocg * 4 + r) * 49 + i] = fmaxf(acc[r][i], 0.f);
  }
}

__global__ __launch_bounds__(256) void fc_k(
    const float* __restrict__ h3, const float* __restrict__ fw,
    const float* __restrict__ fb, float* __restrict__ hout,
    unsigned short* __restrict__ a_split) {
  __shared__ float a_s[4 * 3136];
  int n0 = blockIdx.x * 4;
  {
    const float4* src = (const float4*)(h3 + n0 * 3136);
    float4* dst = (float4*)a_s;
    for (int i = threadIdx.x; i < 3136; i += 256) dst[i] = src[i];
  }
  __syncthreads();
  int j = threadIdx.x;
  float a0 = fb[j], a1 = a0, a2 = a0, a3 = a0;
  for (int k = 0; k < 3136; ++k) {
    float wv = fw[k * 256 + j];
    a0 += a_s[k] * wv;
    a1 += a_s[3136 + k] * wv;
    a2 += a_s[2 * 3136 + k] * wv;
    a3 += a_s[3 * 3136 + k] * wv;
  }
  float hv[4];
  hv[0] = fmaxf(a0, 0.f); hv[1] = fmaxf(a1, 0.f);
  hv[2] = fmaxf(a2, 0.f); hv[3] = fmaxf(a3, 0.f);
#pragma unroll
  for (int r = 0; r < 4; ++r) {
    hout[(n0 + r) * 256 + j] = hv[r];
    if (a_split) {
      unsigned short hi = f2bf_rne(hv[r]);
      unsigned short lo = f2bf_rne(hv[r] - bf2f(hi));
      a_split[(size_t)(n0 + r) * 768 + j] = hi;
      a_split[(size_t)(n0 + r) * 768 + 256 + j] = hi;
      a_split[(size_t)(n0 + r) * 768 + 512 + j] = lo;
    }
  }
}

__global__ __launch_bounds__(256) void norm_k(const float* __restrict__ e,
                                              float* __restrict__ nrm) {
  int row = blockIdx.x * 4 + (threadIdx.x >> 6);
  if (row >= 50000) return;
  int lane = threadIdx.x & 63;
  float4 v = ((const float4*)(e + row * 256))[lane];
  float s = v.x * v.x + v.y * v.y + v.z * v.z + v.w * v.w;
  for (int off = 32; off > 0; off >>= 1) s += __shfl_down(s, off);
  if (lane == 0) nrm[row] = s;
}

__global__ __launch_bounds__(256) void dist_topk_k(
    const float* __restrict__ hbuf, const float* __restrict__ emb,
    const float* __restrict__ nrm, float* __restrict__ cand_d,
    int* __restrict__ cand_i) {
  __shared__ float a_s[16 * 256];
  __shared__ float b_s[512 * 17];
  int rb = blockIdx.x & 31, cb = blockIdx.x >> 5;
  int t = threadIdx.x;
  {
    const float4* src = (const float4*)(hbuf + rb * 16 * 256);
    float4* dst = (float4*)a_s;
    for (int i = t; i < 1024; i += 256) dst[i] = src[i];
  }
  float acc[8][4];
#pragma unroll
  for (int r = 0; r < 8; ++r)
#pragma unroll
    for (int c = 0; c < 4; ++c) acc[r][c] = 0.f;
  int ct = t & 127, rt = t >> 7;
  for (int kb = 0; kb < 256; kb += 16) {
    __syncthreads();
    for (int i = t; i < 2048; i += 256) {
      int j = i >> 2, kq = i & 3;
      int jg = cb * 512 + j;
      float4 v = make_float4(0.f, 0.f, 0.f, 0.f);
      if (jg < 50000) v = *(const float4*)(emb + jg * 256 + kb + kq * 4);
      float* dst = b_s + j * 17 + kq * 4;
      dst[0] = v.x; dst[1] = v.y; dst[2] = v.z; dst[3] = v.w;
    }
    __syncthreads();
#pragma unroll
    for (int k = 0; k < 16; ++k) {
      float av[8];
#pragma unroll
      for (int r = 0; r < 8; ++r) av[r] = a_s[(rt * 8 + r) * 256 + kb + k];
#pragma unroll
      for (int cc = 0; cc < 4; ++cc) {
        float bv = b_s[(ct + cc * 128) * 17 + k];
#pragma unroll
        for (int r = 0; r < 8; ++r) acc[r][cc] += av[r] * bv;
      }
    }
  }
  __syncthreads();
  float* score = b_s;
#pragma unroll
  for (int cc = 0; cc < 4; ++cc) {
    int c = ct + cc * 128;
    int jg = cb * 512 + c;
    float nv = (jg < 50000) ? nrm[jg] : 0.f;
#pragma unroll
    for (int r = 0; r < 8; ++r)
      score[(rt * 8 + r) * 512 + c] = (jg < 50000) ? (nv - 2.f * acc[r][cc]) : FINF;
  }
  __syncthreads();
  int wave = t >> 6, lane = t & 63;
  for (int rr = 0; rr < 4; ++rr) {
    int r = wave * 4 + rr;
    float v[8];
#pragma unroll
    for (int i = 0; i < 8; ++i) v[i] = score[r * 512 + lane + i * 64];
    for (int it = 0; it < 5; ++it) {
      float bv = v[0];
      int bc = lane;
#pragma unroll
      for (int i = 1; i < 8; ++i) {
        float xv = v[i];
        int c = lane + i * 64;
        if (xv < bv) { bv = xv; bc = c; }
      }
      for (int off = 32; off > 0; off >>= 1) {
        float ov = __shfl_down(bv, off);
        int ocx = __shfl_down(bc, off);
        if (ov < bv || (ov == bv && ocx < bc)) { bv = ov; bc = ocx; }
      }
      bv = __shfl(bv, 0);
      bc = __shfl(bc, 0);
      if (lane == 0) {
        int row_g = rb * 16 + r;
        int slot = (row_g * 98 + cb) * 5 + it;
        cand_d[slot] = bv;
        cand_i[slot] = cb * 512 + bc;
      }
#pragma unroll
      for (int i = 0; i < 8; ++i)
        if (lane + i * 64 == bc) v[i] = FINF;
    }
  }
}

__global__ __launch_bounds__(64) void merge_k(
    const float* __restrict__ cand_d, const int* __restrict__ cand_i,
    const float* __restrict__ hbuf, const float* __restrict__ bufq,
    const float* __restrict__ out_w, const float* __restrict__ out_b,
    float* __restrict__ qout) {
  int row = blockIdx.x, lane = threadIdx.x;
  __shared__ float sd[490];
  __shared__ int si[490];
  __shared__ int win[5];
  for (int i = lane; i < 490; i += 64) {
    sd[i] = cand_d[row * 490 + i];
    si[i] = cand_i[row * 490 + i];
  }
  __syncthreads();
  float v[8];
  int ix[8];
#pragma unroll
  for (int i = 0; i < 8; ++i) {
    int s = lane + i * 64;
    v[i] = (s < 490) ? sd[s] : FINF;
    ix[i] = (s < 490) ? si[s] : 0x7fffffff;
  }
  for (int it = 0; it < 5; ++it) {
    float bv = v[0];
    int bi = ix[0];
#pragma unroll
    for (int i = 1; i < 8; ++i)
      if (v[i] < bv || (v[i] == bv && ix[i] < bi)) { bv = v[i]; bi = ix[i]; }
    for (int off = 32; off > 0; off >>= 1) {
      float ov = __shfl_down(bv, off);
      int oi = __shfl_down(bi, off);
      if (ov < bv || (ov == bv && oi < bi)) { bv = ov; bi = oi; }
    }
    bi = __shfl(bi, 0);
    if (lane == 0) win[it] = bi;
#pragma unroll
    for (int i = 0; i < 8; ++i)
      if (ix[i] == bi) v[i] = FINF;
  }
  __syncthreads();
  if (lane < 18) {
    float np = 0.f;
#pragma unroll
    for (int it = 0; it < 5; ++it) np += bufq[win[it] * 18 + lane];
    np *= 0.2f;
    const float* hr = hbuf + row * 256;
    float q = out_b[lane];
    for (int d = 0; d < 256; ++d) q += hr[d] * out_w[d * 18 + lane];
    qout[row * 18 + lane] = 0.5f * q + 0.5f * np;
  }
}

extern "C" void kernel_launch(void* const* d_in, const int* in_sizes, int n_in,
                              void* d_out, int out_size, void* d_ws, size_t ws_size,
                              hipStream_t stream) {
  const float* x       = (const float*)d_in[0];
  const float* conv1_w = (const float*)d_in[1];
  const float* conv1_b = (const float*)d_in[2];
  const float* conv2_w = (const float*)d_in[3];
  const float* conv2_b = (const float*)d_in[4];
  const float* conv3_w = (const float*)d_in[5];
  const float* conv3_b = (const float*)d_in[6];
  const float* fc_w    = (const float*)d_in[7];
  const float* fc_b    = (const float*)d_in[8];
  const float* out_w   = (const float*)d_in[9];
  const float* out_b   = (const float*)d_in[10];
  const float* buf_emb = (const float*)d_in[11];
  const float* buf_q   = (const float*)d_in[12];

  float* out = (float*)d_out;  // [0,9216): q_blend; [9216,...): h
  float* hout = out + 9216;

  float* ws = (float*)d_ws;
  // mfma-path layout (float offsets into ws)
  unsigned short* h1s  = (unsigned short*)(ws);               // [0, 6,553,600 f)
  unsigned short* h2s  = (unsigned short*)(ws + 6553600);     // [6,553,600, 9,207,808 f)
  unsigned short* h3hi = (unsigned short*)(ws);               // reuses dead h1 region
  unsigned short* h3lo = (unsigned short*)(ws + 802816);
  unsigned short* Bs1h = (unsigned short*)(ws + 6553600);     // in h2s region (dead until conv2m)
  unsigned short* Bs1l = (unsigned short*)(ws + 6557696);
  float* nrm = ws + 9207808;                                  // [9,207,808, 9,257,984 f)
  unsigned long long* cand = (unsigned long long*)(ws + 9257984);  // [9,257,984, 13,272,064 f)
  // overlays inside cand region (dead before dist3 writes cand):
  unsigned short* Bs2h = (unsigned short*)(ws + 9257984);
  unsigned short* Bs2l = (unsigned short*)(ws + 9274368);
  unsigned short* Bs3h = (unsigned short*)(ws + 9290752);
  unsigned short* Bs3l = (unsigned short*)(ws + 9309184);     // ends 9,327,616 f
  unsigned short* fwhi = (unsigned short*)(ws + 9327616);
  unsigned short* fwlo = (unsigned short*)(ws + 9729024);     // ends 10,130,432 f
  float* hpre = ws + 10130432;
  unsigned short* a_split = (unsigned short*)(ws + 13272064);
  unsigned short* Bemb = (unsigned short*)(ws + 13468672);    // ends 26,313,728 f
  const size_t NEED = 105254912ull;

  bool mfma_path = (ws_size >= NEED);

  if (mfma_path) {
    w1swz_k<<<8, 128, 0, stream>>>(conv1_w, Bs1h, Bs1l);
    w2swz_k<<<16, 256, 0, stream>>>(conv2_w, Bs2h, Bs2l);
    w3swz_k<<<18, 256, 0, stream>>>(conv3_w, Bs3h, Bs3l);
    fcwcvt_k<<<dim3(49, 4), 256, 0, stream>>>(fc_w, fwhi, fwlo);
    embcvt_k<<<12500, 256, 0, stream>>>(buf_emb, Bemb, nrm);
    conv1m_k<<<800, 256, 0, stream>>>(x, Bs1h, Bs1l, conv1_b, h1s);
    conv2m_k<<<162, 256, 0, stream>>>(h1s, Bs2h, Bs2l, conv2_b, h2s);
    conv3m_k<<<98, 256, 0, stream>>>(h2s, Bs3h, Bs3l, conv3_b, h3hi, h3lo);
    fc2_k<<<112, 256, 0, stream>>>(h3hi, h3lo, fwhi, fwlo, hpre);
    fc_post_k<<<512, 256, 0, stream>>>(hpre, fc_b, hout, a_split);
    dist3_k<<<1568, 256, 0, stream>>>(a_split, Bemb, nrm, cand);
    merge2_k<<<512, 64, 0, stream>>>(cand, hout, buf_q, out_w, out_b, out);
  } else {
    // round-1 f32 fallback
    float* h1 = ws;
    float* h2 = h1 + 6553600;
    float* h3 = ws;
    float* nrm_o = h2 + 2654208;
    float* cand_d = nrm_o + 50000;
    int* cand_i = (int*)(cand_d + 250880);
    conv1_k<<<512, 320, 0, stream>>>(x, conv1_w, conv1_b, h1);
    conv2_k<<<512, 256, 0, stream>>>(h1, conv2_w, conv2_b, h2);
    conv3_k<<<512, 128, 0, stream>>>(h2, conv3_w, conv3_b, h3);
    fc_k<<<128, 256, 0, stream>>>(h3, fc_w, fc_b, hout, nullptr);
    norm_k<<<12500, 256, 0, stream>>>(buf_emb, nrm_o);
    dist_topk_k<<<3136, 256, 0, stream>>>(hout, buf_emb, nrm_o, cand_d, cand_i);
    merge_k<<<512, 64, 0, stream>>>(cand_d, cand_i, hout, buf_q, out_w, out_b, out);
  }
}

// Round 19
// 241.781 us; speedup vs baseline: 1.2667x; 1.0392x over previous
//
#include <hip/hip_runtime.h>
#include <hip/hip_bf16.h>

#define FINF 3.402823466e38f

typedef short bf16x8 __attribute__((ext_vector_type(8)));
typedef float f32x4 __attribute__((ext_vector_type(4)));

__device__ __forceinline__ unsigned short f2bf_rne(float f) {
  unsigned u = __float_as_uint(f);
  unsigned r = u + 0x7fff + ((u >> 16) & 1);
  return (unsigned short)(r >> 16);
}
__device__ __forceinline__ float bf2f(unsigned short u) {
  return __uint_as_float(((unsigned)u) << 16);
}
__device__ __forceinline__ unsigned long long shflx64(unsigned long long v, int m) {
  unsigned lo = __shfl_xor((unsigned)(v & 0xFFFFFFFFu), m, 64);
  unsigned hi = __shfl_xor((unsigned)(v >> 32), m, 64);
  return (((unsigned long long)hi) << 32) | lo;
}
// raw barrier: waits LDS ops only, leaves global prefetches in flight
__device__ __forceinline__ void lds_barrier() {
  asm volatile("s_waitcnt lgkmcnt(0)" ::: "memory");
  __builtin_amdgcn_s_barrier();
  __builtin_amdgcn_sched_barrier(0);
}
// wave-local LDS sync: ds_write -> ds_read within ONE wave needs only lgkmcnt,
// no s_barrier (rule #18: sched_barrier stops MFMA hoisting past the wait)
__device__ __forceinline__ void wave_sync() {
  asm volatile("s_waitcnt lgkmcnt(0)" ::: "memory");
  __builtin_amdgcn_sched_barrier(0);
}
// async global->LDS, 16B per lane; LDS dest = uniform base + lane*16
__device__ __forceinline__ void gload16(const unsigned short* g, short* l) {
  __builtin_amdgcn_global_load_lds(
      (const __attribute__((address_space(1))) unsigned int*)g,
      (__attribute__((address_space(3))) unsigned int*)l, 16, 0, 0);
}

// ---------------- prep: all weight conversions fused into one launch ----------------
// b<8: conv1_w -> [ky8][nf2][64][8] hi/lo (128 threads active)
// b<24: conv2_w -> [tap16][nf4][64][8] hi/lo
// b<42: conv3_w -> [tt18][nf4][64][8] hi/lo
// else: fc_w [3136,256] -> fwhi/fwlo [256][3136] (idx = b-42: p=idx%49, nb=idx/49)
__global__ __launch_bounds__(256) void prep_k(
    const float* __restrict__ w1, unsigned short* __restrict__ b1h, unsigned short* __restrict__ b1l,
    const float* __restrict__ w2, unsigned short* __restrict__ b2h, unsigned short* __restrict__ b2l,
    const float* __restrict__ w3, unsigned short* __restrict__ b3h, unsigned short* __restrict__ b3l,
    const float* __restrict__ fw, unsigned short* __restrict__ fwhi, unsigned short* __restrict__ fwlo) {
  __shared__ float tile[64][65];
  int b = blockIdx.x, t = threadIdx.x;
  if (b < 8) {
    if (t < 128) {
      int ky = b;
      int nf = t >> 6, l = t & 63;
      int oc = nf * 16 + (l & 15), ic = l >> 4;
      bf16x8 hv, lv;
#pragma unroll
      for (int j = 0; j < 8; ++j) {
        float v = w1[((oc * 4 + ic) * 8 + ky) * 8 + j];
        unsigned short h = f2bf_rne(v);
        hv[j] = (short)h;
        lv[j] = (short)f2bf_rne(v - bf2f(h));
      }
      *(bf16x8*)(&b1h[((size_t)(ky * 2 + nf) * 64 + l) * 8]) = hv;
      *(bf16x8*)(&b1l[((size_t)(ky * 2 + nf) * 64 + l) * 8]) = lv;
    }
  } else if (b < 24) {
    int tap = b - 8, ky = tap >> 2, kx = tap & 3;
    int nf = t >> 6, l = t & 63;
    int oc = nf * 16 + (l & 15);
    bf16x8 hv, lv;
#pragma unroll
    for (int j = 0; j < 8; ++j) {
      int ic = (l >> 4) * 8 + j;
      float v = w2[((oc * 32 + ic) * 4 + ky) * 4 + kx];
      unsigned short h = f2bf_rne(v);
      hv[j] = (short)h;
      lv[j] = (short)f2bf_rne(v - bf2f(h));
    }
    *(bf16x8*)(&b2h[((size_t)(tap * 4 + nf) * 64 + l) * 8]) = hv;
    *(bf16x8*)(&b2l[((size_t)(tap * 4 + nf) * 64 + l) * 8]) = lv;
  } else if (b < 42) {
    int tt = b - 24, tap = tt >> 1, half = tt & 1, ky = tap / 3, kx = tap % 3;
    int nf = t >> 6, l = t & 63;
    int oc = nf * 16 + (l & 15);
    bf16x8 hv, lv;
#pragma unroll
    for (int j = 0; j < 8; ++j) {
      int ic = half * 32 + (l >> 4) * 8 + j;
      float v = w3[((oc * 64 + ic) * 3 + ky) * 3 + kx];
      unsigned short h = f2bf_rne(v);
      hv[j] = (short)h;
      lv[j] = (short)f2bf_rne(v - bf2f(h));
    }
    *(bf16x8*)(&b3h[((size_t)(tt * 4 + nf) * 64 + l) * 8]) = hv;
    *(bf16x8*)(&b3l[((size_t)(tt * 4 + nf) * 64 + l) * 8]) = lv;
  } else {
    int idx = b - 42, p = idx % 49, nb = idx / 49;
#pragma unroll
    for (int i = 0; i < 16; ++i) {
      int c = (t >> 6) * 16 + i;
      tile[c][t & 63] = fw[(c * 49 + p) * 256 + nb * 64 + (t & 63)];
    }
    __syncthreads();
#pragma unroll
    for (int i = 0; i < 16; ++i) {
      int n2 = (t >> 6) * 16 + i, c2 = t & 63;
      float v = tile[c2][n2];
      unsigned short h = f2bf_rne(v);
      size_t o = (size_t)(nb * 64 + n2) * 3136 + p * 64 + c2;
      fwhi[o] = h;
      fwlo[o] = f2bf_rne(v - bf2f(h));
    }
  }
}

// ---------------- conv1m: x f32 -> h1s NHWC [204800 pix][32hi|32lo], 8-tap MFMA ----------------
// LDS is wave-local (wave w writes rows w*64+lane, reads rows w*64+mf*16+lm) -> no barriers.
__global__ __launch_bounds__(256) void conv1m_k(
    const float* __restrict__ x,
    const unsigned short* __restrict__ bh, const unsigned short* __restrict__ bl,
    const float* __restrict__ bias, unsigned short* __restrict__ h1s) {
  __shared__ short As[256 * 72];  // row*72: [0,32)=hi (4ic x 8kx), [36,68)=lo
  int t = threadIdx.x, w = t >> 6, lane = t & 63, lm = lane & 15, hi4 = lane >> 4;
  int m = blockIdx.x * 256 + t;
  int n = m / 400, p = m % 400, oy = p / 20, ox = p % 20;
  size_t xoff = (size_t)n * 28224 + (size_t)(oy * 4) * 84 + ox * 4;  // + ic*7056 + ky*84
  f32x4 acc[4][2];
#pragma unroll
  for (int mf = 0; mf < 4; ++mf)
#pragma unroll
    for (int nf = 0; nf < 2; ++nf) acc[mf][nf] = (f32x4){0.f, 0.f, 0.f, 0.f};

  float4 fa[8];  // current tap: [ic*2 + half]
#pragma unroll
  for (int ic = 0; ic < 4; ++ic) {
    fa[ic * 2 + 0] = *(const float4*)(x + xoff + ic * 7056);
    fa[ic * 2 + 1] = *(const float4*)(x + xoff + ic * 7056 + 4);
  }
  const unsigned short* bfp = bh + (size_t)lane * 8;
  const unsigned short* blp = bl + (size_t)lane * 8;
  bf16x8 cbh[2], cbl[2];
#pragma unroll
  for (int nf = 0; nf < 2; ++nf) {
    cbh[nf] = *(const bf16x8*)(bfp + nf * 512);
    cbl[nf] = *(const bf16x8*)(blp + nf * 512);
  }
#pragma unroll
  for (int ky = 0; ky < 8; ++ky) {
    if (ky) wave_sync();  // own-wave reads of previous tap done
    {
      short* wp = &As[t * 72];
#pragma unroll
      for (int ic = 0; ic < 4; ++ic) {
        float e0 = fa[ic * 2].x, e1 = fa[ic * 2].y, e2 = fa[ic * 2].z, e3 = fa[ic * 2].w;
        float e4 = fa[ic * 2 + 1].x, e5 = fa[ic * 2 + 1].y, e6 = fa[ic * 2 + 1].z, e7 = fa[ic * 2 + 1].w;
        bf16x8 hv, lv;
        unsigned short h;
        h = f2bf_rne(e0); hv[0] = (short)h; lv[0] = (short)f2bf_rne(e0 - bf2f(h));
        h = f2bf_rne(e1); hv[1] = (short)h; lv[1] = (short)f2bf_rne(e1 - bf2f(h));
        h = f2bf_rne(e2); hv[2] = (short)h; lv[2] = (short)f2bf_rne(e2 - bf2f(h));
        h = f2bf_rne(e3); hv[3] = (short)h; lv[3] = (short)f2bf_rne(e3 - bf2f(h));
        h = f2bf_rne(e4); hv[4] = (short)h; lv[4] = (short)f2bf_rne(e4 - bf2f(h));
        h = f2bf_rne(e5); hv[5] = (short)h; lv[5] = (short)f2bf_rne(e5 - bf2f(h));
        h = f2bf_rne(e6); hv[6] = (short)h; lv[6] = (short)f2bf_rne(e6 - bf2f(h));
        h = f2bf_rne(e7); hv[7] = (short)h; lv[7] = (short)f2bf_rne(e7 - bf2f(h));
        *(bf16x8*)(wp + ic * 8) = hv;
        *(bf16x8*)(wp + 36 + ic * 8) = lv;
      }
    }
    wave_sync();  // own writes visible to own reads
    bf16x8 nbh[2], nbl[2];
    if (ky < 7) {
      size_t ap = xoff + (size_t)(ky + 1) * 84;
#pragma unroll
      for (int ic = 0; ic < 4; ++ic) {
        fa[ic * 2 + 0] = *(const float4*)(x + ap + ic * 7056);
        fa[ic * 2 + 1] = *(const float4*)(x + ap + ic * 7056 + 4);
      }
#pragma unroll
      for (int nf = 0; nf < 2; ++nf) {
        nbh[nf] = *(const bf16x8*)(bfp + ((ky + 1) * 2 + nf) * 512);
        nbl[nf] = *(const bf16x8*)(blp + ((ky + 1) * 2 + nf) * 512);
      }
    }
    bf16x8 ah[4], al[4];
#pragma unroll
    for (int mf = 0; mf < 4; ++mf) {
      const short* rp = &As[(w * 64 + mf * 16 + lm) * 72 + hi4 * 8];
      ah[mf] = *(const bf16x8*)(rp);
      al[mf] = *(const bf16x8*)(rp + 36);
    }
#pragma unroll
    for (int mf = 0; mf < 4; ++mf)
#pragma unroll
      for (int nf = 0; nf < 2; ++nf) {
        acc[mf][nf] = __builtin_amdgcn_mfma_f32_16x16x32_bf16(ah[mf], cbh[nf], acc[mf][nf], 0, 0, 0);
        acc[mf][nf] = __builtin_amdgcn_mfma_f32_16x16x32_bf16(ah[mf], cbl[nf], acc[mf][nf], 0, 0, 0);
        acc[mf][nf] = __builtin_amdgcn_mfma_f32_16x16x32_bf16(al[mf], cbh[nf], acc[mf][nf], 0, 0, 0);
      }
    if (ky < 7) {
#pragma unroll
      for (int nf = 0; nf < 2; ++nf) { cbh[nf] = nbh[nf]; cbl[nf] = nbl[nf]; }
    }
  }
  float bv[2];
#pragma unroll
  for (int nf = 0; nf < 2; ++nf) bv[nf] = bias[nf * 16 + lm];
#pragma unroll
  for (int mf = 0; mf < 4; ++mf)
#pragma unroll
    for (int nf = 0; nf < 2; ++nf)
#pragma unroll
      for (int r = 0; r < 4; ++r) {
        size_t mrow = (size_t)blockIdx.x * 256 + w * 64 + mf * 16 + hi4 * 4 + r;
        float v = fmaxf(acc[mf][nf][r] + bv[nf], 0.f);
        unsigned short h = f2bf_rne(v);
        h1s[mrow * 64 + nf * 16 + lm] = h;
        h1s[mrow * 64 + 32 + nf * 16 + lm] = f2bf_rne(v - bf2f(h));
      }
}

// ---------------- conv2m: h1s NHWC -> h2s [41472 pix][64hi|64lo], 16-tap MFMA, wave-local LDS ----------------
__global__ __launch_bounds__(256) void conv2m_k(
    const unsigned short* __restrict__ h1s, const unsigned short* __restrict__ bh,
    const unsigned short* __restrict__ bl, const float* __restrict__ bias,
    unsigned short* __restrict__ h2s) {
  __shared__ short As[256 * 72];
  int t = threadIdx.x, w = t >> 6, lane = t & 63, lm = lane & 15, hi4 = lane >> 4;
  int m = blockIdx.x * 256 + t;
  int n = m / 81, p = m % 81, oy = p / 9, ox = p % 9;
  const unsigned short* abase = h1s + (size_t)(n * 400 + oy * 40 + ox * 2) * 64;
  f32x4 acc[4][4];
#pragma unroll
  for (int mf = 0; mf < 4; ++mf)
#pragma unroll
    for (int nf = 0; nf < 4; ++nf) acc[mf][nf] = (f32x4){0.f, 0.f, 0.f, 0.f};

  bf16x8 s0, s1, s2, s3, s4, s5, s6, s7;
  {
    const unsigned short* ap = abase;  // tap 0
    s0 = *(const bf16x8*)(ap);      s1 = *(const bf16x8*)(ap + 8);
    s2 = *(const bf16x8*)(ap + 16); s3 = *(const bf16x8*)(ap + 24);
    s4 = *(const bf16x8*)(ap + 32); s5 = *(const bf16x8*)(ap + 40);
    s6 = *(const bf16x8*)(ap + 48); s7 = *(const bf16x8*)(ap + 56);
  }
  const unsigned short* bfp = bh + (size_t)lane * 8;
  const unsigned short* blp = bl + (size_t)lane * 8;
  bf16x8 cbh[4], cbl[4];
#pragma unroll
  for (int nf = 0; nf < 4; ++nf) {
    cbh[nf] = *(const bf16x8*)(bfp + nf * 512);
    cbl[nf] = *(const bf16x8*)(blp + nf * 512);
  }
#pragma unroll
  for (int tap = 0; tap < 16; ++tap) {
    if (tap) wave_sync();
    {
      short* wp = &As[t * 72];
      *(bf16x8*)(wp) = s0;      *(bf16x8*)(wp + 8) = s1;
      *(bf16x8*)(wp + 16) = s2; *(bf16x8*)(wp + 24) = s3;
      *(bf16x8*)(wp + 36) = s4; *(bf16x8*)(wp + 44) = s5;
      *(bf16x8*)(wp + 52) = s6; *(bf16x8*)(wp + 60) = s7;
    }
    wave_sync();
    bf16x8 nbh[4], nbl[4];
    if (tap < 15) {
      const unsigned short* ap = abase + (((tap + 1) >> 2) * 1280 + ((tap + 1) & 3) * 64);
      s0 = *(const bf16x8*)(ap);      s1 = *(const bf16x8*)(ap + 8);
      s2 = *(const bf16x8*)(ap + 16); s3 = *(const bf16x8*)(ap + 24);
      s4 = *(const bf16x8*)(ap + 32); s5 = *(const bf16x8*)(ap + 40);
      s6 = *(const bf16x8*)(ap + 48); s7 = *(const bf16x8*)(ap + 56);
#pragma unroll
      for (int nf = 0; nf < 4; ++nf) {
        nbh[nf] = *(const bf16x8*)(bfp + ((tap + 1) * 4 + nf) * 512);
        nbl[nf] = *(const bf16x8*)(blp + ((tap + 1) * 4 + nf) * 512);
      }
    }
    bf16x8 ah[4], al[4];
#pragma unroll
    for (int mf = 0; mf < 4; ++mf) {
      const short* rp = &As[(w * 64 + mf * 16 + lm) * 72 + hi4 * 8];
      ah[mf] = *(const bf16x8*)(rp);
      al[mf] = *(const bf16x8*)(rp + 36);
    }
#pragma unroll
    for (int mf = 0; mf < 4; ++mf)
#pragma unroll
      for (int nf = 0; nf < 4; ++nf) {
        acc[mf][nf] = __builtin_amdgcn_mfma_f32_16x16x32_bf16(ah[mf], cbh[nf], acc[mf][nf], 0, 0, 0);
        acc[mf][nf] = __builtin_amdgcn_mfma_f32_16x16x32_bf16(ah[mf], cbl[nf], acc[mf][nf], 0, 0, 0);
        acc[mf][nf] = __builtin_amdgcn_mfma_f32_16x16x32_bf16(al[mf], cbh[nf], acc[mf][nf], 0, 0, 0);
      }
    if (tap < 15) {
#pragma unroll
      for (int nf = 0; nf < 4; ++nf) { cbh[nf] = nbh[nf]; cbl[nf] = nbl[nf]; }
    }
  }
  float bv[4];
#pragma unroll
  for (int nf = 0; nf < 4; ++nf) bv[nf] = bias[nf * 16 + lm];
#pragma unroll
  for (int mf = 0; mf < 4; ++mf)
#pragma unroll
    for (int nf = 0; nf < 4; ++nf)
#pragma unroll
      for (int r = 0; r < 4; ++r) {
        size_t mrow = (size_t)blockIdx.x * 256 + w * 64 + mf * 16 + hi4 * 4 + r;
        float v = fmaxf(acc[mf][nf][r] + bv[nf], 0.f);
        unsigned short h = f2bf_rne(v);
        h2s[mrow * 128 + nf * 16 + lm] = h;
        h2s[mrow * 128 + 64 + nf * 16 + lm] = f2bf_rne(v - bf2f(h));
      }
}

// ---------------- conv3m: h2s -> h3hi/h3lo [25088 pix][64], 18-chunk MFMA, wave-local LDS ----------------
__global__ __launch_bounds__(256) void conv3m_k(
    const unsigned short* __restrict__ h2s, const unsigned short* __restrict__ bh,
    const unsigned short* __restrict__ bl, const float* __restrict__ bias,
    unsigned short* __restrict__ h3hi, unsigned short* __restrict__ h3lo) {
  __shared__ short As[256 * 72];
  int t = threadIdx.x, w = t >> 6, lane = t & 63, lm = lane & 15, hi4 = lane >> 4;
  int m = blockIdx.x * 256 + t;
  int n = m / 49, p = m % 49, oy = p / 7, ox = p % 7;
  const unsigned short* abase = h2s + (size_t)(n * 81 + oy * 9 + ox) * 128;
  f32x4 acc[4][4];
#pragma unroll
  for (int mf = 0; mf < 4; ++mf)
#pragma unroll
    for (int nf = 0; nf < 4; ++nf) acc[mf][nf] = (f32x4){0.f, 0.f, 0.f, 0.f};

  bf16x8 s0, s1, s2, s3, s4, s5, s6, s7;
  {
    const unsigned short* ap = abase;
    s0 = *(const bf16x8*)(ap);      s1 = *(const bf16x8*)(ap + 8);
    s2 = *(const bf16x8*)(ap + 16); s3 = *(const bf16x8*)(ap + 24);
    s4 = *(const bf16x8*)(ap + 64); s5 = *(const bf16x8*)(ap + 72);
    s6 = *(const bf16x8*)(ap + 80); s7 = *(const bf16x8*)(ap + 88);
  }
  const unsigned short* bfp = bh + (size_t)lane * 8;
  const unsigned short* blp = bl + (size_t)lane * 8;
  bf16x8 cbh[4], cbl[4];
#pragma unroll
  for (int nf = 0; nf < 4; ++nf) {
    cbh[nf] = *(const bf16x8*)(bfp + nf * 512);
    cbl[nf] = *(const bf16x8*)(blp + nf * 512);
  }
#pragma unroll
  for (int tt = 0; tt < 18; ++tt) {
    if (tt) wave_sync();
    {
      short* wp = &As[t * 72];
      *(bf16x8*)(wp) = s0;      *(bf16x8*)(wp + 8) = s1;
      *(bf16x8*)(wp + 16) = s2; *(bf16x8*)(wp + 24) = s3;
      *(bf16x8*)(wp + 36) = s4; *(bf16x8*)(wp + 44) = s5;
      *(bf16x8*)(wp + 52) = s6; *(bf16x8*)(wp + 60) = s7;
    }
    wave_sync();
    bf16x8 nbh[4], nbl[4];
    if (tt < 17) {
      const int tn = tt + 1, tapn = tn >> 1, halfn = tn & 1;
      const unsigned short* ap = abase + ((tapn / 3) * 9 + (tapn % 3)) * 128 + halfn * 32;
      s0 = *(const bf16x8*)(ap);      s1 = *(const bf16x8*)(ap + 8);
      s2 = *(const bf16x8*)(ap + 16); s3 = *(const bf16x8*)(ap + 24);
      s4 = *(const bf16x8*)(ap + 64); s5 = *(const bf16x8*)(ap + 72);
      s6 = *(const bf16x8*)(ap + 80); s7 = *(const bf16x8*)(ap + 88);
#pragma unroll
      for (int nf = 0; nf < 4; ++nf) {
        nbh[nf] = *(const bf16x8*)(bfp + ((tt + 1) * 4 + nf) * 512);
        nbl[nf] = *(const bf16x8*)(blp + ((tt + 1) * 4 + nf) * 512);
      }
    }
    bf16x8 ah[4], al[4];
#pragma unroll
    for (int mf = 0; mf < 4; ++mf) {
      const short* rp = &As[(w * 64 + mf * 16 + lm) * 72 + hi4 * 8];
      ah[mf] = *(const bf16x8*)(rp);
      al[mf] = *(const bf16x8*)(rp + 36);
    }
#pragma unroll
    for (int mf = 0; mf < 4; ++mf)
#pragma unroll
      for (int nf = 0; nf < 4; ++nf) {
        acc[mf][nf] = __builtin_amdgcn_mfma_f32_16x16x32_bf16(ah[mf], cbh[nf], acc[mf][nf], 0, 0, 0);
        acc[mf][nf] = __builtin_amdgcn_mfma_f32_16x16x32_bf16(ah[mf], cbl[nf], acc[mf][nf], 0, 0, 0);
        acc[mf][nf] = __builtin_amdgcn_mfma_f32_16x16x32_bf16(al[mf], cbh[nf], acc[mf][nf], 0, 0, 0);
      }
    if (tt < 17) {
#pragma unroll
      for (int nf = 0; nf < 4; ++nf) { cbh[nf] = nbh[nf]; cbl[nf] = nbl[nf]; }
    }
  }
  float bv[4];
#pragma unroll
  for (int nf = 0; nf < 4; ++nf) bv[nf] = bias[nf * 16 + lm];
#pragma unroll
  for (int mf = 0; mf < 4; ++mf)
#pragma unroll
    for (int nf = 0; nf < 4; ++nf)
#pragma unroll
      for (int r = 0; r < 4; ++r) {
        size_t mrow = (size_t)blockIdx.x * 256 + w * 64 + mf * 16 + hi4 * 4 + r;
        float v = fmaxf(acc[mf][nf][r] + bv[nf], 0.f);
        unsigned short h = f2bf_rne(v);
        h3hi[mrow * 64 + nf * 16 + lm] = h;
        h3lo[mrow * 64 + nf * 16 + lm] = f2bf_rne(v - bf2f(h));
      }
}

// ---------------- fc2: split-bf16 MFMA, grid 8mb x 14kc, 7 k-steps each, fused 3 terms ----------------
__global__ __launch_bounds__(256) void fc2_k(
    const unsigned short* __restrict__ h3hi, const unsigned short* __restrict__ h3lo,
    const unsigned short* __restrict__ fwhi, const unsigned short* __restrict__ fwlo,
    float* __restrict__ hpre) {
  int t = threadIdx.x, w = t >> 6, lane = t & 63, lm = lane & 15, hi4 = lane >> 4;
  int b = blockIdx.x, mb = b / 14, kc = b % 14;
  int m0 = mb * 64, n0 = w * 64;
  size_t kof = (size_t)kc * 224 + hi4 * 8;
  const unsigned short* pah[4]; const unsigned short* pal[4];
  const unsigned short* pbh[4]; const unsigned short* pbl[4];
#pragma unroll
  for (int mf = 0; mf < 4; ++mf) {
    pah[mf] = h3hi + (size_t)(m0 + mf * 16 + lm) * 3136 + kof;
    pal[mf] = h3lo + (size_t)(m0 + mf * 16 + lm) * 3136 + kof;
  }
#pragma unroll
  for (int nf = 0; nf < 4; ++nf) {
    pbh[nf] = fwhi + (size_t)(n0 + nf * 16 + lm) * 3136 + kof;
    pbl[nf] = fwlo + (size_t)(n0 + nf * 16 + lm) * 3136 + kof;
  }
  f32x4 acc[4][4];
#pragma unroll
  for (int mf = 0; mf < 4; ++mf)
#pragma unroll
    for (int nf = 0; nf < 4; ++nf) acc[mf][nf] = (f32x4){0.f, 0.f, 0.f, 0.f};
  bf16x8 cah[4], cal[4], cbh[4], cbl[4];
#pragma unroll
  for (int i = 0; i < 4; ++i) {
    cah[i] = *(const bf16x8*)(pah[i]); cal[i] = *(const bf16x8*)(pal[i]);
    cbh[i] = *(const bf16x8*)(pbh[i]); cbl[i] = *(const bf16x8*)(pbl[i]);
  }
#pragma unroll
  for (int ks = 0; ks < 7; ++ks) {
    bf16x8 nah[4], nal[4], nbh[4], nbl[4];
    if (ks < 6) {
      const int off = (ks + 1) * 32;
#pragma unroll
      for (int i = 0; i < 4; ++i) {
        nah[i] = *(const bf16x8*)(pah[i] + off); nal[i] = *(const bf16x8*)(pal[i] + off);
        nbh[i] = *(const bf16x8*)(pbh[i] + off); nbl[i] = *(const bf16x8*)(pbl[i] + off);
      }
    }
#pragma unroll
    for (int mf = 0; mf < 4; ++mf)
#pragma unroll
      for (int nf = 0; nf < 4; ++nf) {
        acc[mf][nf] = __builtin_amdgcn_mfma_f32_16x16x32_bf16(cah[mf], cbh[nf], acc[mf][nf], 0, 0, 0);
        acc[mf][nf] = __builtin_amdgcn_mfma_f32_16x16x32_bf16(cah[mf], cbl[nf], acc[mf][nf], 0, 0, 0);
        acc[mf][nf] = __builtin_amdgcn_mfma_f32_16x16x32_bf16(cal[mf], cbh[nf], acc[mf][nf], 0, 0, 0);
      }
    if (ks < 6) {
#pragma unroll
      for (int i = 0; i < 4; ++i) {
        cah[i] = nah[i]; cal[i] = nal[i]; cbh[i] = nbh[i]; cbl[i] = nbl[i];
      }
    }
  }
  float* outp = hpre + (size_t)kc * 131072;
#pragma unroll
  for (int mf = 0; mf < 4; ++mf)
#pragma unroll
    for (int nf = 0; nf < 4; ++nf)
#pragma unroll
      for (int r = 0; r < 4; ++r)
        outp[(m0 + mf * 16 + hi4 * 4 + r) * 256 + n0 + nf * 16 + lm] = acc[mf][nf][r];
}

// ---------------- fc_post: sum 14 k-planes + bias + relu -> hout + a_split [512/row hi|lo] ----------------
__global__ __launch_bounds__(256) void fc_post_k(
    const float* __restrict__ hpre, const float* __restrict__ fb,
    float* __restrict__ hout, unsigned short* __restrict__ a_split) {
  int m = blockIdx.x, n = threadIdx.x;
  float v = fb[n];
#pragma unroll
  for (int kc = 0; kc < 14; ++kc) v += hpre[(size_t)kc * 131072 + m * 256 + n];
  v = fmaxf(v, 0.f);
  hout[m * 256 + n] = v;
  unsigned short hi = f2bf_rne(v);
  unsigned short lo = f2bf_rne(v - bf2f(hi));
  a_split[(size_t)m * 512 + n] = hi;
  a_split[(size_t)m * 512 + 256 + n] = lo;
}

// ---------------- embcvt: buf_emb -> Bemb[50176,512] bf16 (hi|lo) + nrm ----------------
__global__ __launch_bounds__(256) void embcvt_k(const float* __restrict__ e,
                                                unsigned short* __restrict__ Bemb,
                                                float* __restrict__ nrm) {
  int row = blockIdx.x * 4 + (threadIdx.x >> 6);
  if (row >= 50000) return;
  int lane = threadIdx.x & 63;
  float4 v = ((const float4*)(e + row * 256))[lane];
  float s = v.x * v.x + v.y * v.y + v.z * v.z + v.w * v.w;
  unsigned short h0 = f2bf_rne(v.x), h1 = f2bf_rne(v.y), h2 = f2bf_rne(v.z), h3 = f2bf_rne(v.w);
  unsigned short l0 = f2bf_rne(v.x - bf2f(h0)), l1 = f2bf_rne(v.y - bf2f(h1));
  unsigned short l2 = f2bf_rne(v.z - bf2f(h2)), l3 = f2bf_rne(v.w - bf2f(h3));
  *(ushort4*)(Bemb + (size_t)row * 512 + lane * 4) = make_ushort4(h0, h1, h2, h3);
  *(ushort4*)(Bemb + (size_t)row * 512 + 256 + lane * 4) = make_ushort4(l0, l1, l2, l3);
  for (int off = 32; off > 0; off >>= 1) s += __shfl_down(s, off);
  if (lane == 0) nrm[row] = s;
}

// ---------------- dist3: merged-term gload_lds MFMA distance GEMM + fused top-5 ----------------
// grid 1568 = 8xcd x 196; p = xcd*196+idx; nb = p>>2 (0..391), mb = p&3.
// Tile M=128 x N=128; 4 waves 2mw x 2nw. K = 4 slices of 64 shorts; per slice load
// Ah/Al/Bh/Bl planes ([128][64] each, 64KB total, single-buffer) and run all 3 split
// terms (Ah*Bh + Ah*Bl + Al*Bh) = 96 MFMA/wave per latency exposure.
// A rows now [hi|lo] = 512 shorts (same stride as B). s_setprio(1) around MFMA (T5).
// Swizzle: 16B slot' = slot ^ (row&7) at per-lane GLOBAL source + on ds_read.
__global__ __launch_bounds__(256) void dist3_k(
    const unsigned short* __restrict__ a_split, const unsigned short* __restrict__ Bemb,
    const float* __restrict__ nrm, unsigned long long* __restrict__ cand) {
  __shared__ short Ah[8192];
  __shared__ short Al[8192];
  __shared__ short Bh[8192];
  __shared__ short Bl[8192];
  int t = threadIdx.x, w = t >> 6, lane = t & 63, lm = lane & 15, hi = lane >> 4;
  int mw = w >> 1, nw = w & 1;
  int b = blockIdx.x;
  int p = (b & 7) * 196 + (b >> 3);
  int nb = p >> 2, mb = p & 3;

  const unsigned short* aTile = a_split + (size_t)mb * 128 * 512;
  const unsigned short* bTile = Bemb + (size_t)nb * 128 * 512;

  int crow[4], csl[4];
#pragma unroll
  for (int i = 0; i < 4; ++i) {
    int p16 = (w * 4 + i) * 64 + lane;
    crow[i] = p16 >> 3;
    csl[i] = ((p16 & 7) ^ (crow[i] & 7)) * 8;
  }

  f32x4 acc[4][4];  // [nf][mf]
#pragma unroll
  for (int nf = 0; nf < 4; ++nf)
#pragma unroll
    for (int mf = 0; mf < 4; ++mf) acc[nf][mf] = (f32x4){0.f, 0.f, 0.f, 0.f};

  const int arow0 = mw * 64;
  const int brow0 = nw * 64;

  // prologue: issue slice 0 (kk=0)
#pragma unroll
  for (int i = 0; i < 4; ++i) {
    gload16(aTile + (size_t)crow[i] * 512 + csl[i], &Ah[(w * 4 + i) * 512]);
    gload16(aTile + (size_t)crow[i] * 512 + 256 + csl[i], &Al[(w * 4 + i) * 512]);
    gload16(bTile + (size_t)crow[i] * 512 + csl[i], &Bh[(w * 4 + i) * 512]);
    gload16(bTile + (size_t)crow[i] * 512 + 256 + csl[i], &Bl[(w * 4 + i) * 512]);
  }

#pragma unroll
  for (int kk = 0; kk < 4; ++kk) {
    asm volatile("s_waitcnt vmcnt(0)" ::: "memory");
    __builtin_amdgcn_s_barrier();
    __builtin_amdgcn_sched_barrier(0);
#pragma unroll
    for (int q2 = 0; q2 < 2; ++q2) {
      bf16x8 fah[4], fal[4], fbh[4], fbl[4];
#pragma unroll
      for (int mf = 0; mf < 4; ++mf) {
        int row = arow0 + mf * 16 + lm;
        int off = row * 64 + (((q2 * 4 + hi) ^ (lm & 7)) * 8);
        fah[mf] = *(const bf16x8*)(&Ah[off]);
        fal[mf] = *(const bf16x8*)(&Al[off]);
      }
#pragma unroll
      for (int nf = 0; nf < 4; ++nf) {
        int row = brow0 + nf * 16 + lm;
        int off = row * 64 + (((q2 * 4 + hi) ^ (lm & 7)) * 8);
        fbh[nf] = *(const bf16x8*)(&Bh[off]);
        fbl[nf] = *(const bf16x8*)(&Bl[off]);
      }
      __builtin_amdgcn_s_setprio(1);
#pragma unroll
      for (int nf = 0; nf < 4; ++nf)
#pragma unroll
        for (int mf = 0; mf < 4; ++mf) {
          acc[nf][mf] = __builtin_amdgcn_mfma_f32_16x16x32_bf16(fbh[nf], fah[mf], acc[nf][mf], 0, 0, 0);
          acc[nf][mf] = __builtin_amdgcn_mfma_f32_16x16x32_bf16(fbl[nf], fah[mf], acc[nf][mf], 0, 0, 0);
          acc[nf][mf] = __builtin_amdgcn_mfma_f32_16x16x32_bf16(fbh[nf], fal[mf], acc[nf][mf], 0, 0, 0);
        }
      __builtin_amdgcn_s_setprio(0);
    }
    if (kk < 3) {
      lds_barrier();  // all waves done reading this slice
      const int ko = (kk + 1) * 64;
#pragma unroll
      for (int i = 0; i < 4; ++i) {
        gload16(aTile + (size_t)crow[i] * 512 + ko + csl[i], &Ah[(w * 4 + i) * 512]);
        gload16(aTile + (size_t)crow[i] * 512 + 256 + ko + csl[i], &Al[(w * 4 + i) * 512]);
        gload16(bTile + (size_t)crow[i] * 512 + ko + csl[i], &Bh[(w * 4 + i) * 512]);
        gload16(bTile + (size_t)crow[i] * 512 + 256 + ko + csl[i], &Bl[(w * 4 + i) * 512]);
      }
    }
  }

  // ---- fused selection: per lane, per mf: sorted-5 of (score|n) u64 keys ----
  const int nbase = nb * 128 + nw * 64;
  const int mbase = mb * 128 + mw * 64;
  unsigned long long Lst[4][5];
#pragma unroll
  for (int mf = 0; mf < 4; ++mf)
#pragma unroll
    for (int j = 0; j < 5; ++j) Lst[mf][j] = ~0ull;

#pragma unroll
  for (int nf = 0; nf < 4; ++nf) {
    int n0 = nbase + nf * 16 + hi * 4;
    float4 nv = *(const float4*)(nrm + n0);
#pragma unroll
    for (int r = 0; r < 4; ++r) {
      int n = n0 + r;
      bool ok = n < 50000;
      float nvr = (r == 0) ? nv.x : (r == 1) ? nv.y : (r == 2) ? nv.z : nv.w;
#pragma unroll
      for (int mf = 0; mf < 4; ++mf) {
        float sc = nvr - 2.f * acc[nf][mf][r];
        unsigned u = __float_as_uint(sc);
        u = ((int)u < 0) ? ~u : (u | 0x80000000u);
        unsigned long long k = ok ? ((((unsigned long long)u) << 32) | (unsigned)n) : ~0ull;
        if (k < Lst[mf][4]) {
          bool b3 = k < Lst[mf][3], b2 = k < Lst[mf][2], b1 = k < Lst[mf][1], b0 = k < Lst[mf][0];
          Lst[mf][4] = b3 ? Lst[mf][3] : k;
          Lst[mf][3] = b3 ? (b2 ? Lst[mf][2] : k) : Lst[mf][3];
          Lst[mf][2] = b2 ? (b1 ? Lst[mf][1] : k) : Lst[mf][2];
          Lst[mf][1] = b1 ? (b0 ? Lst[mf][0] : k) : Lst[mf][1];
          Lst[mf][0] = b0 ? k : Lst[mf][0];
        }
      }
    }
  }
#pragma unroll
  for (int mf = 0; mf < 4; ++mf) {
#pragma unroll
    for (int s = 16; s <= 32; s <<= 1) {
      unsigned long long b0 = shflx64(Lst[mf][0], s), b1 = shflx64(Lst[mf][1], s),
                         b2 = shflx64(Lst[mf][2], s), b3 = shflx64(Lst[mf][3], s),
                         b4 = shflx64(Lst[mf][4], s);
      unsigned long long a0 = Lst[mf][0], a1 = Lst[mf][1], a2 = Lst[mf][2],
                         a3 = Lst[mf][3], a4 = Lst[mf][4];
#pragma unroll
      for (int j = 0; j < 5; ++j) {
        bool ta = a0 <= b0;
        Lst[mf][j] = ta ? a0 : b0;
        unsigned long long na0 = ta ? a1 : a0, na1 = ta ? a2 : a1, na2 = ta ? a3 : a2, na3 = ta ? a4 : a3;
        unsigned long long nb0 = ta ? b0 : b1, nb1 = ta ? b1 : b2, nb2 = ta ? b2 : b3, nb3 = ta ? b3 : b4;
        a0 = na0; a1 = na1; a2 = na2; a3 = na3;
        b0 = nb0; b1 = nb1; b2 = nb2; b3 = nb3;
      }
    }
  }
  if (lane < 16) {
#pragma unroll
    for (int mf = 0; mf < 4; ++mf) {
      size_t base = ((size_t)(mbase + mf * 16 + lm) * 784 + (nb * 2 + nw)) * 5;
#pragma unroll
      for (int j = 0; j < 5; ++j) cand[base + j] = Lst[mf][j];
    }
  }
}

// ---------------- merge2: per row top-5 of 3920 keys, gather+blend ----------------
__global__ __launch_bounds__(64) void merge2_k(
    const unsigned long long* __restrict__ cand, const float* __restrict__ hbuf,
    const float* __restrict__ bufq, const float* __restrict__ out_w,
    const float* __restrict__ out_b, float* __restrict__ qout) {
  int row = blockIdx.x, lane = threadIdx.x;
  unsigned long long L0 = ~0ull, L1 = ~0ull, L2 = ~0ull, L3 = ~0ull, L4 = ~0ull;
  const unsigned long long* cr = cand + (size_t)row * 3920;
  for (int i = lane; i < 3920; i += 64) {
    unsigned long long k = cr[i];
    if (k < L4) {
      bool b3 = k < L3, b2 = k < L2, b1 = k < L1, b0 = k < L0;
      L4 = b3 ? L3 : k;
      L3 = b3 ? (b2 ? L2 : k) : L3;
      L2 = b2 ? (b1 ? L1 : k) : L2;
      L1 = b1 ? (b0 ? L0 : k) : L1;
      L0 = b0 ? k : L0;
    }
  }
#pragma unroll
  for (int s = 1; s < 64; s <<= 1) {
    unsigned long long o0 = shflx64(L0, s), o1 = shflx64(L1, s), o2 = shflx64(L2, s),
                       o3 = shflx64(L3, s), o4 = shflx64(L4, s);
    unsigned long long a0 = L0, a1 = L1, a2 = L2, a3 = L3, a4 = L4;
    unsigned long long b0 = o0, b1 = o1, b2 = o2, b3 = o3, b4 = o4;
    unsigned long long m[5];
#pragma unroll
    for (int j = 0; j < 5; ++j) {
      bool ta = a0 <= b0;
      m[j] = ta ? a0 : b0;
      unsigned long long na0 = ta ? a1 : a0, na1 = ta ? a2 : a1, na2 = ta ? a3 : a2, na3 = ta ? a4 : a3;
      unsigned long long nb0 = ta ? b0 : b1, nb1 = ta ? b1 : b2, nb2 = ta ? b2 : b3, nb3 = ta ? b3 : b4;
      a0 = na0; a1 = na1; a2 = na2; a3 = na3;
      b0 = nb0; b1 = nb1; b2 = nb2; b3 = nb3;
    }
    L0 = m[0]; L1 = m[1]; L2 = m[2]; L3 = m[3]; L4 = m[4];
  }
  int i0 = (int)(L0 & 0xFFFFFFFFu), i1 = (int)(L1 & 0xFFFFFFFFu), i2 = (int)(L2 & 0xFFFFFFFFu);
  int i3 = (int)(L3 & 0xFFFFFFFFu), i4 = (int)(L4 & 0xFFFFFFFFu);
  if (lane < 18) {
    float np = 0.2f * (bufq[(size_t)i0 * 18 + lane] + bufq[(size_t)i1 * 18 + lane] +
                       bufq[(size_t)i2 * 18 + lane] + bufq[(size_t)i3 * 18 + lane] +
                       bufq[(size_t)i4 * 18 + lane]);
    const float* hr = hbuf + row * 256;
    float q = out_b[lane];
    for (int d = 0; d < 256; ++d) q += hr[d] * out_w[d * 18 + lane];
    qout[row * 18 + lane] = 0.5f * q + 0.5f * np;
  }
}

// ================= fallback (round-1 f32 path, unchanged) =================
__global__ __launch_bounds__(320) void conv1_k(
    const float* __restrict__ x, const float* __restrict__ w,
    const float* __restrict__ b, float* __restrict__ y) {
  __shared__ float x_s[4 * 84 * 84];
  int n = blockIdx.x;
  {
    const float4* src = (const float4*)(x + n * 28224);
    float4* dst = (float4*)x_s;
    for (int i = threadIdx.x; i < 7056; i += 320) dst[i] = src[i];
  }
  __syncthreads();
  int t = threadIdx.x;
  int ocg = t / 80, rem = t % 80, oy = rem / 4, oxg = rem % 4;
  float acc[8][5];
#pragma unroll
  for (int r = 0; r < 8; ++r) {
    float bv = b[ocg * 8 + r];
#pragma unroll
    for (int i = 0; i < 5; ++i) acc[r][i] = bv;
  }
  for (int ic = 0; ic < 4; ++ic) {
    for (int ky = 0; ky < 8; ++ky) {
      const float* xrow = x_s + ic * 7056 + (oy * 4 + ky) * 84 + oxg * 20;
      const float* wrow = w + ic * 64 + ky * 8;
#pragma unroll
      for (int kx = 0; kx < 8; ++kx) {
        float xv[5];
#pragma unroll
        for (int i = 0; i < 5; ++i) xv[i] = xrow[i * 4 + kx];
#pragma unroll
        for (int r = 0; r < 8; ++r) {
          float wv = wrow[(ocg * 8 + r) * 256 + kx];
#pragma unroll
          for (int i = 0; i < 5; ++i) acc[r][i] += wv * xv[i];
        }
      }
    }
  }
  float* yb = y + n * 12800 + oy * 20 + oxg * 5;
#pragma unroll
  for (int r = 0; r < 8; ++r)
#pragma unroll
    for (int i = 0; i < 5; ++i)
      yb[(ocg * 8 + r) * 400 + i] = fmaxf(acc[r][i], 0.f);
}

__global__ __launch_bounds__(256) void conv2_k(
    const float* __restrict__ h1, const float* __restrict__ w,
    const float* __restrict__ b, float* __restrict__ y) {
  __shared__ float x_s[32 * 400];
  int n = blockIdx.x;
  {
    const float4* src = (const float4*)(h1 + n * 12800);
    float4* dst = (float4*)x_s;
    for (int i = threadIdx.x; i < 3200; i += 256) dst[i] = src[i];
  }
  __syncthreads();
  int t = threadIdx.x;
  if (t < 216) {
    int ocg = t / 27, rem = t % 27, oy = rem / 3, oxg = rem % 3;
    float acc[8][3];
#pragma unroll
    for (int r = 0; r < 8; ++r) {
      float bv = b[ocg * 8 + r];
#pragma unroll
      for (int i = 0; i < 3; ++i) acc[r][i] = bv;
    }
    const float* xbase = x_s + (oy * 2) * 20 + oxg * 6;
    for (int ic = 0; ic < 32; ++ic) {
#pragma unroll
      for (int ky = 0; ky < 4; ++ky) {
        const float* xr = xbase + ic * 400 + ky * 20;
        const float* wr = w + ic * 16 + ky * 4;
#pragma unroll
        for (int kx = 0; kx < 4; ++kx) {
          float xv0 = xr[kx], xv1 = xr[kx + 2], xv2 = xr[kx + 4];
#pragma unroll
          for (int r = 0; r < 8; ++r) {
            float wv = wr[(ocg * 8 + r) * 512 + kx];
            acc[r][0] += wv * xv0;
            acc[r][1] += wv * xv1;
            acc[r][2] += wv * xv2;
          }
        }
      }
    }
    float* yb = y + n * 5184 + oy * 9 + oxg * 3;
#pragma unroll
    for (int r = 0; r < 8; ++r)
#pragma unroll
      for (int i = 0; i < 3; ++i)
        yb[(ocg * 8 + r) * 81 + i] = fmaxf(acc[r][i], 0.f);
  }
}

__global__ __launch_bounds__(128) void conv3_k(
    const float* __restrict__ h2, const float* __restrict__ w,
    const float* __restrict__ b, float* __restrict__ y) {
  __shared__ float x_s[64 * 81];
  int n = blockIdx.x;
  {
    const float4* src = (const float4*)(h2 + n * 5184);
    float4* dst = (float4*)x_s;
    for (int i = threadIdx.x; i < 1296; i += 128) dst[i] = src[i];
  }
  __syncthreads();
  int t = threadIdx.x;
  if (t < 112) {
    int ocg = t / 7, oy = t % 7;
    float acc[4][7];
#pragma unroll
    for (int r = 0; r < 4; ++r) {
      float bv = b[ocg * 4 + r];
#pragma unroll
      for (int i = 0; i < 7; ++i) acc[r][i] = bv;
    }
    for (int ic = 0; ic < 64; ++ic) {
#pragma unroll
      for (int ky = 0; ky < 3; ++ky) {
        const float* xr = x_s + ic * 81 + (oy + ky) * 9;
        float xv[9];
#pragma unroll
        for (int i = 0; i < 9; ++i) xv[i] = xr[i];
        const float* wr = w + ic * 9 + ky * 3;
#pragma unroll
        for (int kx = 0; kx < 3; ++kx) {
#pragma unroll
          for (int r = 0; r < 4; ++r) {
            float wv = wr[(ocg * 4 + r) * 576 + kx];
#pragma unroll
            for (int i = 0; i < 7; ++i) acc[r][i] += wv * xv[i + kx];
          }
        }
      }
    }
    float* yb = y + n * 3136 + oy * 7;
#pragma unroll
    for (int r = 0; r < 4; ++r)
#pragma unroll
      for (int i = 0; i < 7; ++i)
        yb[(ocg * 4 + r) * 49 + i] = fmaxf(acc[r][i], 0.f);
  }
}

__global__ __launch_bounds__(256) void fc_k(
    const float* __restrict__ h3, const float* __restrict__ fw,
    const float* __restrict__ fb, float* __restrict__ hout,
    unsigned short* __restrict__ a_split) {
  __shared__ float a_s[4 * 3136];
  int n0 = blockIdx.x * 4;
  {
    const float4* src = (const float4*)(h3 + n0 * 3136);
    float4* dst = (float4*)a_s;
    for (int i = threadIdx.x; i < 3136; i += 256) dst[i] = src[i];
  }
  __syncthreads();
  int j = threadIdx.x;
  float a0 = fb[j], a1 = a0, a2 = a0, a3 = a0;
  for (int k = 0; k < 3136; ++k) {
    float wv = fw[k * 256 + j];
    a0 += a_s[k] * wv;
    a1 += a_s[3136 + k] * wv;
    a2 += a_s[2 * 3136 + k] * wv;
    a3 += a_s[3 * 3136 + k] * wv;
  }
  float hv[4];
  hv[0] = fmaxf(a0, 0.f); hv[1] = fmaxf(a1, 0.f);
  hv[2] = fmaxf(a2, 0.f); hv[3] = fmaxf(a3, 0.f);
#pragma unroll
  for (int r = 0; r < 4; ++r) {
    hout[(n0 + r) * 256 + j] = hv[r];
    if (a_split) {
      unsigned short hi = f2bf_rne(hv[r]);
      unsigned short lo = f2bf_rne(hv[r] - bf2f(hi));
      a_split[(size_t)(n0 + r) * 512 + j] = hi;
      a_split[(size_t)(n0 + r) * 512 + 256 + j] = lo;
    }
  }
}

__global__ __launch_bounds__(256) void norm_k(const float* __restrict__ e,
                                              float* __restrict__ nrm) {
  int row = blockIdx.x * 4 + (threadIdx.x >> 6);
  if (row >= 50000) return;
  int lane = threadIdx.x & 63;
  float4 v = ((const float4*)(e + row * 256))[lane];
  float s = v.x * v.x + v.y * v.y + v.z * v.z + v.w * v.w;
  for (int off = 32; off > 0; off >>= 1) s += __shfl_down(s, off);
  if (lane == 0) nrm[row] = s;
}

__global__ __launch_bounds__(256) void dist_topk_k(
    const float* __restrict__ hbuf, const float* __restrict__ emb,
    const float* __restrict__ nrm, float* __restrict__ cand_d,
    int* __restrict__ cand_i) {
  __shared__ float a_s[16 * 256];
  __shared__ float b_s[512 * 17];
  int rb = blockIdx.x & 31, cb = blockIdx.x >> 5;
  int t = threadIdx.x;
  {
    const float4* src = (const float4*)(hbuf + rb * 16 * 256);
    float4* dst = (float4*)a_s;
    for (int i = t; i < 1024; i += 256) dst[i] = src[i];
  }
  float acc[8][4];
#pragma unroll
  for (int r = 0; r < 8; ++r)
#pragma unroll
    for (int c = 0; c < 4; ++c) acc[r][c] = 0.f;
  int ct = t & 127, rt = t >> 7;
  for (int kb = 0; kb < 256; kb += 16) {
    __syncthreads();
    for (int i = t; i < 2048; i += 256) {
      int j = i >> 2, kq = i & 3;
      int jg = cb * 512 + j;
      float4 v = make_float4(0.f, 0.f, 0.f, 0.f);
      if (jg < 50000) v = *(const float4*)(emb + jg * 256 + kb + kq * 4);
      float* dst = b_s + j * 17 + kq * 4;
      dst[0] = v.x; dst[1] = v.y; dst[2] = v.z; dst[3] = v.w;
    }
    __syncthreads();
#pragma unroll
    for (int k = 0; k < 16; ++k) {
      float av[8];
#pragma unroll
      for (int r = 0; r < 8; ++r) av[r] = a_s[(rt * 8 + r) * 256 + kb + k];
#pragma unroll
      for (int cc = 0; cc < 4; ++cc) {
        float bv = b_s[(ct + cc * 128) * 17 + k];
#pragma unroll
        for (int r = 0; r < 8; ++r) acc[r][cc] += av[r] * bv;
      }
    }
  }
  __syncthreads();
  float* score = b_s;
#pragma unroll
  for (int cc = 0; cc < 4; ++cc) {
    int c = ct + cc * 128;
    int jg = cb * 512 + c;
    float nv = (jg < 50000) ? nrm[jg] : 0.f;
#pragma unroll
    for (int r = 0; r < 8; ++r)
      score[(rt * 8 + r) * 512 + c] = (jg < 50000) ? (nv - 2.f * acc[r][cc]) : FINF;
  }
  __syncthreads();
  int wave = t >> 6, lane = t & 63;
  for (int rr = 0; rr < 4; ++rr) {
    int r = wave * 4 + rr;
    float v[8];
#pragma unroll
    for (int i = 0; i < 8; ++i) v[i] = score[r * 512 + lane + i * 64];
    for (int it = 0; it < 5; ++it) {
      float bv = v[0];
      int bc = lane;
#pragma unroll
      for (int i = 1; i < 8; ++i) {
        float xv = v[i];
        int c = lane + i * 64;
        if (xv < bv) { bv = xv; bc = c; }
      }
      for (int off = 32; off > 0; off >>= 1) {
        float ov = __shfl_down(bv, off);
        int ocx = __shfl_down(bc, off);
        if (ov < bv || (ov == bv && ocx < bc)) { bv = ov; bc = ocx; }
      }
      bv = __shfl(bv, 0);
      bc = __shfl(bc, 0);
      if (lane == 0) {
        int row_g = rb * 16 + r;
        int slot = (row_g * 98 + cb) * 5 + it;
        cand_d[slot] = bv;
        cand_i[slot] = cb * 512 + bc;
      }
#pragma unroll
      for (int i = 0; i < 8; ++i)
        if (lane + i * 64 == bc) v[i] = FINF;
    }
  }
}

__global__ __launch_bounds__(64) void merge_k(
    const float* __restrict__ cand_d, const int* __restrict__ cand_i,
    const float* __restrict__ hbuf, const float* __restrict__ bufq,
    const float* __restrict__ out_w, const float* __restrict__ out_b,
    float* __restrict__ qout) {
  int row = blockIdx.x, lane = threadIdx.x;
  __shared__ float sd[490];
  __shared__ int si[490];
  __shared__ int win[5];
  for (int i = lane; i < 490; i += 64) {
    sd[i] = cand_d[row * 490 + i];
    si[i] = cand_i[row * 490 + i];
  }
  __syncthreads();
  float v[8];
  int ix[8];
#pragma unroll
  for (int i = 0; i < 8; ++i) {
    int s = lane + i * 64;
    v[i] = (s < 490) ? sd[s] : FINF;
    ix[i] = (s < 490) ? si[s] : 0x7fffffff;
  }
  for (int it = 0; it < 5; ++it) {
    float bv = v[0];
    int bi = ix[0];
#pragma unroll
    for (int i = 1; i < 8; ++i)
      if (v[i] < bv || (v[i] == bv && ix[i] < bi)) { bv = v[i]; bi = ix[i]; }
    for (int off = 32; off > 0; off >>= 1) {
      float ov = __shfl_down(bv, off);
      int oi = __shfl_down(bi, off);
      if (ov < bv || (ov == bv && oi < bi)) { bv = ov; bi = oi; }
    }
    bi = __shfl(bi, 0);
    if (lane == 0) win[it] = bi;
#pragma unroll
    for (int i = 0; i < 8; ++i)
      if (ix[i] == bi) v[i] = FINF;
  }
  __syncthreads();
  if (lane < 18) {
    float np = 0.f;
#pragma unroll
    for (int it = 0; it < 5; ++it) np += bufq[win[it] * 18 + lane];
    np *= 0.2f;
    const float* hr = hbuf + row * 256;
    float q = out_b[lane];
    for (int d = 0; d < 256; ++d) q += hr[d] * out_w[d * 18 + lane];
    qout[row * 18 + lane] = 0.5f * q + 0.5f * np;
  }
}

extern "C" void kernel_launch(void* const* d_in, const int* in_sizes, int n_in,
                              void* d_out, int out_size, void* d_ws, size_t ws_size,
                              hipStream_t stream) {
  const float* x       = (const float*)d_in[0];
  const float* conv1_w = (const float*)d_in[1];
  const float* conv1_b = (const float*)d_in[2];
  const float* conv2_w = (const float*)d_in[3];
  const float* conv2_b = (const float*)d_in[4];
  const float* conv3_w = (const float*)d_in[5];
  const float* conv3_b = (const float*)d_in[6];
  const float* fc_w    = (const float*)d_in[7];
  const float* fc_b    = (const float*)d_in[8];
  const float* out_w   = (const float*)d_in[9];
  const float* out_b   = (const float*)d_in[10];
  const float* buf_emb = (const float*)d_in[11];
  const float* buf_q   = (const float*)d_in[12];

  float* out = (float*)d_out;  // [0,9216): q_blend; [9216,...): h
  float* hout = out + 9216;

  float* ws = (float*)d_ws;
  // mfma-path layout (float offsets into ws)
  unsigned short* h1s  = (unsigned short*)(ws);               // [0, 6,553,600 f)
  unsigned short* h2s  = (unsigned short*)(ws + 6553600);     // [6,553,600, 9,207,808 f)
  unsigned short* h3hi = (unsigned short*)(ws);               // reuses dead h1 region
  unsigned short* h3lo = (unsigned short*)(ws + 802816);
  unsigned short* Bs1h = (unsigned short*)(ws + 6553600);     // in h2s region (dead until conv2m)
  unsigned short* Bs1l = (unsigned short*)(ws + 6557696);
  float* nrm = ws + 9207808;                                  // [9,207,808, 9,257,984 f)
  unsigned long long* cand = (unsigned long long*)(ws + 9257984);  // [9,257,984, 13,272,064 f)
  // overlays inside cand region (dead before dist3 writes cand):
  unsigned short* Bs2h = (unsigned short*)(ws + 9257984);
  unsigned short* Bs2l = (unsigned short*)(ws + 9274368);
  unsigned short* Bs3h = (unsigned short*)(ws + 9290752);
  unsigned short* Bs3l = (unsigned short*)(ws + 9309184);     // ends 9,327,616 f
  unsigned short* fwhi = (unsigned short*)(ws + 9327616);
  unsigned short* fwlo = (unsigned short*)(ws + 9729024);     // ends 10,130,432 f
  float* hpre = ws + 10130432;
  unsigned short* a_split = (unsigned short*)(ws + 13272064); // 512 rows x 512 sh = 131,072 f
  unsigned short* Bemb = (unsigned short*)(ws + 13468672);    // ends 26,313,728 f
  const size_t NEED = 105254912ull;

  bool mfma_path = (ws_size >= NEED);

  if (mfma_path) {
    prep_k<<<238, 256, 0, stream>>>(conv1_w, Bs1h, Bs1l, conv2_w, Bs2h, Bs2l,
                                    conv3_w, Bs3h, Bs3l, fc_w, fwhi, fwlo);
    embcvt_k<<<12500, 256, 0, stream>>>(buf_emb, Bemb, nrm);
    conv1m_k<<<800, 256, 0, stream>>>(x, Bs1h, Bs1l, conv1_b, h1s);
    conv2m_k<<<162, 256, 0, stream>>>(h1s, Bs2h, Bs2l, conv2_b, h2s);
    conv3m_k<<<98, 256, 0, stream>>>(h2s, Bs3h, Bs3l, conv3_b, h3hi, h3lo);
    fc2_k<<<112, 256, 0, stream>>>(h3hi, h3lo, fwhi, fwlo, hpre);
    fc_post_k<<<512, 256, 0, stream>>>(hpre, fc_b, hout, a_split);
    dist3_k<<<1568, 256, 0, stream>>>(a_split, Bemb, nrm, cand);
    merge2_k<<<512, 64, 0, stream>>>(cand, hout, buf_q, out_w, out_b, out);
  } else {
    // round-1 f32 fallback
    float* h1 = ws;
    float* h2 = h1 + 6553600;
    float* h3 = ws;
    float* nrm_o = h2 + 2654208;
    float* cand_d = nrm_o + 50000;
    int* cand_i = (int*)(cand_d + 250880);
    conv1_k<<<512, 320, 0, stream>>>(x, conv1_w, conv1_b, h1);
    conv2_k<<<512, 256, 0, stream>>>(h1, conv2_w, conv2_b, h2);
    conv3_k<<<512, 128, 0, stream>>>(h2, conv3_w, conv3_b, h3);
    fc_k<<<128, 256, 0, stream>>>(h3, fc_w, fc_b, hout, nullptr);
    norm_k<<<12500, 256, 0, stream>>>(buf_emb, nrm_o);
    dist_topk_k<<<3136, 256, 0, stream>>>(hout, buf_emb, nrm_o, cand_d, cand_i);
    merge_k<<<512, 64, 0, stream>>>(cand_d, cand_i, hout, buf_q, out_w, out_b, out);
  }
}

// Round 20
// 231.759 us; speedup vs baseline: 1.3215x; 1.0432x over previous
//
#include <hip/hip_runtime.h>
#include <hip/hip_bf16.h>

#define FINF 3.402823466e38f

typedef short bf16x8 __attribute__((ext_vector_type(8)));
typedef float f32x4 __attribute__((ext_vector_type(4)));

__device__ __forceinline__ unsigned short f2bf_rne(float f) {
  unsigned u = __float_as_uint(f);
  unsigned r = u + 0x7fff + ((u >> 16) & 1);
  return (unsigned short)(r >> 16);
}
__device__ __forceinline__ float bf2f(unsigned short u) {
  return __uint_as_float(((unsigned)u) << 16);
}
__device__ __forceinline__ unsigned long long shflx64(unsigned long long v, int m) {
  unsigned lo = __shfl_xor((unsigned)(v & 0xFFFFFFFFu), m, 64);
  unsigned hi = __shfl_xor((unsigned)(v >> 32), m, 64);
  return (((unsigned long long)hi) << 32) | lo;
}
// raw barrier: waits LDS ops only, leaves global prefetches in flight
__device__ __forceinline__ void lds_barrier() {
  asm volatile("s_waitcnt lgkmcnt(0)" ::: "memory");
  __builtin_amdgcn_s_barrier();
  __builtin_amdgcn_sched_barrier(0);
}
// wave-local LDS sync: ds_write -> ds_read within ONE wave needs only lgkmcnt,
// no s_barrier (rule #18: sched_barrier stops MFMA hoisting past the wait)
__device__ __forceinline__ void wave_sync() {
  asm volatile("s_waitcnt lgkmcnt(0)" ::: "memory");
  __builtin_amdgcn_sched_barrier(0);
}
// async global->LDS, 16B per lane; LDS dest = uniform base + lane*16
__device__ __forceinline__ void gload16(const unsigned short* g, short* l) {
  __builtin_amdgcn_global_load_lds(
      (const __attribute__((address_space(1))) unsigned int*)g,
      (__attribute__((address_space(3))) unsigned int*)l, 16, 0, 0);
}

// ---------------- prep: all weight conversions fused into one launch ----------------
__global__ __launch_bounds__(256) void prep_k(
    const float* __restrict__ w1, unsigned short* __restrict__ b1h, unsigned short* __restrict__ b1l,
    const float* __restrict__ w2, unsigned short* __restrict__ b2h, unsigned short* __restrict__ b2l,
    const float* __restrict__ w3, unsigned short* __restrict__ b3h, unsigned short* __restrict__ b3l,
    const float* __restrict__ fw, unsigned short* __restrict__ fwhi, unsigned short* __restrict__ fwlo) {
  __shared__ float tile[64][65];
  int b = blockIdx.x, t = threadIdx.x;
  if (b < 8) {
    if (t < 128) {
      int ky = b;
      int nf = t >> 6, l = t & 63;
      int oc = nf * 16 + (l & 15), ic = l >> 4;
      bf16x8 hv, lv;
#pragma unroll
      for (int j = 0; j < 8; ++j) {
        float v = w1[((oc * 4 + ic) * 8 + ky) * 8 + j];
        unsigned short h = f2bf_rne(v);
        hv[j] = (short)h;
        lv[j] = (short)f2bf_rne(v - bf2f(h));
      }
      *(bf16x8*)(&b1h[((size_t)(ky * 2 + nf) * 64 + l) * 8]) = hv;
      *(bf16x8*)(&b1l[((size_t)(ky * 2 + nf) * 64 + l) * 8]) = lv;
    }
  } else if (b < 24) {
    int tap = b - 8, ky = tap >> 2, kx = tap & 3;
    int nf = t >> 6, l = t & 63;
    int oc = nf * 16 + (l & 15);
    bf16x8 hv, lv;
#pragma unroll
    for (int j = 0; j < 8; ++j) {
      int ic = (l >> 4) * 8 + j;
      float v = w2[((oc * 32 + ic) * 4 + ky) * 4 + kx];
      unsigned short h = f2bf_rne(v);
      hv[j] = (short)h;
      lv[j] = (short)f2bf_rne(v - bf2f(h));
    }
    *(bf16x8*)(&b2h[((size_t)(tap * 4 + nf) * 64 + l) * 8]) = hv;
    *(bf16x8*)(&b2l[((size_t)(tap * 4 + nf) * 64 + l) * 8]) = lv;
  } else if (b < 42) {
    int tt = b - 24, tap = tt >> 1, half = tt & 1, ky = tap / 3, kx = tap % 3;
    int nf = t >> 6, l = t & 63;
    int oc = nf * 16 + (l & 15);
    bf16x8 hv, lv;
#pragma unroll
    for (int j = 0; j < 8; ++j) {
      int ic = half * 32 + (l >> 4) * 8 + j;
      float v = w3[((oc * 64 + ic) * 3 + ky) * 3 + kx];
      unsigned short h = f2bf_rne(v);
      hv[j] = (short)h;
      lv[j] = (short)f2bf_rne(v - bf2f(h));
    }
    *(bf16x8*)(&b3h[((size_t)(tt * 4 + nf) * 64 + l) * 8]) = hv;
    *(bf16x8*)(&b3l[((size_t)(tt * 4 + nf) * 64 + l) * 8]) = lv;
  } else {
    int idx = b - 42, p = idx % 49, nb = idx / 49;
#pragma unroll
    for (int i = 0; i < 16; ++i) {
      int c = (t >> 6) * 16 + i;
      tile[c][t & 63] = fw[(c * 49 + p) * 256 + nb * 64 + (t & 63)];
    }
    __syncthreads();
#pragma unroll
    for (int i = 0; i < 16; ++i) {
      int n2 = (t >> 6) * 16 + i, c2 = t & 63;
      float v = tile[c2][n2];
      unsigned short h = f2bf_rne(v);
      size_t o = (size_t)(nb * 64 + n2) * 3136 + p * 64 + c2;
      fwhi[o] = h;
      fwlo[o] = f2bf_rne(v - bf2f(h));
    }
  }
}

// ---------------- conv1m: x f32 -> h1s NHWC [204800 pix][32hi|32lo], 8-tap MFMA ----------------
// 1-wave blocks (all LDS/sync wave-local): grid 3200 x 64.
__global__ __launch_bounds__(64) void conv1m_k(
    const float* __restrict__ x,
    const unsigned short* __restrict__ bh, const unsigned short* __restrict__ bl,
    const float* __restrict__ bias, unsigned short* __restrict__ h1s) {
  __shared__ short As[64 * 72];  // row*72: [0,32)=hi (4ic x 8kx), [36,68)=lo
  int t = threadIdx.x, lane = t, lm = lane & 15, hi4 = lane >> 4;
  int m = blockIdx.x * 64 + t;
  int n = m / 400, p = m % 400, oy = p / 20, ox = p % 20;
  size_t xoff = (size_t)n * 28224 + (size_t)(oy * 4) * 84 + ox * 4;  // + ic*7056 + ky*84
  f32x4 acc[4][2];
#pragma unroll
  for (int mf = 0; mf < 4; ++mf)
#pragma unroll
    for (int nf = 0; nf < 2; ++nf) acc[mf][nf] = (f32x4){0.f, 0.f, 0.f, 0.f};

  float4 fa[8];  // current tap: [ic*2 + half]
#pragma unroll
  for (int ic = 0; ic < 4; ++ic) {
    fa[ic * 2 + 0] = *(const float4*)(x + xoff + ic * 7056);
    fa[ic * 2 + 1] = *(const float4*)(x + xoff + ic * 7056 + 4);
  }
  const unsigned short* bfp = bh + (size_t)lane * 8;
  const unsigned short* blp = bl + (size_t)lane * 8;
  bf16x8 cbh[2], cbl[2];
#pragma unroll
  for (int nf = 0; nf < 2; ++nf) {
    cbh[nf] = *(const bf16x8*)(bfp + nf * 512);
    cbl[nf] = *(const bf16x8*)(blp + nf * 512);
  }
#pragma unroll
  for (int ky = 0; ky < 8; ++ky) {
    if (ky) wave_sync();  // own-wave reads of previous tap done
    {
      short* wp = &As[t * 72];
#pragma unroll
      for (int ic = 0; ic < 4; ++ic) {
        float e0 = fa[ic * 2].x, e1 = fa[ic * 2].y, e2 = fa[ic * 2].z, e3 = fa[ic * 2].w;
        float e4 = fa[ic * 2 + 1].x, e5 = fa[ic * 2 + 1].y, e6 = fa[ic * 2 + 1].z, e7 = fa[ic * 2 + 1].w;
        bf16x8 hv, lv;
        unsigned short h;
        h = f2bf_rne(e0); hv[0] = (short)h; lv[0] = (short)f2bf_rne(e0 - bf2f(h));
        h = f2bf_rne(e1); hv[1] = (short)h; lv[1] = (short)f2bf_rne(e1 - bf2f(h));
        h = f2bf_rne(e2); hv[2] = (short)h; lv[2] = (short)f2bf_rne(e2 - bf2f(h));
        h = f2bf_rne(e3); hv[3] = (short)h; lv[3] = (short)f2bf_rne(e3 - bf2f(h));
        h = f2bf_rne(e4); hv[4] = (short)h; lv[4] = (short)f2bf_rne(e4 - bf2f(h));
        h = f2bf_rne(e5); hv[5] = (short)h; lv[5] = (short)f2bf_rne(e5 - bf2f(h));
        h = f2bf_rne(e6); hv[6] = (short)h; lv[6] = (short)f2bf_rne(e6 - bf2f(h));
        h = f2bf_rne(e7); hv[7] = (short)h; lv[7] = (short)f2bf_rne(e7 - bf2f(h));
        *(bf16x8*)(wp + ic * 8) = hv;
        *(bf16x8*)(wp + 36 + ic * 8) = lv;
      }
    }
    wave_sync();  // own writes visible to own reads
    bf16x8 nbh[2], nbl[2];
    if (ky < 7) {
      size_t ap = xoff + (size_t)(ky + 1) * 84;
#pragma unroll
      for (int ic = 0; ic < 4; ++ic) {
        fa[ic * 2 + 0] = *(const float4*)(x + ap + ic * 7056);
        fa[ic * 2 + 1] = *(const float4*)(x + ap + ic * 7056 + 4);
      }
#pragma unroll
      for (int nf = 0; nf < 2; ++nf) {
        nbh[nf] = *(const bf16x8*)(bfp + ((ky + 1) * 2 + nf) * 512);
        nbl[nf] = *(const bf16x8*)(blp + ((ky + 1) * 2 + nf) * 512);
      }
    }
    bf16x8 ah[4], al[4];
#pragma unroll
    for (int mf = 0; mf < 4; ++mf) {
      const short* rp = &As[(mf * 16 + lm) * 72 + hi4 * 8];
      ah[mf] = *(const bf16x8*)(rp);
      al[mf] = *(const bf16x8*)(rp + 36);
    }
#pragma unroll
    for (int mf = 0; mf < 4; ++mf)
#pragma unroll
      for (int nf = 0; nf < 2; ++nf) {
        acc[mf][nf] = __builtin_amdgcn_mfma_f32_16x16x32_bf16(ah[mf], cbh[nf], acc[mf][nf], 0, 0, 0);
        acc[mf][nf] = __builtin_amdgcn_mfma_f32_16x16x32_bf16(ah[mf], cbl[nf], acc[mf][nf], 0, 0, 0);
        acc[mf][nf] = __builtin_amdgcn_mfma_f32_16x16x32_bf16(al[mf], cbh[nf], acc[mf][nf], 0, 0, 0);
      }
    if (ky < 7) {
#pragma unroll
      for (int nf = 0; nf < 2; ++nf) { cbh[nf] = nbh[nf]; cbl[nf] = nbl[nf]; }
    }
  }
  float bv[2];
#pragma unroll
  for (int nf = 0; nf < 2; ++nf) bv[nf] = bias[nf * 16 + lm];
#pragma unroll
  for (int mf = 0; mf < 4; ++mf)
#pragma unroll
    for (int nf = 0; nf < 2; ++nf)
#pragma unroll
      for (int r = 0; r < 4; ++r) {
        size_t mrow = (size_t)blockIdx.x * 64 + mf * 16 + hi4 * 4 + r;
        float v = fmaxf(acc[mf][nf][r] + bv[nf], 0.f);
        unsigned short h = f2bf_rne(v);
        h1s[mrow * 64 + nf * 16 + lm] = h;
        h1s[mrow * 64 + 32 + nf * 16 + lm] = f2bf_rne(v - bf2f(h));
      }
}

// ---------------- conv2m: h1s NHWC -> h2s [41472 pix][64hi|64lo], 16-tap MFMA, 1-wave blocks ----------------
__global__ __launch_bounds__(64) void conv2m_k(
    const unsigned short* __restrict__ h1s, const unsigned short* __restrict__ bh,
    const unsigned short* __restrict__ bl, const float* __restrict__ bias,
    unsigned short* __restrict__ h2s) {
  __shared__ short As[64 * 72];
  int t = threadIdx.x, lane = t, lm = lane & 15, hi4 = lane >> 4;
  int m = blockIdx.x * 64 + t;
  int n = m / 81, p = m % 81, oy = p / 9, ox = p % 9;
  const unsigned short* abase = h1s + (size_t)(n * 400 + oy * 40 + ox * 2) * 64;
  f32x4 acc[4][4];
#pragma unroll
  for (int mf = 0; mf < 4; ++mf)
#pragma unroll
    for (int nf = 0; nf < 4; ++nf) acc[mf][nf] = (f32x4){0.f, 0.f, 0.f, 0.f};

  bf16x8 s0, s1, s2, s3, s4, s5, s6, s7;
  {
    const unsigned short* ap = abase;  // tap 0
    s0 = *(const bf16x8*)(ap);      s1 = *(const bf16x8*)(ap + 8);
    s2 = *(const bf16x8*)(ap + 16); s3 = *(const bf16x8*)(ap + 24);
    s4 = *(const bf16x8*)(ap + 32); s5 = *(const bf16x8*)(ap + 40);
    s6 = *(const bf16x8*)(ap + 48); s7 = *(const bf16x8*)(ap + 56);
  }
  const unsigned short* bfp = bh + (size_t)lane * 8;
  const unsigned short* blp = bl + (size_t)lane * 8;
  bf16x8 cbh[4], cbl[4];
#pragma unroll
  for (int nf = 0; nf < 4; ++nf) {
    cbh[nf] = *(const bf16x8*)(bfp + nf * 512);
    cbl[nf] = *(const bf16x8*)(blp + nf * 512);
  }
#pragma unroll
  for (int tap = 0; tap < 16; ++tap) {
    if (tap) wave_sync();
    {
      short* wp = &As[t * 72];
      *(bf16x8*)(wp) = s0;      *(bf16x8*)(wp + 8) = s1;
      *(bf16x8*)(wp + 16) = s2; *(bf16x8*)(wp + 24) = s3;
      *(bf16x8*)(wp + 36) = s4; *(bf16x8*)(wp + 44) = s5;
      *(bf16x8*)(wp + 52) = s6; *(bf16x8*)(wp + 60) = s7;
    }
    wave_sync();
    bf16x8 nbh[4], nbl[4];
    if (tap < 15) {
      const unsigned short* ap = abase + (((tap + 1) >> 2) * 1280 + ((tap + 1) & 3) * 64);
      s0 = *(const bf16x8*)(ap);      s1 = *(const bf16x8*)(ap + 8);
      s2 = *(const bf16x8*)(ap + 16); s3 = *(const bf16x8*)(ap + 24);
      s4 = *(const bf16x8*)(ap + 32); s5 = *(const bf16x8*)(ap + 40);
      s6 = *(const bf16x8*)(ap + 48); s7 = *(const bf16x8*)(ap + 56);
#pragma unroll
      for (int nf = 0; nf < 4; ++nf) {
        nbh[nf] = *(const bf16x8*)(bfp + ((tap + 1) * 4 + nf) * 512);
        nbl[nf] = *(const bf16x8*)(blp + ((tap + 1) * 4 + nf) * 512);
      }
    }
    bf16x8 ah[4], al[4];
#pragma unroll
    for (int mf = 0; mf < 4; ++mf) {
      const short* rp = &As[(mf * 16 + lm) * 72 + hi4 * 8];
      ah[mf] = *(const bf16x8*)(rp);
      al[mf] = *(const bf16x8*)(rp + 36);
    }
#pragma unroll
    for (int mf = 0; mf < 4; ++mf)
#pragma unroll
      for (int nf = 0; nf < 4; ++nf) {
        acc[mf][nf] = __builtin_amdgcn_mfma_f32_16x16x32_bf16(ah[mf], cbh[nf], acc[mf][nf], 0, 0, 0);
        acc[mf][nf] = __builtin_amdgcn_mfma_f32_16x16x32_bf16(ah[mf], cbl[nf], acc[mf][nf], 0, 0, 0);
        acc[mf][nf] = __builtin_amdgcn_mfma_f32_16x16x32_bf16(al[mf], cbh[nf], acc[mf][nf], 0, 0, 0);
      }
    if (tap < 15) {
#pragma unroll
      for (int nf = 0; nf < 4; ++nf) { cbh[nf] = nbh[nf]; cbl[nf] = nbl[nf]; }
    }
  }
  float bv[4];
#pragma unroll
  for (int nf = 0; nf < 4; ++nf) bv[nf] = bias[nf * 16 + lm];
#pragma unroll
  for (int mf = 0; mf < 4; ++mf)
#pragma unroll
    for (int nf = 0; nf < 4; ++nf)
#pragma unroll
      for (int r = 0; r < 4; ++r) {
        size_t mrow = (size_t)blockIdx.x * 64 + mf * 16 + hi4 * 4 + r;
        float v = fmaxf(acc[mf][nf][r] + bv[nf], 0.f);
        unsigned short h = f2bf_rne(v);
        h2s[mrow * 128 + nf * 16 + lm] = h;
        h2s[mrow * 128 + 64 + nf * 16 + lm] = f2bf_rne(v - bf2f(h));
      }
}

// ---------------- conv3m: h2s -> h3hi/h3lo [25088 pix][64], 18-chunk MFMA, 1-wave blocks ----------------
__global__ __launch_bounds__(64) void conv3m_k(
    const unsigned short* __restrict__ h2s, const unsigned short* __restrict__ bh,
    const unsigned short* __restrict__ bl, const float* __restrict__ bias,
    unsigned short* __restrict__ h3hi, unsigned short* __restrict__ h3lo) {
  __shared__ short As[64 * 72];
  int t = threadIdx.x, lane = t, lm = lane & 15, hi4 = lane >> 4;
  int m = blockIdx.x * 64 + t;
  int n = m / 49, p = m % 49, oy = p / 7, ox = p % 7;
  const unsigned short* abase = h2s + (size_t)(n * 81 + oy * 9 + ox) * 128;
  f32x4 acc[4][4];
#pragma unroll
  for (int mf = 0; mf < 4; ++mf)
#pragma unroll
    for (int nf = 0; nf < 4; ++nf) acc[mf][nf] = (f32x4){0.f, 0.f, 0.f, 0.f};

  bf16x8 s0, s1, s2, s3, s4, s5, s6, s7;
  {
    const unsigned short* ap = abase;
    s0 = *(const bf16x8*)(ap);      s1 = *(const bf16x8*)(ap + 8);
    s2 = *(const bf16x8*)(ap + 16); s3 = *(const bf16x8*)(ap + 24);
    s4 = *(const bf16x8*)(ap + 64); s5 = *(const bf16x8*)(ap + 72);
    s6 = *(const bf16x8*)(ap + 80); s7 = *(const bf16x8*)(ap + 88);
  }
  const unsigned short* bfp = bh + (size_t)lane * 8;
  const unsigned short* blp = bl + (size_t)lane * 8;
  bf16x8 cbh[4], cbl[4];
#pragma unroll
  for (int nf = 0; nf < 4; ++nf) {
    cbh[nf] = *(const bf16x8*)(bfp + nf * 512);
    cbl[nf] = *(const bf16x8*)(blp + nf * 512);
  }
#pragma unroll
  for (int tt = 0; tt < 18; ++tt) {
    if (tt) wave_sync();
    {
      short* wp = &As[t * 72];
      *(bf16x8*)(wp) = s0;      *(bf16x8*)(wp + 8) = s1;
      *(bf16x8*)(wp + 16) = s2; *(bf16x8*)(wp + 24) = s3;
      *(bf16x8*)(wp + 36) = s4; *(bf16x8*)(wp + 44) = s5;
      *(bf16x8*)(wp + 52) = s6; *(bf16x8*)(wp + 60) = s7;
    }
    wave_sync();
    bf16x8 nbh[4], nbl[4];
    if (tt < 17) {
      const int tn = tt + 1, tapn = tn >> 1, halfn = tn & 1;
      const unsigned short* ap = abase + ((tapn / 3) * 9 + (tapn % 3)) * 128 + halfn * 32;
      s0 = *(const bf16x8*)(ap);      s1 = *(const bf16x8*)(ap + 8);
      s2 = *(const bf16x8*)(ap + 16); s3 = *(const bf16x8*)(ap + 24);
      s4 = *(const bf16x8*)(ap + 64); s5 = *(const bf16x8*)(ap + 72);
      s6 = *(const bf16x8*)(ap + 80); s7 = *(const bf16x8*)(ap + 88);
#pragma unroll
      for (int nf = 0; nf < 4; ++nf) {
        nbh[nf] = *(const bf16x8*)(bfp + ((tt + 1) * 4 + nf) * 512);
        nbl[nf] = *(const bf16x8*)(blp + ((tt + 1) * 4 + nf) * 512);
      }
    }
    bf16x8 ah[4], al[4];
#pragma unroll
    for (int mf = 0; mf < 4; ++mf) {
      const short* rp = &As[(mf * 16 + lm) * 72 + hi4 * 8];
      ah[mf] = *(const bf16x8*)(rp);
      al[mf] = *(const bf16x8*)(rp + 36);
    }
#pragma unroll
    for (int mf = 0; mf < 4; ++mf)
#pragma unroll
      for (int nf = 0; nf < 4; ++nf) {
        acc[mf][nf] = __builtin_amdgcn_mfma_f32_16x16x32_bf16(ah[mf], cbh[nf], acc[mf][nf], 0, 0, 0);
        acc[mf][nf] = __builtin_amdgcn_mfma_f32_16x16x32_bf16(ah[mf], cbl[nf], acc[mf][nf], 0, 0, 0);
        acc[mf][nf] = __builtin_amdgcn_mfma_f32_16x16x32_bf16(al[mf], cbh[nf], acc[mf][nf], 0, 0, 0);
      }
    if (tt < 17) {
#pragma unroll
      for (int nf = 0; nf < 4; ++nf) { cbh[nf] = nbh[nf]; cbl[nf] = nbl[nf]; }
    }
  }
  float bv[4];
#pragma unroll
  for (int nf = 0; nf < 4; ++nf) bv[nf] = bias[nf * 16 + lm];
#pragma unroll
  for (int mf = 0; mf < 4; ++mf)
#pragma unroll
    for (int nf = 0; nf < 4; ++nf)
#pragma unroll
      for (int r = 0; r < 4; ++r) {
        size_t mrow = (size_t)blockIdx.x * 64 + mf * 16 + hi4 * 4 + r;
        float v = fmaxf(acc[mf][nf][r] + bv[nf], 0.f);
        unsigned short h = f2bf_rne(v);
        h3hi[mrow * 64 + nf * 16 + lm] = h;
        h3lo[mrow * 64 + nf * 16 + lm] = f2bf_rne(v - bf2f(h));
      }
}

// ---------------- fc2: split-bf16 MFMA, 1-wave blocks: grid 8mb x 14kc x 4nw ----------------
__global__ __launch_bounds__(64) void fc2_k(
    const unsigned short* __restrict__ h3hi, const unsigned short* __restrict__ h3lo,
    const unsigned short* __restrict__ fwhi, const unsigned short* __restrict__ fwlo,
    float* __restrict__ hpre) {
  int t = threadIdx.x, lane = t, lm = lane & 15, hi4 = lane >> 4;
  int b = blockIdx.x;
  int mb = b / 56, r56 = b % 56, kc = r56 >> 2, nw = r56 & 3;
  int m0 = mb * 64, n0 = nw * 64;
  size_t kof = (size_t)kc * 224 + hi4 * 8;
  const unsigned short* pah[4]; const unsigned short* pal[4];
  const unsigned short* pbh[4]; const unsigned short* pbl[4];
#pragma unroll
  for (int mf = 0; mf < 4; ++mf) {
    pah[mf] = h3hi + (size_t)(m0 + mf * 16 + lm) * 3136 + kof;
    pal[mf] = h3lo + (size_t)(m0 + mf * 16 + lm) * 3136 + kof;
  }
#pragma unroll
  for (int nf = 0; nf < 4; ++nf) {
    pbh[nf] = fwhi + (size_t)(n0 + nf * 16 + lm) * 3136 + kof;
    pbl[nf] = fwlo + (size_t)(n0 + nf * 16 + lm) * 3136 + kof;
  }
  f32x4 acc[4][4];
#pragma unroll
  for (int mf = 0; mf < 4; ++mf)
#pragma unroll
    for (int nf = 0; nf < 4; ++nf) acc[mf][nf] = (f32x4){0.f, 0.f, 0.f, 0.f};
  bf16x8 cah[4], cal[4], cbh[4], cbl[4];
#pragma unroll
  for (int i = 0; i < 4; ++i) {
    cah[i] = *(const bf16x8*)(pah[i]); cal[i] = *(const bf16x8*)(pal[i]);
    cbh[i] = *(const bf16x8*)(pbh[i]); cbl[i] = *(const bf16x8*)(pbl[i]);
  }
#pragma unroll
  for (int ks = 0; ks < 7; ++ks) {
    bf16x8 nah[4], nal[4], nbh[4], nbl[4];
    if (ks < 6) {
      const int off = (ks + 1) * 32;
#pragma unroll
      for (int i = 0; i < 4; ++i) {
        nah[i] = *(const bf16x8*)(pah[i] + off); nal[i] = *(const bf16x8*)(pal[i] + off);
        nbh[i] = *(const bf16x8*)(pbh[i] + off); nbl[i] = *(const bf16x8*)(pbl[i] + off);
      }
    }
#pragma unroll
    for (int mf = 0; mf < 4; ++mf)
#pragma unroll
      for (int nf = 0; nf < 4; ++nf) {
        acc[mf][nf] = __builtin_amdgcn_mfma_f32_16x16x32_bf16(cah[mf], cbh[nf], acc[mf][nf], 0, 0, 0);
        acc[mf][nf] = __builtin_amdgcn_mfma_f32_16x16x32_bf16(cah[mf], cbl[nf], acc[mf][nf], 0, 0, 0);
        acc[mf][nf] = __builtin_amdgcn_mfma_f32_16x16x32_bf16(cal[mf], cbh[nf], acc[mf][nf], 0, 0, 0);
      }
    if (ks < 6) {
#pragma unroll
      for (int i = 0; i < 4; ++i) {
        cah[i] = nah[i]; cal[i] = nal[i]; cbh[i] = nbh[i]; cbl[i] = nbl[i];
      }
    }
  }
  float* outp = hpre + (size_t)kc * 131072;
#pragma unroll
  for (int mf = 0; mf < 4; ++mf)
#pragma unroll
    for (int nf = 0; nf < 4; ++nf)
#pragma unroll
      for (int r = 0; r < 4; ++r)
        outp[(m0 + mf * 16 + hi4 * 4 + r) * 256 + n0 + nf * 16 + lm] = acc[mf][nf][r];
}

// ---------------- fc_post: sum 14 k-planes + bias + relu -> hout + a_split [512/row hi|lo] ----------------
__global__ __launch_bounds__(256) void fc_post_k(
    const float* __restrict__ hpre, const float* __restrict__ fb,
    float* __restrict__ hout, unsigned short* __restrict__ a_split) {
  int m = blockIdx.x, n = threadIdx.x;
  float v = fb[n];
#pragma unroll
  for (int kc = 0; kc < 14; ++kc) v += hpre[(size_t)kc * 131072 + m * 256 + n];
  v = fmaxf(v, 0.f);
  hout[m * 256 + n] = v;
  unsigned short hi = f2bf_rne(v);
  unsigned short lo = f2bf_rne(v - bf2f(hi));
  a_split[(size_t)m * 512 + n] = hi;
  a_split[(size_t)m * 512 + 256 + n] = lo;
}

// ---------------- embcvt: buf_emb -> Bemb[50176,512] bf16 (hi|lo) + nrm ----------------
__global__ __launch_bounds__(256) void embcvt_k(const float* __restrict__ e,
                                                unsigned short* __restrict__ Bemb,
                                                float* __restrict__ nrm) {
  int row = blockIdx.x * 4 + (threadIdx.x >> 6);
  if (row >= 50000) return;
  int lane = threadIdx.x & 63;
  float4 v = ((const float4*)(e + row * 256))[lane];
  float s = v.x * v.x + v.y * v.y + v.z * v.z + v.w * v.w;
  unsigned short h0 = f2bf_rne(v.x), h1 = f2bf_rne(v.y), h2 = f2bf_rne(v.z), h3 = f2bf_rne(v.w);
  unsigned short l0 = f2bf_rne(v.x - bf2f(h0)), l1 = f2bf_rne(v.y - bf2f(h1));
  unsigned short l2 = f2bf_rne(v.z - bf2f(h2)), l3 = f2bf_rne(v.w - bf2f(h3));
  *(ushort4*)(Bemb + (size_t)row * 512 + lane * 4) = make_ushort4(h0, h1, h2, h3);
  *(ushort4*)(Bemb + (size_t)row * 512 + 256 + lane * 4) = make_ushort4(l0, l1, l2, l3);
  for (int off = 32; off > 0; off >>= 1) s += __shfl_down(s, off);
  if (lane == 0) nrm[row] = s;
}

// ---------------- dist3: merged-term gload_lds MFMA distance GEMM + fused top-5 ----------------
// grid 1568 = 8xcd x 196; p = xcd*196+idx; nb = p>>2 (0..391), mb = p&3.
// Tile M=128 x N=128; 4 waves 2mw x 2nw. K = 4 slices of 64 shorts; per slice load
// Ah/Al/Bh/Bl planes ([128][64] each, 64KB total, single-buffer) and run all 3 split
// terms (Ah*Bh + Ah*Bl + Al*Bh) = 96 MFMA/wave per latency exposure.
// A rows [hi|lo] = 512 shorts (same stride as B). s_setprio(1) around MFMA (T5).
// Swizzle: 16B slot' = slot ^ (row&7) at per-lane GLOBAL source + on ds_read.
__global__ __launch_bounds__(256) void dist3_k(
    const unsigned short* __restrict__ a_split, const unsigned short* __restrict__ Bemb,
    const float* __restrict__ nrm, unsigned long long* __restrict__ cand) {
  __shared__ short Ah[8192];
  __shared__ short Al[8192];
  __shared__ short Bh[8192];
  __shared__ short Bl[8192];
  int t = threadIdx.x, w = t >> 6, lane = t & 63, lm = lane & 15, hi = lane >> 4;
  int mw = w >> 1, nw = w & 1;
  int b = blockIdx.x;
  int p = (b & 7) * 196 + (b >> 3);
  int nb = p >> 2, mb = p & 3;

  const unsigned short* aTile = a_split + (size_t)mb * 128 * 512;
  const unsigned short* bTile = Bemb + (size_t)nb * 128 * 512;

  int crow[4], csl[4];
#pragma unroll
  for (int i = 0; i < 4; ++i) {
    int p16 = (w * 4 + i) * 64 + lane;
    crow[i] = p16 >> 3;
    csl[i] = ((p16 & 7) ^ (crow[i] & 7)) * 8;
  }

  f32x4 acc[4][4];  // [nf][mf]
#pragma unroll
  for (int nf = 0; nf < 4; ++nf)
#pragma unroll
    for (int mf = 0; mf < 4; ++mf) acc[nf][mf] = (f32x4){0.f, 0.f, 0.f, 0.f};

  const int arow0 = mw * 64;
  const int brow0 = nw * 64;

  // prologue: issue slice 0 (kk=0)
#pragma unroll
  for (int i = 0; i < 4; ++i) {
    gload16(aTile + (size_t)crow[i] * 512 + csl[i], &Ah[(w * 4 + i) * 512]);
    gload16(aTile + (size_t)crow[i] * 512 + 256 + csl[i], &Al[(w * 4 + i) * 512]);
    gload16(bTile + (size_t)crow[i] * 512 + csl[i], &Bh[(w * 4 + i) * 512]);
    gload16(bTile + (size_t)crow[i] * 512 + 256 + csl[i], &Bl[(w * 4 + i) * 512]);
  }

#pragma unroll
  for (int kk = 0; kk < 4; ++kk) {
    asm volatile("s_waitcnt vmcnt(0)" ::: "memory");
    __builtin_amdgcn_s_barrier();
    __builtin_amdgcn_sched_barrier(0);
#pragma unroll
    for (int q2 = 0; q2 < 2; ++q2) {
      bf16x8 fah[4], fal[4], fbh[4], fbl[4];
#pragma unroll
      for (int mf = 0; mf < 4; ++mf) {
        int row = arow0 + mf * 16 + lm;
        int off = row * 64 + (((q2 * 4 + hi) ^ (lm & 7)) * 8);
        fah[mf] = *(const bf16x8*)(&Ah[off]);
        fal[mf] = *(const bf16x8*)(&Al[off]);
      }
#pragma unroll
      for (int nf = 0; nf < 4; ++nf) {
        int row = brow0 + nf * 16 + lm;
        int off = row * 64 + (((q2 * 4 + hi) ^ (lm & 7)) * 8);
        fbh[nf] = *(const bf16x8*)(&Bh[off]);
        fbl[nf] = *(const bf16x8*)(&Bl[off]);
      }
      __builtin_amdgcn_s_setprio(1);
#pragma unroll
      for (int nf = 0; nf < 4; ++nf)
#pragma unroll
        for (int mf = 0; mf < 4; ++mf) {
          acc[nf][mf] = __builtin_amdgcn_mfma_f32_16x16x32_bf16(fbh[nf], fah[mf], acc[nf][mf], 0, 0, 0);
          acc[nf][mf] = __builtin_amdgcn_mfma_f32_16x16x32_bf16(fbl[nf], fah[mf], acc[nf][mf], 0, 0, 0);
          acc[nf][mf] = __builtin_amdgcn_mfma_f32_16x16x32_bf16(fbh[nf], fal[mf], acc[nf][mf], 0, 0, 0);
        }
      __builtin_amdgcn_s_setprio(0);
    }
    if (kk < 3) {
      lds_barrier();  // all waves done reading this slice
      const int ko = (kk + 1) * 64;
#pragma unroll
      for (int i = 0; i < 4; ++i) {
        gload16(aTile + (size_t)crow[i] * 512 + ko + csl[i], &Ah[(w * 4 + i) * 512]);
        gload16(aTile + (size_t)crow[i] * 512 + 256 + ko + csl[i], &Al[(w * 4 + i) * 512]);
        gload16(bTile + (size_t)crow[i] * 512 + ko + csl[i], &Bh[(w * 4 + i) * 512]);
        gload16(bTile + (size_t)crow[i] * 512 + 256 + ko + csl[i], &Bl[(w * 4 + i) * 512]);
      }
    }
  }

  // ---- fused selection: per lane, per mf: sorted-5 of (score|n) u64 keys ----
  const int nbase = nb * 128 + nw * 64;
  const int mbase = mb * 128 + mw * 64;
  unsigned long long Lst[4][5];
#pragma unroll
  for (int mf = 0; mf < 4; ++mf)
#pragma unroll
    for (int j = 0; j < 5; ++j) Lst[mf][j] = ~0ull;

#pragma unroll
  for (int nf = 0; nf < 4; ++nf) {
    int n0 = nbase + nf * 16 + hi * 4;
    float4 nv = *(const float4*)(nrm + n0);
#pragma unroll
    for (int r = 0; r < 4; ++r) {
      int n = n0 + r;
      bool ok = n < 50000;
      float nvr = (r == 0) ? nv.x : (r == 1) ? nv.y : (r == 2) ? nv.z : nv.w;
#pragma unroll
      for (int mf = 0; mf < 4; ++mf) {
        float sc = nvr - 2.f * acc[nf][mf][r];
        unsigned u = __float_as_uint(sc);
        u = ((int)u < 0) ? ~u : (u | 0x80000000u);
        unsigned long long k = ok ? ((((unsigned long long)u) << 32) | (unsigned)n) : ~0ull;
        if (k < Lst[mf][4]) {
          bool b3 = k < Lst[mf][3], b2 = k < Lst[mf][2], b1 = k < Lst[mf][1], b0 = k < Lst[mf][0];
          Lst[mf][4] = b3 ? Lst[mf][3] : k;
          Lst[mf][3] = b3 ? (b2 ? Lst[mf][2] : k) : Lst[mf][3];
          Lst[mf][2] = b2 ? (b1 ? Lst[mf][1] : k) : Lst[mf][2];
          Lst[mf][1] = b1 ? (b0 ? Lst[mf][0] : k) : Lst[mf][1];
          Lst[mf][0] = b0 ? k : Lst[mf][0];
        }
      }
    }
  }
#pragma unroll
  for (int mf = 0; mf < 4; ++mf) {
#pragma unroll
    for (int s = 16; s <= 32; s <<= 1) {
      unsigned long long b0 = shflx64(Lst[mf][0], s), b1 = shflx64(Lst[mf][1], s),
                         b2 = shflx64(Lst[mf][2], s), b3 = shflx64(Lst[mf][3], s),
                         b4 = shflx64(Lst[mf][4], s);
      unsigned long long a0 = Lst[mf][0], a1 = Lst[mf][1], a2 = Lst[mf][2],
                         a3 = Lst[mf][3], a4 = Lst[mf][4];
#pragma unroll
      for (int j = 0; j < 5; ++j) {
        bool ta = a0 <= b0;
        Lst[mf][j] = ta ? a0 : b0;
        unsigned long long na0 = ta ? a1 : a0, na1 = ta ? a2 : a1, na2 = ta ? a3 : a2, na3 = ta ? a4 : a3;
        unsigned long long nb0 = ta ? b0 : b1, nb1 = ta ? b1 : b2, nb2 = ta ? b2 : b3, nb3 = ta ? b3 : b4;
        a0 = na0; a1 = na1; a2 = na2; a3 = na3;
        b0 = nb0; b1 = nb1; b2 = nb2; b3 = nb3;
      }
    }
  }
  if (lane < 16) {
#pragma unroll
    for (int mf = 0; mf < 4; ++mf) {
      size_t base = ((size_t)(mbase + mf * 16 + lm) * 784 + (nb * 2 + nw)) * 5;
#pragma unroll
      for (int j = 0; j < 5; ++j) cand[base + j] = Lst[mf][j];
    }
  }
}

// ---------------- merge2: per row top-5 of 3920 keys, gather+blend ----------------
__global__ __launch_bounds__(64) void merge2_k(
    const unsigned long long* __restrict__ cand, const float* __restrict__ hbuf,
    const float* __restrict__ bufq, const float* __restrict__ out_w,
    const float* __restrict__ out_b, float* __restrict__ qout) {
  int row = blockIdx.x, lane = threadIdx.x;
  unsigned long long L0 = ~0ull, L1 = ~0ull, L2 = ~0ull, L3 = ~0ull, L4 = ~0ull;
  const unsigned long long* cr = cand + (size_t)row * 3920;
  for (int i = lane; i < 3920; i += 64) {
    unsigned long long k = cr[i];
    if (k < L4) {
      bool b3 = k < L3, b2 = k < L2, b1 = k < L1, b0 = k < L0;
      L4 = b3 ? L3 : k;
      L3 = b3 ? (b2 ? L2 : k) : L3;
      L2 = b2 ? (b1 ? L1 : k) : L2;
      L1 = b1 ? (b0 ? L0 : k) : L1;
      L0 = b0 ? k : L0;
    }
  }
#pragma unroll
  for (int s = 1; s < 64; s <<= 1) {
    unsigned long long o0 = shflx64(L0, s), o1 = shflx64(L1, s), o2 = shflx64(L2, s),
                       o3 = shflx64(L3, s), o4 = shflx64(L4, s);
    unsigned long long a0 = L0, a1 = L1, a2 = L2, a3 = L3, a4 = L4;
    unsigned long long b0 = o0, b1 = o1, b2 = o2, b3 = o3, b4 = o4;
    unsigned long long m[5];
#pragma unroll
    for (int j = 0; j < 5; ++j) {
      bool ta = a0 <= b0;
      m[j] = ta ? a0 : b0;
      unsigned long long na0 = ta ? a1 : a0, na1 = ta ? a2 : a1, na2 = ta ? a3 : a2, na3 = ta ? a4 : a3;
      unsigned long long nb0 = ta ? b0 : b1, nb1 = ta ? b1 : b2, nb2 = ta ? b2 : b3, nb3 = ta ? b3 : b4;
      a0 = na0; a1 = na1; a2 = na2; a3 = na3;
      b0 = nb0; b1 = nb1; b2 = nb2; b3 = nb3;
    }
    L0 = m[0]; L1 = m[1]; L2 = m[2]; L3 = m[3]; L4 = m[4];
  }
  int i0 = (int)(L0 & 0xFFFFFFFFu), i1 = (int)(L1 & 0xFFFFFFFFu), i2 = (int)(L2 & 0xFFFFFFFFu);
  int i3 = (int)(L3 & 0xFFFFFFFFu), i4 = (int)(L4 & 0xFFFFFFFFu);
  if (lane < 18) {
    float np = 0.2f * (bufq[(size_t)i0 * 18 + lane] + bufq[(size_t)i1 * 18 + lane] +
                       bufq[(size_t)i2 * 18 + lane] + bufq[(size_t)i3 * 18 + lane] +
                       bufq[(size_t)i4 * 18 + lane]);
    const float* hr = hbuf + row * 256;
    float q = out_b[lane];
    for (int d = 0; d < 256; ++d) q += hr[d] * out_w[d * 18 + lane];
    qout[row * 18 + lane] = 0.5f * q + 0.5f * np;
  }
}

// ================= fallback (round-1 f32 path, unchanged) =================
__global__ __launch_bounds__(320) void conv1_k(
    const float* __restrict__ x, const float* __restrict__ w,
    const float* __restrict__ b, float* __restrict__ y) {
  __shared__ float x_s[4 * 84 * 84];
  int n = blockIdx.x;
  {
    const float4* src = (const float4*)(x + n * 28224);
    float4* dst = (float4*)x_s;
    for (int i = threadIdx.x; i < 7056; i += 320) dst[i] = src[i];
  }
  __syncthreads();
  int t = threadIdx.x;
  int ocg = t / 80, rem = t % 80, oy = rem / 4, oxg = rem % 4;
  float acc[8][5];
#pragma unroll
  for (int r = 0; r < 8; ++r) {
    float bv = b[ocg * 8 + r];
#pragma unroll
    for (int i = 0; i < 5; ++i) acc[r][i] = bv;
  }
  for (int ic = 0; ic < 4; ++ic) {
    for (int ky = 0; ky < 8; ++ky) {
      const float* xrow = x_s + ic * 7056 + (oy * 4 + ky) * 84 + oxg * 20;
      const float* wrow = w + ic * 64 + ky * 8;
#pragma unroll
      for (int kx = 0; kx < 8; ++kx) {
        float xv[5];
#pragma unroll
        for (int i = 0; i < 5; ++i) xv[i] = xrow[i * 4 + kx];
#pragma unroll
        for (int r = 0; r < 8; ++r) {
          float wv = wrow[(ocg * 8 + r) * 256 + kx];
#pragma unroll
          for (int i = 0; i < 5; ++i) acc[r][i] += wv * xv[i];
        }
      }
    }
  }
  float* yb = y + n * 12800 + oy * 20 + oxg * 5;
#pragma unroll
  for (int r = 0; r < 8; ++r)
#pragma unroll
    for (int i = 0; i < 5; ++i)
      yb[(ocg * 8 + r) * 400 + i] = fmaxf(acc[r][i], 0.f);
}

__global__ __launch_bounds__(256) void conv2_k(
    const float* __restrict__ h1, const float* __restrict__ w,
    const float* __restrict__ b, float* __restrict__ y) {
  __shared__ float x_s[32 * 400];
  int n = blockIdx.x;
  {
    const float4* src = (const float4*)(h1 + n * 12800);
    float4* dst = (float4*)x_s;
    for (int i = threadIdx.x; i < 3200; i += 256) dst[i] = src[i];
  }
  __syncthreads();
  int t = threadIdx.x;
  if (t < 216) {
    int ocg = t / 27, rem = t % 27, oy = rem / 3, oxg = rem % 3;
    float acc[8][3];
#pragma unroll
    for (int r = 0; r < 8; ++r) {
      float bv = b[ocg * 8 + r];
#pragma unroll
      for (int i = 0; i < 3; ++i) acc[r][i] = bv;
    }
    const float* xbase = x_s + (oy * 2) * 20 + oxg * 6;
    for (int ic = 0; ic < 32; ++ic) {
#pragma unroll
      for (int ky = 0; ky < 4; ++ky) {
        const float* xr = xbase + ic * 400 + ky * 20;
        const float* wr = w + ic * 16 + ky * 4;
#pragma unroll
        for (int kx = 0; kx < 4; ++kx) {
          float xv0 = xr[kx], xv1 = xr[kx + 2], xv2 = xr[kx + 4];
#pragma unroll
          for (int r = 0; r < 8; ++r) {
            float wv = wr[(ocg * 8 + r) * 512 + kx];
            acc[r][0] += wv * xv0;
            acc[r][1] += wv * xv1;
            acc[r][2] += wv * xv2;
          }
        }
      }
    }
    float* yb = y + n * 5184 + oy * 9 + oxg * 3;
#pragma unroll
    for (int r = 0; r < 8; ++r)
#pragma unroll
      for (int i = 0; i < 3; ++i)
        yb[(ocg * 8 + r) * 81 + i] = fmaxf(acc[r][i], 0.f);
  }
}

__global__ __launch_bounds__(128) void conv3_k(
    const float* __restrict__ h2, const float* __restrict__ w,
    const float* __restrict__ b, float* __restrict__ y) {
  __shared__ float x_s[64 * 81];
  int n = blockIdx.x;
  {
    const float4* src = (const float4*)(h2 + n * 5184);
    float4* dst = (float4*)x_s;
    for (int i = threadIdx.x; i < 1296; i += 128) dst[i] = src[i];
  }
  __syncthreads();
  int t = threadIdx.x;
  if (t < 112) {
    int ocg = t / 7, oy = t % 7;
    float acc[4][7];
#pragma unroll
    for (int r = 0; r < 4; ++r) {
      float bv = b[ocg * 4 + r];
#pragma unroll
      for (int i = 0; i < 7; ++i) acc[r][i] = bv;
    }
    for (int ic = 0; ic < 64; ++ic) {
#pragma unroll
      for (int ky = 0; ky < 3; ++ky) {
        const float* xr = x_s + ic * 81 + (oy + ky) * 9;
        float xv[9];
#pragma unroll
        for (int i = 0; i < 9; ++i) xv[i] = xr[i];
        const float* wr = w + ic * 9 + ky * 3;
#pragma unroll
        for (int kx = 0; kx < 3; ++kx) {
#pragma unroll
          for (int r = 0; r < 4; ++r) {
            float wv = wr[(ocg * 4 + r) * 576 + kx];
#pragma unroll
            for (int i = 0; i < 7; ++i) acc[r][i] += wv * xv[i + kx];
          }
        }
      }
    }
    float* yb = y + n * 3136 + oy * 7;
#pragma unroll
    for (int r = 0; r < 4; ++r)
#pragma unroll
      for (int i = 0; i < 7; ++i)
        yb[(ocg * 4 + r) * 49 + i] = fmaxf(acc[r][i], 0.f);
  }
}

__global__ __launch_bounds__(256) void fc_k(
    const float* __restrict__ h3, const float* __restrict__ fw,
    const float* __restrict__ fb, float* __restrict__ hout,
    unsigned short* __restrict__ a_split) {
  __shared__ float a_s[4 * 3136];
  int n0 = blockIdx.x * 4;
  {
    const float4* src = (const float4*)(h3 + n0 * 3136);
    float4* dst = (float4*)a_s;
    for (int i = threadIdx.x; i < 3136; i += 256) dst[i] = src[i];
  }
  __syncthreads();
  int j = threadIdx.x;
  float a0 = fb[j], a1 = a0, a2 = a0, a3 = a0;
  for (int k = 0; k < 3136; ++k) {
    float wv = fw[k * 256 + j];
    a0 += a_s[k] * wv;
    a1 += a_s[3136 + k] * wv;
    a2 += a_s[2 * 3136 + k] * wv;
    a3 += a_s[3 * 3136 + k] * wv;
  }
  float hv[4];
  hv[0] = fmaxf(a0, 0.f); hv[1] = fmaxf(a1, 0.f);
  hv[2] = fmaxf(a2, 0.f); hv[3] = fmaxf(a3, 0.f);
#pragma unroll
  for (int r = 0; r < 4; ++r) {
    hout[(n0 + r) * 256 + j] = hv[r];
    if (a_split) {
      unsigned short hi = f2bf_rne(hv[r]);
      unsigned short lo = f2bf_rne(hv[r] - bf2f(hi));
      a_split[(size_t)(n0 + r) * 512 + j] = hi;
      a_split[(size_t)(n0 + r) * 512 + 256 + j] = lo;
    }
  }
}

__global__ __launch_bounds__(256) void norm_k(const float* __restrict__ e,
                                              float* __restrict__ nrm) {
  int row = blockIdx.x * 4 + (threadIdx.x >> 6);
  if (row >= 50000) return;
  int lane = threadIdx.x & 63;
  float4 v = ((const float4*)(e + row * 256))[lane];
  float s = v.x * v.x + v.y * v.y + v.z * v.z + v.w * v.w;
  for (int off = 32; off > 0; off >>= 1) s += __shfl_down(s, off);
  if (lane == 0) nrm[row] = s;
}

__global__ __launch_bounds__(256) void dist_topk_k(
    const float* __restrict__ hbuf, const float* __restrict__ emb,
    const float* __restrict__ nrm, float* __restrict__ cand_d,
    int* __restrict__ cand_i) {
  __shared__ float a_s[16 * 256];
  __shared__ float b_s[512 * 17];
  int rb = blockIdx.x & 31, cb = blockIdx.x >> 5;
  int t = threadIdx.x;
  {
    const float4* src = (const float4*)(hbuf + rb * 16 * 256);
    float4* dst = (float4*)a_s;
    for (int i = t; i < 1024; i += 256) dst[i] = src[i];
  }
  float acc[8][4];
#pragma unroll
  for (int r = 0; r < 8; ++r)
#pragma unroll
    for (int c = 0; c < 4; ++c) acc[r][c] = 0.f;
  int ct = t & 127, rt = t >> 7;
  for (int kb = 0; kb < 256; kb += 16) {
    __syncthreads();
    for (int i = t; i < 2048; i += 256) {
      int j = i >> 2, kq = i & 3;
      int jg = cb * 512 + j;
      float4 v = make_float4(0.f, 0.f, 0.f, 0.f);
      if (jg < 50000) v = *(const float4*)(emb + jg * 256 + kb + kq * 4);
      float* dst = b_s + j * 17 + kq * 4;
      dst[0] = v.x; dst[1] = v.y; dst[2] = v.z; dst[3] = v.w;
    }
    __syncthreads();
#pragma unroll
    for (int k = 0; k < 16; ++k) {
      float av[8];
#pragma unroll
      for (int r = 0; r < 8; ++r) av[r] = a_s[(rt * 8 + r) * 256 + kb + k];
#pragma unroll
      for (int cc = 0; cc < 4; ++cc) {
        float bv = b_s[(ct + cc * 128) * 17 + k];
#pragma unroll
        for (int r = 0; r < 8; ++r) acc[r][cc] += av[r] * bv;
      }
    }
  }
  __syncthreads();
  float* score = b_s;
#pragma unroll
  for (int cc = 0; cc < 4; ++cc) {
    int c = ct + cc * 128;
    int jg = cb * 512 + c;
    float nv = (jg < 50000) ? nrm[jg] : 0.f;
#pragma unroll
    for (int r = 0; r < 8; ++r)
      score[(rt * 8 + r) * 512 + c] = (jg < 50000) ? (nv - 2.f * acc[r][cc]) : FINF;
  }
  __syncthreads();
  int wave = t >> 6, lane = t & 63;
  for (int rr = 0; rr < 4; ++rr) {
    int r = wave * 4 + rr;
    float v[8];
#pragma unroll
    for (int i = 0; i < 8; ++i) v[i] = score[r * 512 + lane + i * 64];
    for (int it = 0; it < 5; ++it) {
      float bv = v[0];
      int bc = lane;
#pragma unroll
      for (int i = 1; i < 8; ++i) {
        float xv = v[i];
        int c = lane + i * 64;
        if (xv < bv) { bv = xv; bc = c; }
      }
      for (int off = 32; off > 0; off >>= 1) {
        float ov = __shfl_down(bv, off);
        int ocx = __shfl_down(bc, off);
        if (ov < bv || (ov == bv && ocx < bc)) { bv = ov; bc = ocx; }
      }
      bv = __shfl(bv, 0);
      bc = __shfl(bc, 0);
      if (lane == 0) {
        int row_g = rb * 16 + r;
        int slot = (row_g * 98 + cb) * 5 + it;
        cand_d[slot] = bv;
        cand_i[slot] = cb * 512 + bc;
      }
#pragma unroll
      for (int i = 0; i < 8; ++i)
        if (lane + i * 64 == bc) v[i] = FINF;
    }
  }
}

__global__ __launch_bounds__(64) void merge_k(
    const float* __restrict__ cand_d, const int* __restrict__ cand_i,
    const float* __restrict__ hbuf, const float* __restrict__ bufq,
    const float* __restrict__ out_w, const float* __restrict__ out_b,
    float* __restrict__ qout) {
  int row = blockIdx.x, lane = threadIdx.x;
  __shared__ float sd[490];
  __shared__ int si[490];
  __shared__ int win[5];
  for (int i = lane; i < 490; i += 64) {
    sd[i] = cand_d[row * 490 + i];
    si[i] = cand_i[row * 490 + i];
  }
  __syncthreads();
  float v[8];
  int ix[8];
#pragma unroll
  for (int i = 0; i < 8; ++i) {
    int s = lane + i * 64;
    v[i] = (s < 490) ? sd[s] : FINF;
    ix[i] = (s < 490) ? si[s] : 0x7fffffff;
  }
  for (int it = 0; it < 5; ++it) {
    float bv = v[0];
    int bi = ix[0];
#pragma unroll
    for (int i = 1; i < 8; ++i)
      if (v[i] < bv || (v[i] == bv && ix[i] < bi)) { bv = v[i]; bi = ix[i]; }
    for (int off = 32; off > 0; off >>= 1) {
      float ov = __shfl_down(bv, off);
      int oi = __shfl_down(bi, off);
      if (ov < bv || (ov == bv && oi < bi)) { bv = ov; bi = oi; }
    }
    bi = __shfl(bi, 0);
    if (lane == 0) win[it] = bi;
#pragma unroll
    for (int i = 0; i < 8; ++i)
      if (ix[i] == bi) v[i] = FINF;
  }
  __syncthreads();
  if (lane < 18) {
    float np = 0.f;
#pragma unroll
    for (int it = 0; it < 5; ++it) np += bufq[win[it] * 18 + lane];
    np *= 0.2f;
    const float* hr = hbuf + row * 256;
    float q = out_b[lane];
    for (int d = 0; d < 256; ++d) q += hr[d] * out_w[d * 18 + lane];
    qout[row * 18 + lane] = 0.5f * q + 0.5f * np;
  }
}

extern "C" void kernel_launch(void* const* d_in, const int* in_sizes, int n_in,
                              void* d_out, int out_size, void* d_ws, size_t ws_size,
                              hipStream_t stream) {
  const float* x       = (const float*)d_in[0];
  const float* conv1_w = (const float*)d_in[1];
  const float* conv1_b = (const float*)d_in[2];
  const float* conv2_w = (const float*)d_in[3];
  const float* conv2_b = (const float*)d_in[4];
  const float* conv3_w = (const float*)d_in[5];
  const float* conv3_b = (const float*)d_in[6];
  const float* fc_w    = (const float*)d_in[7];
  const float* fc_b    = (const float*)d_in[8];
  const float* out_w   = (const float*)d_in[9];
  const float* out_b   = (const float*)d_in[10];
  const float* buf_emb = (const float*)d_in[11];
  const float* buf_q   = (const float*)d_in[12];

  float* out = (float*)d_out;  // [0,9216): q_blend; [9216,...): h
  float* hout = out + 9216;

  float* ws = (float*)d_ws;
  // mfma-path layout (float offsets into ws)
  unsigned short* h1s  = (unsigned short*)(ws);               // [0, 6,553,600 f)
  unsigned short* h2s  = (unsigned short*)(ws + 6553600);     // [6,553,600, 9,207,808 f)
  unsigned short* h3hi = (unsigned short*)(ws);               // reuses dead h1 region
  unsigned short* h3lo = (unsigned short*)(ws + 802816);
  unsigned short* Bs1h = (unsigned short*)(ws + 6553600);     // in h2s region (dead until conv2m)
  unsigned short* Bs1l = (unsigned short*)(ws + 6557696);
  float* nrm = ws + 9207808;                                  // [9,207,808, 9,257,984 f)
  unsigned long long* cand = (unsigned long long*)(ws + 9257984);  // [9,257,984, 13,272,064 f)
  // overlays inside cand region (dead before dist3 writes cand):
  unsigned short* Bs2h = (unsigned short*)(ws + 9257984);
  unsigned short* Bs2l = (unsigned short*)(ws + 9274368);
  unsigned short* Bs3h = (unsigned short*)(ws + 9290752);
  unsigned short* Bs3l = (unsigned short*)(ws + 9309184);     // ends 9,327,616 f
  unsigned short* fwhi = (unsigned short*)(ws + 9327616);
  unsigned short* fwlo = (unsigned short*)(ws + 9729024);     // ends 10,130,432 f
  float* hpre = ws + 10130432;
  unsigned short* a_split = (unsigned short*)(ws + 13272064); // 512 rows x 512 sh = 131,072 f
  unsigned short* Bemb = (unsigned short*)(ws + 13468672);    // ends 26,313,728 f
  const size_t NEED = 105254912ull;

  bool mfma_path = (ws_size >= NEED);

  if (mfma_path) {
    prep_k<<<238, 256, 0, stream>>>(conv1_w, Bs1h, Bs1l, conv2_w, Bs2h, Bs2l,
                                    conv3_w, Bs3h, Bs3l, fc_w, fwhi, fwlo);
    embcvt_k<<<12500, 256, 0, stream>>>(buf_emb, Bemb, nrm);
    conv1m_k<<<3200, 64, 0, stream>>>(x, Bs1h, Bs1l, conv1_b, h1s);
    conv2m_k<<<648, 64, 0, stream>>>(h1s, Bs2h, Bs2l, conv2_b, h2s);
    conv3m_k<<<392, 64, 0, stream>>>(h2s, Bs3h, Bs3l, conv3_b, h3hi, h3lo);
    fc2_k<<<448, 64, 0, stream>>>(h3hi, h3lo, fwhi, fwlo, hpre);
    fc_post_k<<<512, 256, 0, stream>>>(hpre, fc_b, hout, a_split);
    dist3_k<<<1568, 256, 0, stream>>>(a_split, Bemb, nrm, cand);
    merge2_k<<<512, 64, 0, stream>>>(cand, hout, buf_q, out_w, out_b, out);
  } else {
    // round-1 f32 fallback
    float* h1 = ws;
    float* h2 = h1 + 6553600;
    float* h3 = ws;
    float* nrm_o = h2 + 2654208;
    float* cand_d = nrm_o + 50000;
    int* cand_i = (int*)(cand_d + 250880);
    conv1_k<<<512, 320, 0, stream>>>(x, conv1_w, conv1_b, h1);
    conv2_k<<<512, 256, 0, stream>>>(h1, conv2_w, conv2_b, h2);
    conv3_k<<<512, 128, 0, stream>>>(h2, conv3_w, conv3_b, h3);
    fc_k<<<128, 256, 0, stream>>>(h3, fc_w, fc_b, hout, nullptr);
    norm_k<<<12500, 256, 0, stream>>>(buf_emb, nrm_o);
    dist_topk_k<<<3136, 256, 0, stream>>>(hout, buf_emb, nrm_o, cand_d, cand_i);
    merge_k<<<512, 64, 0, stream>>>(cand_d, cand_i, hout, buf_q, out_w, out_b, out);
  }
}

// Round 21
// 221.480 us; speedup vs baseline: 1.3828x; 1.0464x over previous
//
#include <hip/hip_runtime.h>
#include <hip/hip_bf16.h>

#define FINF 3.402823466e38f

typedef short bf16x8 __attribute__((ext_vector_type(8)));
typedef float f32x4 __attribute__((ext_vector_type(4)));

__device__ __forceinline__ unsigned short f2bf_rne(float f) {
  unsigned u = __float_as_uint(f);
  unsigned r = u + 0x7fff + ((u >> 16) & 1);
  return (unsigned short)(r >> 16);
}
__device__ __forceinline__ float bf2f(unsigned short u) {
  return __uint_as_float(((unsigned)u) << 16);
}
__device__ __forceinline__ unsigned long long shflx64(unsigned long long v, int m) {
  unsigned lo = __shfl_xor((unsigned)(v & 0xFFFFFFFFu), m, 64);
  unsigned hi = __shfl_xor((unsigned)(v >> 32), m, 64);
  return (((unsigned long long)hi) << 32) | lo;
}
// raw barrier: waits LDS ops only, leaves global prefetches in flight
__device__ __forceinline__ void lds_barrier() {
  asm volatile("s_waitcnt lgkmcnt(0)" ::: "memory");
  __builtin_amdgcn_s_barrier();
  __builtin_amdgcn_sched_barrier(0);
}
// wave-local LDS sync: ds_write -> ds_read within ONE wave needs only lgkmcnt,
// no s_barrier (rule #18: sched_barrier stops MFMA hoisting past the wait)
__device__ __forceinline__ void wave_sync() {
  asm volatile("s_waitcnt lgkmcnt(0)" ::: "memory");
  __builtin_amdgcn_sched_barrier(0);
}
// async global->LDS, 16B per lane; LDS dest = uniform base + lane*16
__device__ __forceinline__ void gload16(const unsigned short* g, short* l) {
  __builtin_amdgcn_global_load_lds(
      (const __attribute__((address_space(1))) unsigned int*)g,
      (__attribute__((address_space(3))) unsigned int*)l, 16, 0, 0);
}

// ---------------- prep: all weight conversions fused into one launch ----------------
__global__ __launch_bounds__(256) void prep_k(
    const float* __restrict__ w1, unsigned short* __restrict__ b1h, unsigned short* __restrict__ b1l,
    const float* __restrict__ w2, unsigned short* __restrict__ b2h, unsigned short* __restrict__ b2l,
    const float* __restrict__ w3, unsigned short* __restrict__ b3h, unsigned short* __restrict__ b3l,
    const float* __restrict__ fw, unsigned short* __restrict__ fwhi, unsigned short* __restrict__ fwlo) {
  __shared__ float tile[64][65];
  int b = blockIdx.x, t = threadIdx.x;
  if (b < 8) {
    if (t < 128) {
      int ky = b;
      int nf = t >> 6, l = t & 63;
      int oc = nf * 16 + (l & 15), ic = l >> 4;
      bf16x8 hv, lv;
#pragma unroll
      for (int j = 0; j < 8; ++j) {
        float v = w1[((oc * 4 + ic) * 8 + ky) * 8 + j];
        unsigned short h = f2bf_rne(v);
        hv[j] = (short)h;
        lv[j] = (short)f2bf_rne(v - bf2f(h));
      }
      *(bf16x8*)(&b1h[((size_t)(ky * 2 + nf) * 64 + l) * 8]) = hv;
      *(bf16x8*)(&b1l[((size_t)(ky * 2 + nf) * 64 + l) * 8]) = lv;
    }
  } else if (b < 24) {
    int tap = b - 8, ky = tap >> 2, kx = tap & 3;
    int nf = t >> 6, l = t & 63;
    int oc = nf * 16 + (l & 15);
    bf16x8 hv, lv;
#pragma unroll
    for (int j = 0; j < 8; ++j) {
      int ic = (l >> 4) * 8 + j;
      float v = w2[((oc * 32 + ic) * 4 + ky) * 4 + kx];
      unsigned short h = f2bf_rne(v);
      hv[j] = (short)h;
      lv[j] = (short)f2bf_rne(v - bf2f(h));
    }
    *(bf16x8*)(&b2h[((size_t)(tap * 4 + nf) * 64 + l) * 8]) = hv;
    *(bf16x8*)(&b2l[((size_t)(tap * 4 + nf) * 64 + l) * 8]) = lv;
  } else if (b < 42) {
    int tt = b - 24, tap = tt >> 1, half = tt & 1, ky = tap / 3, kx = tap % 3;
    int nf = t >> 6, l = t & 63;
    int oc = nf * 16 + (l & 15);
    bf16x8 hv, lv;
#pragma unroll
    for (int j = 0; j < 8; ++j) {
      int ic = half * 32 + (l >> 4) * 8 + j;
      float v = w3[((oc * 64 + ic) * 3 + ky) * 3 + kx];
      unsigned short h = f2bf_rne(v);
      hv[j] = (short)h;
      lv[j] = (short)f2bf_rne(v - bf2f(h));
    }
    *(bf16x8*)(&b3h[((size_t)(tt * 4 + nf) * 64 + l) * 8]) = hv;
    *(bf16x8*)(&b3l[((size_t)(tt * 4 + nf) * 64 + l) * 8]) = lv;
  } else {
    int idx = b - 42, p = idx % 49, nb = idx / 49;
#pragma unroll
    for (int i = 0; i < 16; ++i) {
      int c = (t >> 6) * 16 + i;
      tile[c][t & 63] = fw[(c * 49 + p) * 256 + nb * 64 + (t & 63)];
    }
    __syncthreads();
#pragma unroll
    for (int i = 0; i < 16; ++i) {
      int n2 = (t >> 6) * 16 + i, c2 = t & 63;
      float v = tile[c2][n2];
      unsigned short h = f2bf_rne(v);
      size_t o = (size_t)(nb * 64 + n2) * 3136 + p * 64 + c2;
      fwhi[o] = h;
      fwlo[o] = f2bf_rne(v - bf2f(h));
    }
  }
}

// ---------------- c1e: conv1m blocks [0,3200) + embcvt blocks [3200,9450), 64-thread ----------------
// conv part: x f32 -> h1s NHWC [204800 pix][32hi|32lo], 8-tap MFMA, wave-local LDS.
// emb part: buf_emb -> Bemb[50176,512] bf16 (hi|lo) + nrm, 8 rows per block (backfills CUs).
__global__ __launch_bounds__(64) void c1e_k(
    const float* __restrict__ x,
    const unsigned short* __restrict__ bh, const unsigned short* __restrict__ bl,
    const float* __restrict__ bias, unsigned short* __restrict__ h1s,
    const float* __restrict__ e, unsigned short* __restrict__ Bemb,
    float* __restrict__ nrm) {
  __shared__ short As[64 * 72];  // row*72: [0,32)=hi (4ic x 8kx), [36,68)=lo
  int blk = blockIdx.x;
  int t = threadIdx.x, lane = t, lm = lane & 15, hi4 = lane >> 4;
  if (blk >= 3200) {
    // ---- embcvt part ----
    int r0 = (blk - 3200) * 8;
#pragma unroll
    for (int i = 0; i < 8; ++i) {
      int row = r0 + i;
      if (row >= 50000) break;
      float4 v = ((const float4*)(e + (size_t)row * 256))[lane];
      float s = v.x * v.x + v.y * v.y + v.z * v.z + v.w * v.w;
      unsigned short h0 = f2bf_rne(v.x), h1 = f2bf_rne(v.y), h2 = f2bf_rne(v.z), h3 = f2bf_rne(v.w);
      unsigned short l0 = f2bf_rne(v.x - bf2f(h0)), l1 = f2bf_rne(v.y - bf2f(h1));
      unsigned short l2 = f2bf_rne(v.z - bf2f(h2)), l3 = f2bf_rne(v.w - bf2f(h3));
      *(ushort4*)(Bemb + (size_t)row * 512 + lane * 4) = make_ushort4(h0, h1, h2, h3);
      *(ushort4*)(Bemb + (size_t)row * 512 + 256 + lane * 4) = make_ushort4(l0, l1, l2, l3);
      for (int off = 32; off > 0; off >>= 1) s += __shfl_down(s, off);
      if (lane == 0) nrm[row] = s;
    }
    return;
  }
  // ---- conv1m part ----
  int m = blk * 64 + t;
  int n = m / 400, p = m % 400, oy = p / 20, ox = p % 20;
  size_t xoff = (size_t)n * 28224 + (size_t)(oy * 4) * 84 + ox * 4;  // + ic*7056 + ky*84
  f32x4 acc[4][2];
#pragma unroll
  for (int mf = 0; mf < 4; ++mf)
#pragma unroll
    for (int nf = 0; nf < 2; ++nf) acc[mf][nf] = (f32x4){0.f, 0.f, 0.f, 0.f};

  float4 fa[8];  // current tap: [ic*2 + half]
#pragma unroll
  for (int ic = 0; ic < 4; ++ic) {
    fa[ic * 2 + 0] = *(const float4*)(x + xoff + ic * 7056);
    fa[ic * 2 + 1] = *(const float4*)(x + xoff + ic * 7056 + 4);
  }
  const unsigned short* bfp = bh + (size_t)lane * 8;
  const unsigned short* blp = bl + (size_t)lane * 8;
  bf16x8 cbh[2], cbl[2];
#pragma unroll
  for (int nf = 0; nf < 2; ++nf) {
    cbh[nf] = *(const bf16x8*)(bfp + nf * 512);
    cbl[nf] = *(const bf16x8*)(blp + nf * 512);
  }
#pragma unroll
  for (int ky = 0; ky < 8; ++ky) {
    if (ky) wave_sync();  // own-wave reads of previous tap done
    {
      short* wp = &As[t * 72];
#pragma unroll
      for (int ic = 0; ic < 4; ++ic) {
        float e0 = fa[ic * 2].x, e1 = fa[ic * 2].y, e2 = fa[ic * 2].z, e3 = fa[ic * 2].w;
        float e4 = fa[ic * 2 + 1].x, e5 = fa[ic * 2 + 1].y, e6 = fa[ic * 2 + 1].z, e7 = fa[ic * 2 + 1].w;
        bf16x8 hv, lv;
        unsigned short h;
        h = f2bf_rne(e0); hv[0] = (short)h; lv[0] = (short)f2bf_rne(e0 - bf2f(h));
        h = f2bf_rne(e1); hv[1] = (short)h; lv[1] = (short)f2bf_rne(e1 - bf2f(h));
        h = f2bf_rne(e2); hv[2] = (short)h; lv[2] = (short)f2bf_rne(e2 - bf2f(h));
        h = f2bf_rne(e3); hv[3] = (short)h; lv[3] = (short)f2bf_rne(e3 - bf2f(h));
        h = f2bf_rne(e4); hv[4] = (short)h; lv[4] = (short)f2bf_rne(e4 - bf2f(h));
        h = f2bf_rne(e5); hv[5] = (short)h; lv[5] = (short)f2bf_rne(e5 - bf2f(h));
        h = f2bf_rne(e6); hv[6] = (short)h; lv[6] = (short)f2bf_rne(e6 - bf2f(h));
        h = f2bf_rne(e7); hv[7] = (short)h; lv[7] = (short)f2bf_rne(e7 - bf2f(h));
        *(bf16x8*)(wp + ic * 8) = hv;
        *(bf16x8*)(wp + 36 + ic * 8) = lv;
      }
    }
    wave_sync();  // own writes visible to own reads
    bf16x8 nbh[2], nbl[2];
    if (ky < 7) {
      size_t ap = xoff + (size_t)(ky + 1) * 84;
#pragma unroll
      for (int ic = 0; ic < 4; ++ic) {
        fa[ic * 2 + 0] = *(const float4*)(x + ap + ic * 7056);
        fa[ic * 2 + 1] = *(const float4*)(x + ap + ic * 7056 + 4);
      }
#pragma unroll
      for (int nf = 0; nf < 2; ++nf) {
        nbh[nf] = *(const bf16x8*)(bfp + ((ky + 1) * 2 + nf) * 512);
        nbl[nf] = *(const bf16x8*)(blp + ((ky + 1) * 2 + nf) * 512);
      }
    }
    bf16x8 ah[4], al[4];
#pragma unroll
    for (int mf = 0; mf < 4; ++mf) {
      const short* rp = &As[(mf * 16 + lm) * 72 + hi4 * 8];
      ah[mf] = *(const bf16x8*)(rp);
      al[mf] = *(const bf16x8*)(rp + 36);
    }
#pragma unroll
    for (int mf = 0; mf < 4; ++mf)
#pragma unroll
      for (int nf = 0; nf < 2; ++nf) {
        acc[mf][nf] = __builtin_amdgcn_mfma_f32_16x16x32_bf16(ah[mf], cbh[nf], acc[mf][nf], 0, 0, 0);
        acc[mf][nf] = __builtin_amdgcn_mfma_f32_16x16x32_bf16(ah[mf], cbl[nf], acc[mf][nf], 0, 0, 0);
        acc[mf][nf] = __builtin_amdgcn_mfma_f32_16x16x32_bf16(al[mf], cbh[nf], acc[mf][nf], 0, 0, 0);
      }
    if (ky < 7) {
#pragma unroll
      for (int nf = 0; nf < 2; ++nf) { cbh[nf] = nbh[nf]; cbl[nf] = nbl[nf]; }
    }
  }
  float bv[2];
#pragma unroll
  for (int nf = 0; nf < 2; ++nf) bv[nf] = bias[nf * 16 + lm];
#pragma unroll
  for (int mf = 0; mf < 4; ++mf)
#pragma unroll
    for (int nf = 0; nf < 2; ++nf)
#pragma unroll
      for (int r = 0; r < 4; ++r) {
        size_t mrow = (size_t)blk * 64 + mf * 16 + hi4 * 4 + r;
        float v = fmaxf(acc[mf][nf][r] + bv[nf], 0.f);
        unsigned short h = f2bf_rne(v);
        h1s[mrow * 64 + nf * 16 + lm] = h;
        h1s[mrow * 64 + 32 + nf * 16 + lm] = f2bf_rne(v - bf2f(h));
      }
}

// ---------------- conv2m: h1s NHWC -> h2s [41472 pix][64hi|64lo], 16-tap MFMA, 1-wave blocks ----------------
__global__ __launch_bounds__(64) void conv2m_k(
    const unsigned short* __restrict__ h1s, const unsigned short* __restrict__ bh,
    const unsigned short* __restrict__ bl, const float* __restrict__ bias,
    unsigned short* __restrict__ h2s) {
  __shared__ short As[64 * 72];
  int t = threadIdx.x, lane = t, lm = lane & 15, hi4 = lane >> 4;
  int m = blockIdx.x * 64 + t;
  int n = m / 81, p = m % 81, oy = p / 9, ox = p % 9;
  const unsigned short* abase = h1s + (size_t)(n * 400 + oy * 40 + ox * 2) * 64;
  f32x4 acc[4][4];
#pragma unroll
  for (int mf = 0; mf < 4; ++mf)
#pragma unroll
    for (int nf = 0; nf < 4; ++nf) acc[mf][nf] = (f32x4){0.f, 0.f, 0.f, 0.f};

  bf16x8 s0, s1, s2, s3, s4, s5, s6, s7;
  {
    const unsigned short* ap = abase;  // tap 0
    s0 = *(const bf16x8*)(ap);      s1 = *(const bf16x8*)(ap + 8);
    s2 = *(const bf16x8*)(ap + 16); s3 = *(const bf16x8*)(ap + 24);
    s4 = *(const bf16x8*)(ap + 32); s5 = *(const bf16x8*)(ap + 40);
    s6 = *(const bf16x8*)(ap + 48); s7 = *(const bf16x8*)(ap + 56);
  }
  const unsigned short* bfp = bh + (size_t)lane * 8;
  const unsigned short* blp = bl + (size_t)lane * 8;
  bf16x8 cbh[4], cbl[4];
#pragma unroll
  for (int nf = 0; nf < 4; ++nf) {
    cbh[nf] = *(const bf16x8*)(bfp + nf * 512);
    cbl[nf] = *(const bf16x8*)(blp + nf * 512);
  }
#pragma unroll
  for (int tap = 0; tap < 16; ++tap) {
    if (tap) wave_sync();
    {
      short* wp = &As[t * 72];
      *(bf16x8*)(wp) = s0;      *(bf16x8*)(wp + 8) = s1;
      *(bf16x8*)(wp + 16) = s2; *(bf16x8*)(wp + 24) = s3;
      *(bf16x8*)(wp + 36) = s4; *(bf16x8*)(wp + 44) = s5;
      *(bf16x8*)(wp + 52) = s6; *(bf16x8*)(wp + 60) = s7;
    }
    wave_sync();
    bf16x8 nbh[4], nbl[4];
    if (tap < 15) {
      const unsigned short* ap = abase + (((tap + 1) >> 2) * 1280 + ((tap + 1) & 3) * 64);
      s0 = *(const bf16x8*)(ap);      s1 = *(const bf16x8*)(ap + 8);
      s2 = *(const bf16x8*)(ap + 16); s3 = *(const bf16x8*)(ap + 24);
      s4 = *(const bf16x8*)(ap + 32); s5 = *(const bf16x8*)(ap + 40);
      s6 = *(const bf16x8*)(ap + 48); s7 = *(const bf16x8*)(ap + 56);
#pragma unroll
      for (int nf = 0; nf < 4; ++nf) {
        nbh[nf] = *(const bf16x8*)(bfp + ((tap + 1) * 4 + nf) * 512);
        nbl[nf] = *(const bf16x8*)(blp + ((tap + 1) * 4 + nf) * 512);
      }
    }
    bf16x8 ah[4], al[4];
#pragma unroll
    for (int mf = 0; mf < 4; ++mf) {
      const short* rp = &As[(mf * 16 + lm) * 72 + hi4 * 8];
      ah[mf] = *(const bf16x8*)(rp);
      al[mf] = *(const bf16x8*)(rp + 36);
    }
#pragma unroll
    for (int mf = 0; mf < 4; ++mf)
#pragma unroll
      for (int nf = 0; nf < 4; ++nf) {
        acc[mf][nf] = __builtin_amdgcn_mfma_f32_16x16x32_bf16(ah[mf], cbh[nf], acc[mf][nf], 0, 0, 0);
        acc[mf][nf] = __builtin_amdgcn_mfma_f32_16x16x32_bf16(ah[mf], cbl[nf], acc[mf][nf], 0, 0, 0);
        acc[mf][nf] = __builtin_amdgcn_mfma_f32_16x16x32_bf16(al[mf], cbh[nf], acc[mf][nf], 0, 0, 0);
      }
    if (tap < 15) {
#pragma unroll
      for (int nf = 0; nf < 4; ++nf) { cbh[nf] = nbh[nf]; cbl[nf] = nbl[nf]; }
    }
  }
  float bv[4];
#pragma unroll
  for (int nf = 0; nf < 4; ++nf) bv[nf] = bias[nf * 16 + lm];
#pragma unroll
  for (int mf = 0; mf < 4; ++mf)
#pragma unroll
    for (int nf = 0; nf < 4; ++nf)
#pragma unroll
      for (int r = 0; r < 4; ++r) {
        size_t mrow = (size_t)blockIdx.x * 64 + mf * 16 + hi4 * 4 + r;
        float v = fmaxf(acc[mf][nf][r] + bv[nf], 0.f);
        unsigned short h = f2bf_rne(v);
        h2s[mrow * 128 + nf * 16 + lm] = h;
        h2s[mrow * 128 + 64 + nf * 16 + lm] = f2bf_rne(v - bf2f(h));
      }
}

// ---------------- conv3m: h2s -> h3hi/h3lo [25088 pix][64], 18-chunk MFMA, 1-wave blocks ----------------
__global__ __launch_bounds__(64) void conv3m_k(
    const unsigned short* __restrict__ h2s, const unsigned short* __restrict__ bh,
    const unsigned short* __restrict__ bl, const float* __restrict__ bias,
    unsigned short* __restrict__ h3hi, unsigned short* __restrict__ h3lo) {
  __shared__ short As[64 * 72];
  int t = threadIdx.x, lane = t, lm = lane & 15, hi4 = lane >> 4;
  int m = blockIdx.x * 64 + t;
  int n = m / 49, p = m % 49, oy = p / 7, ox = p % 7;
  const unsigned short* abase = h2s + (size_t)(n * 81 + oy * 9 + ox) * 128;
  f32x4 acc[4][4];
#pragma unroll
  for (int mf = 0; mf < 4; ++mf)
#pragma unroll
    for (int nf = 0; nf < 4; ++nf) acc[mf][nf] = (f32x4){0.f, 0.f, 0.f, 0.f};

  bf16x8 s0, s1, s2, s3, s4, s5, s6, s7;
  {
    const unsigned short* ap = abase;
    s0 = *(const bf16x8*)(ap);      s1 = *(const bf16x8*)(ap + 8);
    s2 = *(const bf16x8*)(ap + 16); s3 = *(const bf16x8*)(ap + 24);
    s4 = *(const bf16x8*)(ap + 64); s5 = *(const bf16x8*)(ap + 72);
    s6 = *(const bf16x8*)(ap + 80); s7 = *(const bf16x8*)(ap + 88);
  }
  const unsigned short* bfp = bh + (size_t)lane * 8;
  const unsigned short* blp = bl + (size_t)lane * 8;
  bf16x8 cbh[4], cbl[4];
#pragma unroll
  for (int nf = 0; nf < 4; ++nf) {
    cbh[nf] = *(const bf16x8*)(bfp + nf * 512);
    cbl[nf] = *(const bf16x8*)(blp + nf * 512);
  }
#pragma unroll
  for (int tt = 0; tt < 18; ++tt) {
    if (tt) wave_sync();
    {
      short* wp = &As[t * 72];
      *(bf16x8*)(wp) = s0;      *(bf16x8*)(wp + 8) = s1;
      *(bf16x8*)(wp + 16) = s2; *(bf16x8*)(wp + 24) = s3;
      *(bf16x8*)(wp + 36) = s4; *(bf16x8*)(wp + 44) = s5;
      *(bf16x8*)(wp + 52) = s6; *(bf16x8*)(wp + 60) = s7;
    }
    wave_sync();
    bf16x8 nbh[4], nbl[4];
    if (tt < 17) {
      const int tn = tt + 1, tapn = tn >> 1, halfn = tn & 1;
      const unsigned short* ap = abase + ((tapn / 3) * 9 + (tapn % 3)) * 128 + halfn * 32;
      s0 = *(const bf16x8*)(ap);      s1 = *(const bf16x8*)(ap + 8);
      s2 = *(const bf16x8*)(ap + 16); s3 = *(const bf16x8*)(ap + 24);
      s4 = *(const bf16x8*)(ap + 64); s5 = *(const bf16x8*)(ap + 72);
      s6 = *(const bf16x8*)(ap + 80); s7 = *(const bf16x8*)(ap + 88);
#pragma unroll
      for (int nf = 0; nf < 4; ++nf) {
        nbh[nf] = *(const bf16x8*)(bfp + ((tt + 1) * 4 + nf) * 512);
        nbl[nf] = *(const bf16x8*)(blp + ((tt + 1) * 4 + nf) * 512);
      }
    }
    bf16x8 ah[4], al[4];
#pragma unroll
    for (int mf = 0; mf < 4; ++mf) {
      const short* rp = &As[(mf * 16 + lm) * 72 + hi4 * 8];
      ah[mf] = *(const bf16x8*)(rp);
      al[mf] = *(const bf16x8*)(rp + 36);
    }
#pragma unroll
    for (int mf = 0; mf < 4; ++mf)
#pragma unroll
      for (int nf = 0; nf < 4; ++nf) {
        acc[mf][nf] = __builtin_amdgcn_mfma_f32_16x16x32_bf16(ah[mf], cbh[nf], acc[mf][nf], 0, 0, 0);
        acc[mf][nf] = __builtin_amdgcn_mfma_f32_16x16x32_bf16(ah[mf], cbl[nf], acc[mf][nf], 0, 0, 0);
        acc[mf][nf] = __builtin_amdgcn_mfma_f32_16x16x32_bf16(al[mf], cbh[nf], acc[mf][nf], 0, 0, 0);
      }
    if (tt < 17) {
#pragma unroll
      for (int nf = 0; nf < 4; ++nf) { cbh[nf] = nbh[nf]; cbl[nf] = nbl[nf]; }
    }
  }
  float bv[4];
#pragma unroll
  for (int nf = 0; nf < 4; ++nf) bv[nf] = bias[nf * 16 + lm];
#pragma unroll
  for (int mf = 0; mf < 4; ++mf)
#pragma unroll
    for (int nf = 0; nf < 4; ++nf)
#pragma unroll
      for (int r = 0; r < 4; ++r) {
        size_t mrow = (size_t)blockIdx.x * 64 + mf * 16 + hi4 * 4 + r;
        float v = fmaxf(acc[mf][nf][r] + bv[nf], 0.f);
        unsigned short h = f2bf_rne(v);
        h3hi[mrow * 64 + nf * 16 + lm] = h;
        h3lo[mrow * 64 + nf * 16 + lm] = f2bf_rne(v - bf2f(h));
      }
}

// ---------------- fc2: split-bf16 MFMA, 1-wave blocks: grid 8mb x 14kc x 4nw ----------------
__global__ __launch_bounds__(64) void fc2_k(
    const unsigned short* __restrict__ h3hi, const unsigned short* __restrict__ h3lo,
    const unsigned short* __restrict__ fwhi, const unsigned short* __restrict__ fwlo,
    float* __restrict__ hpre) {
  int t = threadIdx.x, lane = t, lm = lane & 15, hi4 = lane >> 4;
  int b = blockIdx.x;
  int mb = b / 56, r56 = b % 56, kc = r56 >> 2, nw = r56 & 3;
  int m0 = mb * 64, n0 = nw * 64;
  size_t kof = (size_t)kc * 224 + hi4 * 8;
  const unsigned short* pah[4]; const unsigned short* pal[4];
  const unsigned short* pbh[4]; const unsigned short* pbl[4];
#pragma unroll
  for (int mf = 0; mf < 4; ++mf) {
    pah[mf] = h3hi + (size_t)(m0 + mf * 16 + lm) * 3136 + kof;
    pal[mf] = h3lo + (size_t)(m0 + mf * 16 + lm) * 3136 + kof;
  }
#pragma unroll
  for (int nf = 0; nf < 4; ++nf) {
    pbh[nf] = fwhi + (size_t)(n0 + nf * 16 + lm) * 3136 + kof;
    pbl[nf] = fwlo + (size_t)(n0 + nf * 16 + lm) * 3136 + kof;
  }
  f32x4 acc[4][4];
#pragma unroll
  for (int mf = 0; mf < 4; ++mf)
#pragma unroll
    for (int nf = 0; nf < 4; ++nf) acc[mf][nf] = (f32x4){0.f, 0.f, 0.f, 0.f};
  bf16x8 cah[4], cal[4], cbh[4], cbl[4];
#pragma unroll
  for (int i = 0; i < 4; ++i) {
    cah[i] = *(const bf16x8*)(pah[i]); cal[i] = *(const bf16x8*)(pal[i]);
    cbh[i] = *(const bf16x8*)(pbh[i]); cbl[i] = *(const bf16x8*)(pbl[i]);
  }
#pragma unroll
  for (int ks = 0; ks < 7; ++ks) {
    bf16x8 nah[4], nal[4], nbh[4], nbl[4];
    if (ks < 6) {
      const int off = (ks + 1) * 32;
#pragma unroll
      for (int i = 0; i < 4; ++i) {
        nah[i] = *(const bf16x8*)(pah[i] + off); nal[i] = *(const bf16x8*)(pal[i] + off);
        nbh[i] = *(const bf16x8*)(pbh[i] + off); nbl[i] = *(const bf16x8*)(pbl[i] + off);
      }
    }
#pragma unroll
    for (int mf = 0; mf < 4; ++mf)
#pragma unroll
      for (int nf = 0; nf < 4; ++nf) {
        acc[mf][nf] = __builtin_amdgcn_mfma_f32_16x16x32_bf16(cah[mf], cbh[nf], acc[mf][nf], 0, 0, 0);
        acc[mf][nf] = __builtin_amdgcn_mfma_f32_16x16x32_bf16(cah[mf], cbl[nf], acc[mf][nf], 0, 0, 0);
        acc[mf][nf] = __builtin_amdgcn_mfma_f32_16x16x32_bf16(cal[mf], cbh[nf], acc[mf][nf], 0, 0, 0);
      }
    if (ks < 6) {
#pragma unroll
      for (int i = 0; i < 4; ++i) {
        cah[i] = nah[i]; cal[i] = nal[i]; cbh[i] = nbh[i]; cbl[i] = nbl[i];
      }
    }
  }
  float* outp = hpre + (size_t)kc * 131072;
#pragma unroll
  for (int mf = 0; mf < 4; ++mf)
#pragma unroll
    for (int nf = 0; nf < 4; ++nf)
#pragma unroll
      for (int r = 0; r < 4; ++r)
        outp[(m0 + mf * 16 + hi4 * 4 + r) * 256 + n0 + nf * 16 + lm] = acc[mf][nf][r];
}

// ---------------- fc_post: sum 14 k-planes + bias + relu -> hout + a_split [512/row hi|lo] ----------------
__global__ __launch_bounds__(256) void fc_post_k(
    const float* __restrict__ hpre, const float* __restrict__ fb,
    float* __restrict__ hout, unsigned short* __restrict__ a_split) {
  int m = blockIdx.x, n = threadIdx.x;
  float v = fb[n];
#pragma unroll
  for (int kc = 0; kc < 14; ++kc) v += hpre[(size_t)kc * 131072 + m * 256 + n];
  v = fmaxf(v, 0.f);
  hout[m * 256 + n] = v;
  unsigned short hi = f2bf_rne(v);
  unsigned short lo = f2bf_rne(v - bf2f(hi));
  a_split[(size_t)m * 512 + n] = hi;
  a_split[(size_t)m * 512 + 256 + n] = lo;
}

// ---------------- dist3: merged-term gload_lds MFMA distance GEMM + fused top-5 ----------------
// grid 1568 = 8xcd x 196; p = xcd*196+idx; nb = p>>2 (0..391), mb = p&3.
// Tile M=128 x N=128; 4 waves 2mw x 2nw. K = 4 slices of 64 shorts; per slice load
// Ah/Al/Bh/Bl planes ([128][64] each, 64KB total, single-buffer) and run all 3 split
// terms (Ah*Bh + Ah*Bl + Al*Bh) = 96 MFMA/wave per latency exposure.
// A rows [hi|lo] = 512 shorts (same stride as B). s_setprio(1) around MFMA (T5).
// Swizzle: 16B slot' = slot ^ (row&7) at per-lane GLOBAL source + on ds_read.
__global__ __launch_bounds__(256) void dist3_k(
    const unsigned short* __restrict__ a_split, const unsigned short* __restrict__ Bemb,
    const float* __restrict__ nrm, unsigned long long* __restrict__ cand) {
  __shared__ short Ah[8192];
  __shared__ short Al[8192];
  __shared__ short Bh[8192];
  __shared__ short Bl[8192];
  int t = threadIdx.x, w = t >> 6, lane = t & 63, lm = lane & 15, hi = lane >> 4;
  int mw = w >> 1, nw = w & 1;
  int b = blockIdx.x;
  int p = (b & 7) * 196 + (b >> 3);
  int nb = p >> 2, mb = p & 3;

  const unsigned short* aTile = a_split + (size_t)mb * 128 * 512;
  const unsigned short* bTile = Bemb + (size_t)nb * 128 * 512;

  int crow[4], csl[4];
#pragma unroll
  for (int i = 0; i < 4; ++i) {
    int p16 = (w * 4 + i) * 64 + lane;
    crow[i] = p16 >> 3;
    csl[i] = ((p16 & 7) ^ (crow[i] & 7)) * 8;
  }

  f32x4 acc[4][4];  // [nf][mf]
#pragma unroll
  for (int nf = 0; nf < 4; ++nf)
#pragma unroll
    for (int mf = 0; mf < 4; ++mf) acc[nf][mf] = (f32x4){0.f, 0.f, 0.f, 0.f};

  const int arow0 = mw * 64;
  const int brow0 = nw * 64;

  // prologue: issue slice 0 (kk=0)
#pragma unroll
  for (int i = 0; i < 4; ++i) {
    gload16(aTile + (size_t)crow[i] * 512 + csl[i], &Ah[(w * 4 + i) * 512]);
    gload16(aTile + (size_t)crow[i] * 512 + 256 + csl[i], &Al[(w * 4 + i) * 512]);
    gload16(bTile + (size_t)crow[i] * 512 + csl[i], &Bh[(w * 4 + i) * 512]);
    gload16(bTile + (size_t)crow[i] * 512 + 256 + csl[i], &Bl[(w * 4 + i) * 512]);
  }

#pragma unroll
  for (int kk = 0; kk < 4; ++kk) {
    asm volatile("s_waitcnt vmcnt(0)" ::: "memory");
    __builtin_amdgcn_s_barrier();
    __builtin_amdgcn_sched_barrier(0);
#pragma unroll
    for (int q2 = 0; q2 < 2; ++q2) {
      bf16x8 fah[4], fal[4], fbh[4], fbl[4];
#pragma unroll
      for (int mf = 0; mf < 4; ++mf) {
        int row = arow0 + mf * 16 + lm;
        int off = row * 64 + (((q2 * 4 + hi) ^ (lm & 7)) * 8);
        fah[mf] = *(const bf16x8*)(&Ah[off]);
        fal[mf] = *(const bf16x8*)(&Al[off]);
      }
#pragma unroll
      for (int nf = 0; nf < 4; ++nf) {
        int row = brow0 + nf * 16 + lm;
        int off = row * 64 + (((q2 * 4 + hi) ^ (lm & 7)) * 8);
        fbh[nf] = *(const bf16x8*)(&Bh[off]);
        fbl[nf] = *(const bf16x8*)(&Bl[off]);
      }
      __builtin_amdgcn_s_setprio(1);
#pragma unroll
      for (int nf = 0; nf < 4; ++nf)
#pragma unroll
        for (int mf = 0; mf < 4; ++mf) {
          acc[nf][mf] = __builtin_amdgcn_mfma_f32_16x16x32_bf16(fbh[nf], fah[mf], acc[nf][mf], 0, 0, 0);
          acc[nf][mf] = __builtin_amdgcn_mfma_f32_16x16x32_bf16(fbl[nf], fah[mf], acc[nf][mf], 0, 0, 0);
          acc[nf][mf] = __builtin_amdgcn_mfma_f32_16x16x32_bf16(fbh[nf], fal[mf], acc[nf][mf], 0, 0, 0);
        }
      __builtin_amdgcn_s_setprio(0);
    }
    if (kk < 3) {
      lds_barrier();  // all waves done reading this slice
      const int ko = (kk + 1) * 64;
#pragma unroll
      for (int i = 0; i < 4; ++i) {
        gload16(aTile + (size_t)crow[i] * 512 + ko + csl[i], &Ah[(w * 4 + i) * 512]);
        gload16(aTile + (size_t)crow[i] * 512 + 256 + ko + csl[i], &Al[(w * 4 + i) * 512]);
        gload16(bTile + (size_t)crow[i] * 512 + ko + csl[i], &Bh[(w * 4 + i) * 512]);
        gload16(bTile + (size_t)crow[i] * 512 + 256 + ko + csl[i], &Bl[(w * 4 + i) * 512]);
      }
    }
  }

  // ---- fused selection: per lane, per mf: sorted-5 of (score|n) u64 keys ----
  const int nbase = nb * 128 + nw * 64;
  const int mbase = mb * 128 + mw * 64;
  unsigned long long Lst[4][5];
#pragma unroll
  for (int mf = 0; mf < 4; ++mf)
#pragma unroll
    for (int j = 0; j < 5; ++j) Lst[mf][j] = ~0ull;

#pragma unroll
  for (int nf = 0; nf < 4; ++nf) {
    int n0 = nbase + nf * 16 + hi * 4;
    float4 nv = *(const float4*)(nrm + n0);
#pragma unroll
    for (int r = 0; r < 4; ++r) {
      int n = n0 + r;
      bool ok = n < 50000;
      float nvr = (r == 0) ? nv.x : (r == 1) ? nv.y : (r == 2) ? nv.z : nv.w;
#pragma unroll
      for (int mf = 0; mf < 4; ++mf) {
        float sc = nvr - 2.f * acc[nf][mf][r];
        unsigned u = __float_as_uint(sc);
        u = ((int)u < 0) ? ~u : (u | 0x80000000u);
        unsigned long long k = ok ? ((((unsigned long long)u) << 32) | (unsigned)n) : ~0ull;
        if (k < Lst[mf][4]) {
          bool b3 = k < Lst[mf][3], b2 = k < Lst[mf][2], b1 = k < Lst[mf][1], b0 = k < Lst[mf][0];
          Lst[mf][4] = b3 ? Lst[mf][3] : k;
          Lst[mf][3] = b3 ? (b2 ? Lst[mf][2] : k) : Lst[mf][3];
          Lst[mf][2] = b2 ? (b1 ? Lst[mf][1] : k) : Lst[mf][2];
          Lst[mf][1] = b1 ? (b0 ? Lst[mf][0] : k) : Lst[mf][1];
          Lst[mf][0] = b0 ? k : Lst[mf][0];
        }
      }
    }
  }
#pragma unroll
  for (int mf = 0; mf < 4; ++mf) {
#pragma unroll
    for (int s = 16; s <= 32; s <<= 1) {
      unsigned long long b0 = shflx64(Lst[mf][0], s), b1 = shflx64(Lst[mf][1], s),
                         b2 = shflx64(Lst[mf][2], s), b3 = shflx64(Lst[mf][3], s),
                         b4 = shflx64(Lst[mf][4], s);
      unsigned long long a0 = Lst[mf][0], a1 = Lst[mf][1], a2 = Lst[mf][2],
                         a3 = Lst[mf][3], a4 = Lst[mf][4];
#pragma unroll
      for (int j = 0; j < 5; ++j) {
        bool ta = a0 <= b0;
        Lst[mf][j] = ta ? a0 : b0;
        unsigned long long na0 = ta ? a1 : a0, na1 = ta ? a2 : a1, na2 = ta ? a3 : a2, na3 = ta ? a4 : a3;
        unsigned long long nb0 = ta ? b0 : b1, nb1 = ta ? b1 : b2, nb2 = ta ? b2 : b3, nb3 = ta ? b3 : b4;
        a0 = na0; a1 = na1; a2 = na2; a3 = na3;
        b0 = nb0; b1 = nb1; b2 = nb2; b3 = nb3;
      }
    }
  }
  if (lane < 16) {
#pragma unroll
    for (int mf = 0; mf < 4; ++mf) {
      size_t base = ((size_t)(mbase + mf * 16 + lm) * 784 + (nb * 2 + nw)) * 5;
#pragma unroll
      for (int j = 0; j < 5; ++j) cand[base + j] = Lst[mf][j];
    }
  }
}

// ---------------- merge2: per row top-5 of 3920 keys, gather+blend ----------------
__global__ __launch_bounds__(64) void merge2_k(
    const unsigned long long* __restrict__ cand, const float* __restrict__ hbuf,
    const float* __restrict__ bufq, const float* __restrict__ out_w,
    const float* __restrict__ out_b, float* __restrict__ qout) {
  int row = blockIdx.x, lane = threadIdx.x;
  unsigned long long L0 = ~0ull, L1 = ~0ull, L2 = ~0ull, L3 = ~0ull, L4 = ~0ull;
  const unsigned long long* cr = cand + (size_t)row * 3920;
  for (int i = lane; i < 3920; i += 64) {
    unsigned long long k = cr[i];
    if (k < L4) {
      bool b3 = k < L3, b2 = k < L2, b1 = k < L1, b0 = k < L0;
      L4 = b3 ? L3 : k;
      L3 = b3 ? (b2 ? L2 : k) : L3;
      L2 = b2 ? (b1 ? L1 : k) : L2;
      L1 = b1 ? (b0 ? L0 : k) : L1;
      L0 = b0 ? k : L0;
    }
  }
#pragma unroll
  for (int s = 1; s < 64; s <<= 1) {
    unsigned long long o0 = shflx64(L0, s), o1 = shflx64(L1, s), o2 = shflx64(L2, s),
                       o3 = shflx64(L3, s), o4 = shflx64(L4, s);
    unsigned long long a0 = L0, a1 = L1, a2 = L2, a3 = L3, a4 = L4;
    unsigned long long b0 = o0, b1 = o1, b2 = o2, b3 = o3, b4 = o4;
    unsigned long long m[5];
#pragma unroll
    for (int j = 0; j < 5; ++j) {
      bool ta = a0 <= b0;
      m[j] = ta ? a0 : b0;
      unsigned long long na0 = ta ? a1 : a0, na1 = ta ? a2 : a1, na2 = ta ? a3 : a2, na3 = ta ? a4 : a3;
      unsigned long long nb0 = ta ? b0 : b1, nb1 = ta ? b1 : b2, nb2 = ta ? b2 : b3, nb3 = ta ? b3 : b4;
      a0 = na0; a1 = na1; a2 = na2; a3 = na3;
      b0 = nb0; b1 = nb1; b2 = nb2; b3 = nb3;
    }
    L0 = m[0]; L1 = m[1]; L2 = m[2]; L3 = m[3]; L4 = m[4];
  }
  int i0 = (int)(L0 & 0xFFFFFFFFu), i1 = (int)(L1 & 0xFFFFFFFFu), i2 = (int)(L2 & 0xFFFFFFFFu);
  int i3 = (int)(L3 & 0xFFFFFFFFu), i4 = (int)(L4 & 0xFFFFFFFFu);
  if (lane < 18) {
    float np = 0.2f * (bufq[(size_t)i0 * 18 + lane] + bufq[(size_t)i1 * 18 + lane] +
                       bufq[(size_t)i2 * 18 + lane] + bufq[(size_t)i3 * 18 + lane] +
                       bufq[(size_t)i4 * 18 + lane]);
    const float* hr = hbuf + row * 256;
    float q = out_b[lane];
    for (int d = 0; d < 256; ++d) q += hr[d] * out_w[d * 18 + lane];
    qout[row * 18 + lane] = 0.5f * q + 0.5f * np;
  }
}

// ================= fallback (round-1 f32 path, unchanged) =================
__global__ __launch_bounds__(320) void conv1_k(
    const float* __restrict__ x, const float* __restrict__ w,
    const float* __restrict__ b, float* __restrict__ y) {
  __shared__ float x_s[4 * 84 * 84];
  int n = blockIdx.x;
  {
    const float4* src = (const float4*)(x + n * 28224);
    float4* dst = (float4*)x_s;
    for (int i = threadIdx.x; i < 7056; i += 320) dst[i] = src[i];
  }
  __syncthreads();
  int t = threadIdx.x;
  int ocg = t / 80, rem = t % 80, oy = rem / 4, oxg = rem % 4;
  float acc[8][5];
#pragma unroll
  for (int r = 0; r < 8; ++r) {
    float bv = b[ocg * 8 + r];
#pragma unroll
    for (int i = 0; i < 5; ++i) acc[r][i] = bv;
  }
  for (int ic = 0; ic < 4; ++ic) {
    for (int ky = 0; ky < 8; ++ky) {
      const float* xrow = x_s + ic * 7056 + (oy * 4 + ky) * 84 + oxg * 20;
      const float* wrow = w + ic * 64 + ky * 8;
#pragma unroll
      for (int kx = 0; kx < 8; ++kx) {
        float xv[5];
#pragma unroll
        for (int i = 0; i < 5; ++i) xv[i] = xrow[i * 4 + kx];
#pragma unroll
        for (int r = 0; r < 8; ++r) {
          float wv = wrow[(ocg * 8 + r) * 256 + kx];
#pragma unroll
          for (int i = 0; i < 5; ++i) acc[r][i] += wv * xv[i];
        }
      }
    }
  }
  float* yb = y + n * 12800 + oy * 20 + oxg * 5;
#pragma unroll
  for (int r = 0; r < 8; ++r)
#pragma unroll
    for (int i = 0; i < 5; ++i)
      yb[(ocg * 8 + r) * 400 + i] = fmaxf(acc[r][i], 0.f);
}

__global__ __launch_bounds__(256) void conv2_k(
    const float* __restrict__ h1, const float* __restrict__ w,
    const float* __restrict__ b, float* __restrict__ y) {
  __shared__ float x_s[32 * 400];
  int n = blockIdx.x;
  {
    const float4* src = (const float4*)(h1 + n * 12800);
    float4* dst = (float4*)x_s;
    for (int i = threadIdx.x; i < 3200; i += 256) dst[i] = src[i];
  }
  __syncthreads();
  int t = threadIdx.x;
  if (t < 216) {
    int ocg = t / 27, rem = t % 27, oy = rem / 3, oxg = rem % 3;
    float acc[8][3];
#pragma unroll
    for (int r = 0; r < 8; ++r) {
      float bv = b[ocg * 8 + r];
#pragma unroll
      for (int i = 0; i < 3; ++i) acc[r][i] = bv;
    }
    const float* xbase = x_s + (oy * 2) * 20 + oxg * 6;
    for (int ic = 0; ic < 32; ++ic) {
#pragma unroll
      for (int ky = 0; ky < 4; ++ky) {
        const float* xr = xbase + ic * 400 + ky * 20;
        const float* wr = w + ic * 16 + ky * 4;
#pragma unroll
        for (int kx = 0; kx < 4; ++kx) {
          float xv0 = xr[kx], xv1 = xr[kx + 2], xv2 = xr[kx + 4];
#pragma unroll
          for (int r = 0; r < 8; ++r) {
            float wv = wr[(ocg * 8 + r) * 512 + kx];
            acc[r][0] += wv * xv0;
            acc[r][1] += wv * xv1;
            acc[r][2] += wv * xv2;
          }
        }
      }
    }
    float* yb = y + n * 5184 + oy * 9 + oxg * 3;
#pragma unroll
    for (int r = 0; r < 8; ++r)
#pragma unroll
      for (int i = 0; i < 3; ++i)
        yb[(ocg * 8 + r) * 81 + i] = fmaxf(acc[r][i], 0.f);
  }
}

__global__ __launch_bounds__(128) void conv3_k(
    const float* __restrict__ h2, const float* __restrict__ w,
    const float* __restrict__ b, float* __restrict__ y) {
  __shared__ float x_s[64 * 81];
  int n = blockIdx.x;
  {
    const float4* src = (const float4*)(h2 + n * 5184);
    float4* dst = (float4*)x_s;
    for (int i = threadIdx.x; i < 1296; i += 128) dst[i] = src[i];
  }
  __syncthreads();
  int t = threadIdx.x;
  if (t < 112) {
    int ocg = t / 7, oy = t % 7;
    float acc[4][7];
#pragma unroll
    for (int r = 0; r < 4; ++r) {
      float bv = b[ocg * 4 + r];
#pragma unroll
      for (int i = 0; i < 7; ++i) acc[r][i] = bv;
    }
    for (int ic = 0; ic < 64; ++ic) {
#pragma unroll
      for (int ky = 0; ky < 3; ++ky) {
        const float* xr = x_s + ic * 81 + (oy + ky) * 9;
        float xv[9];
#pragma unroll
        for (int i = 0; i < 9; ++i) xv[i] = xr[i];
        const float* wr = w + ic * 9 + ky * 3;
#pragma unroll
        for (int kx = 0; kx < 3; ++kx) {
#pragma unroll
          for (int r = 0; r < 4; ++r) {
            float wv = wr[(ocg * 4 + r) * 576 + kx];
#pragma unroll
            for (int i = 0; i < 7; ++i) acc[r][i] += wv * xv[i + kx];
          }
        }
      }
    }
    float* yb = y + n * 3136 + oy * 7;
#pragma unroll
    for (int r = 0; r < 4; ++r)
#pragma unroll
      for (int i = 0; i < 7; ++i)
        yb[(ocg * 4 + r) * 49 + i] = fmaxf(acc[r][i], 0.f);
  }
}

__global__ __launch_bounds__(256) void fc_k(
    const float* __restrict__ h3, const float* __restrict__ fw,
    const float* __restrict__ fb, float* __restrict__ hout,
    unsigned short* __restrict__ a_split) {
  __shared__ float a_s[4 * 3136];
  int n0 = blockIdx.x * 4;
  {
    const float4* src = (const float4*)(h3 + n0 * 3136);
    float4* dst = (float4*)a_s;
    for (int i = threadIdx.x; i < 3136; i += 256) dst[i] = src[i];
  }
  __syncthreads();
  int j = threadIdx.x;
  float a0 = fb[j], a1 = a0, a2 = a0, a3 = a0;
  for (int k = 0; k < 3136; ++k) {
    float wv = fw[k * 256 + j];
    a0 += a_s[k] * wv;
    a1 += a_s[3136 + k] * wv;
    a2 += a_s[2 * 3136 + k] * wv;
    a3 += a_s[3 * 3136 + k] * wv;
  }
  float hv[4];
  hv[0] = fmaxf(a0, 0.f); hv[1] = fmaxf(a1, 0.f);
  hv[2] = fmaxf(a2, 0.f); hv[3] = fmaxf(a3, 0.f);
#pragma unroll
  for (int r = 0; r < 4; ++r) {
    hout[(n0 + r) * 256 + j] = hv[r];
    if (a_split) {
      unsigned short hi = f2bf_rne(hv[r]);
      unsigned short lo = f2bf_rne(hv[r] - bf2f(hi));
      a_split[(size_t)(n0 + r) * 512 + j] = hi;
      a_split[(size_t)(n0 + r) * 512 + 256 + j] = lo;
    }
  }
}

__global__ __launch_bounds__(256) void norm_k(const float* __restrict__ e,
                                              float* __restrict__ nrm) {
  int row = blockIdx.x * 4 + (threadIdx.x >> 6);
  if (row >= 50000) return;
  int lane = threadIdx.x & 63;
  float4 v = ((const float4*)(e + row * 256))[lane];
  float s = v.x * v.x + v.y * v.y + v.z * v.z + v.w * v.w;
  for (int off = 32; off > 0; off >>= 1) s += __shfl_down(s, off);
  if (lane == 0) nrm[row] = s;
}

__global__ __launch_bounds__(256) void dist_topk_k(
    const float* __restrict__ hbuf, const float* __restrict__ emb,
    const float* __restrict__ nrm, float* __restrict__ cand_d,
    int* __restrict__ cand_i) {
  __shared__ float a_s[16 * 256];
  __shared__ float b_s[512 * 17];
  int rb = blockIdx.x & 31, cb = blockIdx.x >> 5;
  int t = threadIdx.x;
  {
    const float4* src = (const float4*)(hbuf + rb * 16 * 256);
    float4* dst = (float4*)a_s;
    for (int i = t; i < 1024; i += 256) dst[i] = src[i];
  }
  float acc[8][4];
#pragma unroll
  for (int r = 0; r < 8; ++r)
#pragma unroll
    for (int c = 0; c < 4; ++c) acc[r][c] = 0.f;
  int ct = t & 127, rt = t >> 7;
  for (int kb = 0; kb < 256; kb += 16) {
    __syncthreads();
    for (int i = t; i < 2048; i += 256) {
      int j = i >> 2, kq = i & 3;
      int jg = cb * 512 + j;
      float4 v = make_float4(0.f, 0.f, 0.f, 0.f);
      if (jg < 50000) v = *(const float4*)(emb + jg * 256 + kb + kq * 4);
      float* dst = b_s + j * 17 + kq * 4;
      dst[0] = v.x; dst[1] = v.y; dst[2] = v.z; dst[3] = v.w;
    }
    __syncthreads();
#pragma unroll
    for (int k = 0; k < 16; ++k) {
      float av[8];
#pragma unroll
      for (int r = 0; r < 8; ++r) av[r] = a_s[(rt * 8 + r) * 256 + kb + k];
#pragma unroll
      for (int cc = 0; cc < 4; ++cc) {
        float bv = b_s[(ct + cc * 128) * 17 + k];
#pragma unroll
        for (int r = 0; r < 8; ++r) acc[r][cc] += av[r] * bv;
      }
    }
  }
  __syncthreads();
  float* score = b_s;
#pragma unroll
  for (int cc = 0; cc < 4; ++cc) {
    int c = ct + cc * 128;
    int jg = cb * 512 + c;
    float nv = (jg < 50000) ? nrm[jg] : 0.f;
#pragma unroll
    for (int r = 0; r < 8; ++r)
      score[(rt * 8 + r) * 512 + c] = (jg < 50000) ? (nv - 2.f * acc[r][cc]) : FINF;
  }
  __syncthreads();
  int wave = t >> 6, lane = t & 63;
  for (int rr = 0; rr < 4; ++rr) {
    int r = wave * 4 + rr;
    float v[8];
#pragma unroll
    for (int i = 0; i < 8; ++i) v[i] = score[r * 512 + lane + i * 64];
    for (int it = 0; it < 5; ++it) {
      float bv = v[0];
      int bc = lane;
#pragma unroll
      for (int i = 1; i < 8; ++i) {
        float xv = v[i];
        int c = lane + i * 64;
        if (xv < bv) { bv = xv; bc = c; }
      }
      for (int off = 32; off > 0; off >>= 1) {
        float ov = __shfl_down(bv, off);
        int ocx = __shfl_down(bc, off);
        if (ov < bv || (ov == bv && ocx < bc)) { bv = ov; bc = ocx; }
      }
      bv = __shfl(bv, 0);
      bc = __shfl(bc, 0);
      if (lane == 0) {
        int row_g = rb * 16 + r;
        int slot = (row_g * 98 + cb) * 5 + it;
        cand_d[slot] = bv;
        cand_i[slot] = cb * 512 + bc;
      }
#pragma unroll
      for (int i = 0; i < 8; ++i)
        if (lane + i * 64 == bc) v[i] = FINF;
    }
  }
}

__global__ __launch_bounds__(64) void merge_k(
    const float* __restrict__ cand_d, const int* __restrict__ cand_i,
    const float* __restrict__ hbuf, const float* __restrict__ bufq,
    const float* __restrict__ out_w, const float* __restrict__ out_b,
    float* __restrict__ qout) {
  int row = blockIdx.x, lane = threadIdx.x;
  __shared__ float sd[490];
  __shared__ int si[490];
  __shared__ int win[5];
  for (int i = lane; i < 490; i += 64) {
    sd[i] = cand_d[row * 490 + i];
    si[i] = cand_i[row * 490 + i];
  }
  __syncthreads();
  float v[8];
  int ix[8];
#pragma unroll
  for (int i = 0; i < 8; ++i) {
    int s = lane + i * 64;
    v[i] = (s < 490) ? sd[s] : FINF;
    ix[i] = (s < 490) ? si[s] : 0x7fffffff;
  }
  for (int it = 0; it < 5; ++it) {
    float bv = v[0];
    int bi = ix[0];
#pragma unroll
    for (int i = 1; i < 8; ++i)
      if (v[i] < bv || (v[i] == bv && ix[i] < bi)) { bv = v[i]; bi = ix[i]; }
    for (int off = 32; off > 0; off >>= 1) {
      float ov = __shfl_down(bv, off);
      int oi = __shfl_down(bi, off);
      if (ov < bv || (ov == bv && oi < bi)) { bv = ov; bi = oi; }
    }
    bi = __shfl(bi, 0);
    if (lane == 0) win[it] = bi;
#pragma unroll
    for (int i = 0; i < 8; ++i)
      if (ix[i] == bi) v[i] = FINF;
  }
  __syncthreads();
  if (lane < 18) {
    float np = 0.f;
#pragma unroll
    for (int it = 0; it < 5; ++it) np += bufq[win[it] * 18 + lane];
    np *= 0.2f;
    const float* hr = hbuf + row * 256;
    float q = out_b[lane];
    for (int d = 0; d < 256; ++d) q += hr[d] * out_w[d * 18 + lane];
    qout[row * 18 + lane] = 0.5f * q + 0.5f * np;
  }
}

extern "C" void kernel_launch(void* const* d_in, const int* in_sizes, int n_in,
                              void* d_out, int out_size, void* d_ws, size_t ws_size,
                              hipStream_t stream) {
  const float* x       = (const float*)d_in[0];
  const float* conv1_w = (const float*)d_in[1];
  const float* conv1_b = (const float*)d_in[2];
  const float* conv2_w = (const float*)d_in[3];
  const float* conv2_b = (const float*)d_in[4];
  const float* conv3_w = (const float*)d_in[5];
  const float* conv3_b = (const float*)d_in[6];
  const float* fc_w    = (const float*)d_in[7];
  const float* fc_b    = (const float*)d_in[8];
  const float* out_w   = (const float*)d_in[9];
  const float* out_b   = (const float*)d_in[10];
  const float* buf_emb = (const float*)d_in[11];
  const float* buf_q   = (const float*)d_in[12];

  float* out = (float*)d_out;  // [0,9216): q_blend; [9216,...): h
  float* hout = out + 9216;

  float* ws = (float*)d_ws;
  // mfma-path layout (float offsets into ws)
  unsigned short* h1s  = (unsigned short*)(ws);               // [0, 6,553,600 f)
  unsigned short* h2s  = (unsigned short*)(ws + 6553600);     // [6,553,600, 9,207,808 f)
  unsigned short* h3hi = (unsigned short*)(ws);               // reuses dead h1 region
  unsigned short* h3lo = (unsigned short*)(ws + 802816);
  unsigned short* Bs1h = (unsigned short*)(ws + 6553600);     // in h2s region (dead until conv2m)
  unsigned short* Bs1l = (unsigned short*)(ws + 6557696);
  float* nrm = ws + 9207808;                                  // [9,207,808, 9,257,984 f)
  unsigned long long* cand = (unsigned long long*)(ws + 9257984);  // [9,257,984, 13,272,064 f)
  // overlays inside cand region (dead before dist3 writes cand):
  unsigned short* Bs2h = (unsigned short*)(ws + 9257984);
  unsigned short* Bs2l = (unsigned short*)(ws + 9274368);
  unsigned short* Bs3h = (unsigned short*)(ws + 9290752);
  unsigned short* Bs3l = (unsigned short*)(ws + 9309184);     // ends 9,327,616 f
  unsigned short* fwhi = (unsigned short*)(ws + 9327616);
  unsigned short* fwlo = (unsigned short*)(ws + 9729024);     // ends 10,130,432 f
  float* hpre = ws + 10130432;
  unsigned short* a_split = (unsigned short*)(ws + 13272064); // 512 rows x 512 sh = 131,072 f
  unsigned short* Bemb = (unsigned short*)(ws + 13468672);    // ends 26,313,728 f
  const size_t NEED = 105254912ull;

  bool mfma_path = (ws_size >= NEED);

  if (mfma_path) {
    prep_k<<<238, 256, 0, stream>>>(conv1_w, Bs1h, Bs1l, conv2_w, Bs2h, Bs2l,
                                    conv3_w, Bs3h, Bs3l, fc_w, fwhi, fwlo);
    c1e_k<<<9450, 64, 0, stream>>>(x, Bs1h, Bs1l, conv1_b, h1s,
                                   buf_emb, Bemb, nrm);  // conv1m + embcvt fused
    conv2m_k<<<648, 64, 0, stream>>>(h1s, Bs2h, Bs2l, conv2_b, h2s);
    conv3m_k<<<392, 64, 0, stream>>>(h2s, Bs3h, Bs3l, conv3_b, h3hi, h3lo);
    fc2_k<<<448, 64, 0, stream>>>(h3hi, h3lo, fwhi, fwlo, hpre);
    fc_post_k<<<512, 256, 0, stream>>>(hpre, fc_b, hout, a_split);
    dist3_k<<<1568, 256, 0, stream>>>(a_split, Bemb, nrm, cand);
    merge2_k<<<512, 64, 0, stream>>>(cand, hout, buf_q, out_w, out_b, out);
  } else {
    // round-1 f32 fallback
    float* h1 = ws;
    float* h2 = h1 + 6553600;
    float* h3 = ws;
    float* nrm_o = h2 + 2654208;
    float* cand_d = nrm_o + 50000;
    int* cand_i = (int*)(cand_d + 250880);
    conv1_k<<<512, 320, 0, stream>>>(x, conv1_w, conv1_b, h1);
    conv2_k<<<512, 256, 0, stream>>>(h1, conv2_w, conv2_b, h2);
    conv3_k<<<512, 128, 0, stream>>>(h2, conv3_w, conv3_b, h3);
    fc_k<<<128, 256, 0, stream>>>(h3, fc_w, fc_b, hout, nullptr);
    norm_k<<<12500, 256, 0, stream>>>(buf_emb, nrm_o);
    dist_topk_k<<<3136, 256, 0, stream>>>(hout, buf_emb, nrm_o, cand_d, cand_i);
    merge_k<<<512, 64, 0, stream>>>(cand_d, cand_i, hout, buf_q, out_w, out_b, out);
  }
}